// Round 3
// baseline (822.863 us; speedup 1.0000x reference)
//
#include <hip/hip_runtime.h>
#include <cstdint>

#define N_NODES 50000
#define N_EDGES 500000
#define ET (N_NODES + N_EDGES)   /* 550000 edges incl. self-loops */

typedef unsigned short u16;
typedef unsigned int   u32;

__device__ __forceinline__ float bf2f(u16 s) { return __uint_as_float((u32)s << 16); }
__device__ __forceinline__ u16 f2bf(float f) {          // round-to-nearest-even
  u32 u = __float_as_uint(f);
  u32 r = (u + 0x7FFFu + ((u >> 16) & 1u)) >> 16;
  return (u16)r;
}
__device__ __forceinline__ void unpack8(uint4 u, float* f) {  // 8 bf16 -> fp32
  f[0] = __uint_as_float(u.x << 16); f[1] = __uint_as_float(u.x & 0xffff0000u);
  f[2] = __uint_as_float(u.y << 16); f[3] = __uint_as_float(u.y & 0xffff0000u);
  f[4] = __uint_as_float(u.z << 16); f[5] = __uint_as_float(u.z & 0xffff0000u);
  f[6] = __uint_as_float(u.w << 16); f[7] = __uint_as_float(u.w & 0xffff0000u);
}

// ---------------- dtype detect + canonicalize to fp32 ----------------
// If inputs are fp32 but read as bf16, even-indexed u16s are fp32 mantissa
// bits -> ~50% have |bf16|>=16 (or NaN). True-bf16 N(0,1) data never does.
__global__ void k_detect(const u16* __restrict__ ne, int* __restrict__ flag) {
  int lane = threadIdx.x;  // 64 threads, one wave
  int bad = 0;
  #pragma unroll
  for (int j = 0; j < 2; ++j) {
    float v = fabsf(bf2f(ne[lane * 2 + j * 128]));  // even positions only
    bad += (!(v < 16.0f)) ? 1 : 0;                  // catches NaN too
  }
  #pragma unroll
  for (int off = 32; off >= 1; off >>= 1) bad += __shfl_xor(bad, off, 64);
  if (lane == 0) flag[0] = (bad > 16) ? 1 : 0;      // 1 => inputs are fp32
}

__global__ void k_convert(const void* __restrict__ src, float* __restrict__ dst,
                          int n, const int* __restrict__ flag) {
  int i = blockIdx.x * 256 + threadIdx.x;
  if (i >= n) return;
  if (flag[0]) dst[i] = ((const float*)src)[i];
  else         dst[i] = bf2f(((const u16*)src)[i]);
}

// ---------------- CSR build (dst-sorted) ----------------
__global__ void k_degree(const int* __restrict__ ei, int* __restrict__ deg) {
  int e = blockIdx.x * 256 + threadIdx.x;
  if (e >= ET) return;
  int d = (e < N_EDGES) ? ei[N_EDGES + e] : (e - N_EDGES);
  atomicAdd(&deg[d], 1);
}

__global__ __launch_bounds__(1024) void k_partial(const int* __restrict__ deg,
                                                  int* __restrict__ excl,
                                                  int* __restrict__ btot) {
  __shared__ int wsum[16];
  int tid = threadIdx.x;
  int i = blockIdx.x * 1024 + tid;
  int v = (i < N_NODES) ? deg[i] : 0;
  int lane = tid & 63, wid = tid >> 6;
  int incl = v;
  #pragma unroll
  for (int off = 1; off < 64; off <<= 1) {
    int t = __shfl_up(incl, off, 64);
    if (lane >= off) incl += t;
  }
  if (lane == 63) wsum[wid] = incl;
  __syncthreads();
  int prefix = 0;
  for (int w = 0; w < wid; ++w) prefix += wsum[w];
  if (i < N_NODES) excl[i] = prefix + incl - v;
  if (tid == 1023) btot[blockIdx.x] = prefix + incl;
}

__global__ void k_bases(const int* __restrict__ btot, int* __restrict__ bbase,
                        int* __restrict__ row_off, int nb) {
  int lane = threadIdx.x;  // 64 threads, single wave
  int v = (lane < nb) ? btot[lane] : 0;
  int incl = v;
  #pragma unroll
  for (int off = 1; off < 64; off <<= 1) {
    int t = __shfl_up(incl, off, 64);
    if (lane >= off) incl += t;
  }
  if (lane < nb) bbase[lane] = incl - v;
  if (lane == 0) row_off[N_NODES] = ET;
}

__global__ __launch_bounds__(1024) void k_add(int* __restrict__ row_off,
                                              int* __restrict__ cursor,
                                              const int* __restrict__ bbase) {
  int i = blockIdx.x * 1024 + threadIdx.x;
  if (i < N_NODES) {
    int r = row_off[i] + bbase[blockIdx.x];
    row_off[i] = r;
    cursor[i] = r;
  }
}

__global__ void k_scatter(const int* __restrict__ ei, int* __restrict__ cursor,
                          int* __restrict__ srcs) {
  int e = blockIdx.x * 256 + threadIdx.x;
  if (e >= ET) return;
  int s, d;
  if (e < N_EDGES) { s = ei[e]; d = ei[N_EDGES + e]; }
  else { s = d = e - N_EDGES; }
  int pos = atomicAdd(&cursor[d], 1);
  srcs[pos] = s;
}

// ---------------- GEMM: C[M,Nc](bf16) = A[M,K] * B[K,Nc](fp32), fp32 acc ----
// A is fp32 (layer1) or bf16 (layer2, our own buffer). 64x128x64 tiles.
template <bool A_BF16>
__global__ __launch_bounds__(256) void k_gemm(const void* __restrict__ Av,
                                              const float* __restrict__ B,
                                              u16* __restrict__ C,
                                              int M, int K, int Nc) {
  __shared__ float As[64][64];    // As[k][m] (A transposed)
  __shared__ float Bs[64][128];   // Bs[k][n]
  const int tid = threadIdx.x;
  const int cg = tid & 31, rg = tid >> 5;
  const int row0 = blockIdx.x * 64, col0 = blockIdx.y * 128;
  float acc[8][4] = {};
  for (int kk = 0; kk < K; kk += 64) {
    if (A_BF16) {
      const u16* A = (const u16*)Av;
      #pragma unroll
      for (int it = 0; it < 2; ++it) {
        int v = tid + it * 256;
        int row = v >> 3, w8 = (v & 7) << 3;
        float f[8];
        int gr = row0 + row;
        if (gr < M) {
          uint4 u = *(const uint4*)(A + (size_t)gr * K + kk + w8);
          unpack8(u, f);
        } else {
          #pragma unroll
          for (int j = 0; j < 8; ++j) f[j] = 0.f;
        }
        #pragma unroll
        for (int j = 0; j < 8; ++j) As[w8 + j][row] = f[j];
      }
    } else {
      const float* A = (const float*)Av;
      #pragma unroll
      for (int it = 0; it < 4; ++it) {
        int v = tid + it * 256;
        int row = v >> 4, c4 = (v & 15) << 2;
        float4 u = make_float4(0.f, 0.f, 0.f, 0.f);
        int gr = row0 + row;
        if (gr < M) u = *(const float4*)(A + (size_t)gr * K + kk + c4);
        As[c4 + 0][row] = u.x; As[c4 + 1][row] = u.y;
        As[c4 + 2][row] = u.z; As[c4 + 3][row] = u.w;
      }
    }
    #pragma unroll
    for (int it = 0; it < 8; ++it) {           // stage B 64x128
      int v = tid + it * 256;
      int krow = v >> 5, c4 = (v & 31) << 2;
      *(float4*)&Bs[krow][c4] =
          *(const float4*)(B + (size_t)(kk + krow) * Nc + col0 + c4);
    }
    __syncthreads();
    #pragma unroll 8
    for (int k = 0; k < 64; ++k) {
      float4 a0 = *(const float4*)&As[k][rg * 8];
      float4 a1 = *(const float4*)&As[k][rg * 8 + 4];
      float4 bv = *(const float4*)&Bs[k][cg * 4];
      float a[8] = {a0.x, a0.y, a0.z, a0.w, a1.x, a1.y, a1.z, a1.w};
      float bb[4] = {bv.x, bv.y, bv.z, bv.w};
      #pragma unroll
      for (int i = 0; i < 8; ++i)
        #pragma unroll
        for (int j = 0; j < 4; ++j)
          acc[i][j] = fmaf(a[i], bb[j], acc[i][j]);
    }
    __syncthreads();
  }
  #pragma unroll
  for (int i = 0; i < 8; ++i) {
    int gr = row0 + rg * 8 + i;
    if (gr < M) {
      uint2 o;
      o.x = (u32)f2bf(acc[i][0]) | ((u32)f2bf(acc[i][1]) << 16);
      o.y = (u32)f2bf(acc[i][2]) | ((u32)f2bf(acc[i][3]) << 16);
      *(uint2*)(C + (size_t)gr * Nc + col0 + cg * 4) = o;
    }
  }
}

// ---------------- attention logits ----------------
__global__ __launch_bounds__(256) void k_alpha1(const u16* __restrict__ h1,
                                                const float* __restrict__ a_src,
                                                const float* __restrict__ a_dst,
                                                float* __restrict__ as_o,
                                                float* __restrict__ ad_o) {
  int wid = threadIdx.x >> 6, lane = threadIdx.x & 63;
  int n = blockIdx.x * 4 + wid;
  if (n >= N_NODES) return;
  float f[8];
  unpack8(*(const uint4*)(h1 + (size_t)n * 512 + lane * 8), f);
  float4 a0 = *(const float4*)(a_src + lane * 8);
  float4 a1 = *(const float4*)(a_src + lane * 8 + 4);
  float4 d0 = *(const float4*)(a_dst + lane * 8);
  float4 d1 = *(const float4*)(a_dst + lane * 8 + 4);
  float fa[8] = {a0.x, a0.y, a0.z, a0.w, a1.x, a1.y, a1.z, a1.w};
  float fd[8] = {d0.x, d0.y, d0.z, d0.w, d1.x, d1.y, d1.z, d1.w};
  float s = 0.f, d = 0.f;
  #pragma unroll
  for (int j = 0; j < 8; ++j) { s = fmaf(f[j], fa[j], s); d = fmaf(f[j], fd[j], d); }
  #pragma unroll
  for (int off = 8; off >= 1; off >>= 1) {   // reduce within 16-lane head groups
    s += __shfl_xor(s, off, 64);
    d += __shfl_xor(d, off, 64);
  }
  if ((lane & 15) == 0) {
    int h = lane >> 4;
    as_o[n * 4 + h] = s;
    ad_o[n * 4 + h] = d;
  }
}

__global__ __launch_bounds__(256) void k_alpha2(const u16* __restrict__ h2,
                                                const float* __restrict__ a_src,
                                                const float* __restrict__ a_dst,
                                                float* __restrict__ as_o,
                                                float* __restrict__ ad_o) {
  int wid = threadIdx.x >> 6, lane = threadIdx.x & 63;
  int n = blockIdx.x * 4 + wid;
  if (n >= N_NODES) return;
  uint2 u = *(const uint2*)(h2 + (size_t)n * 256 + lane * 4);
  float f[4];
  f[0] = bf2f((u16)u.x); f[1] = bf2f((u16)(u.x >> 16));
  f[2] = bf2f((u16)u.y); f[3] = bf2f((u16)(u.y >> 16));
  float4 av = *(const float4*)(a_src + lane * 4);
  float4 dv = *(const float4*)(a_dst + lane * 4);
  float fa[4] = {av.x, av.y, av.z, av.w};
  float fd[4] = {dv.x, dv.y, dv.z, dv.w};
  float s = 0.f, d = 0.f;
  #pragma unroll
  for (int j = 0; j < 4; ++j) { s = fmaf(f[j], fa[j], s); d = fmaf(f[j], fd[j], d); }
  #pragma unroll
  for (int off = 32; off >= 1; off >>= 1) {
    s += __shfl_xor(s, off, 64);
    d += __shfl_xor(d, off, 64);
  }
  if (lane == 0) { as_o[n] = s; ad_o[n] = d; }
}

// ---------------- layer-1 aggregation (4 heads x 128 ch) + b1 + ELU ----
// 256 threads, 2 channels/thread (uint gather = 4B/lane).
__global__ __launch_bounds__(256) void k_agg1(const int* __restrict__ row_off,
                                              const int* __restrict__ srcs,
                                              const u16* __restrict__ h1,
                                              const float* __restrict__ as1,
                                              const float* __restrict__ ad1,
                                              const float* __restrict__ b1f,
                                              u16* __restrict__ x2) {
  int n = blockIdx.x, tid = threadIdx.x;
  int start = row_off[n], end = row_off[n + 1];
  __shared__ float m_sh[4], invd_sh[4];
  int wid = tid >> 6, lane = tid & 63;
  {                                   // per-head softmax stats, one wave/head
    int h = wid;
    float adn = ad1[n * 4 + h];
    float mx = -1e30f;
    for (int e = start + lane; e < end; e += 64) {
      float v = as1[srcs[e] * 4 + h] + adn;
      v = v >= 0.f ? v : 0.2f * v;
      mx = fmaxf(mx, v);
    }
    #pragma unroll
    for (int off = 32; off >= 1; off >>= 1) mx = fmaxf(mx, __shfl_xor(mx, off, 64));
    float sum = 0.f;
    for (int e = start + lane; e < end; e += 64) {
      float v = as1[srcs[e] * 4 + h] + adn;
      v = v >= 0.f ? v : 0.2f * v;
      sum += __expf(v - mx);
    }
    #pragma unroll
    for (int off = 32; off >= 1; off >>= 1) sum += __shfl_xor(sum, off, 64);
    if (lane == 0) { m_sh[h] = mx; invd_sh[h] = 1.0f / (sum + 1e-16f); }
  }
  __syncthreads();
  int h = tid >> 6;                            // channels 2*tid, 2*tid+1
  float adn = ad1[n * 4 + h];
  float m = m_sh[h], invd = invd_sh[h];
  float acc0 = 0.f, acc1 = 0.f;
  for (int e = start; e < end; ++e) {
    int s = srcs[e];
    float v = as1[s * 4 + h] + adn;
    v = v >= 0.f ? v : 0.2f * v;
    float wgt = __expf(v - m) * invd;
    u32 u = *(const u32*)(h1 + (size_t)s * 512 + tid * 2);
    acc0 = fmaf(wgt, bf2f((u16)u), acc0);
    acc1 = fmaf(wgt, bf2f((u16)(u >> 16)), acc1);
  }
  float v0 = acc0 + b1f[tid * 2];
  float v1 = acc1 + b1f[tid * 2 + 1];
  v0 = v0 > 0.f ? v0 : (__expf(v0) - 1.0f);    // ELU
  v1 = v1 > 0.f ? v1 : (__expf(v1) - 1.0f);
  *(u32*)(x2 + (size_t)n * 512 + tid * 2) = (u32)f2bf(v0) | ((u32)f2bf(v1) << 16);
}

// ---------------- layer-2 aggregation (1 head x 256 ch) + b2 ----------
__global__ __launch_bounds__(256) void k_agg2(const int* __restrict__ row_off,
                                              const int* __restrict__ srcs,
                                              const u16* __restrict__ h2,
                                              const float* __restrict__ as2,
                                              const float* __restrict__ ad2,
                                              const float* __restrict__ b2f,
                                              float* __restrict__ out2) {
  int n = blockIdx.x, tid = threadIdx.x;
  int start = row_off[n], end = row_off[n + 1];
  __shared__ float sh_m, sh_invd;
  if (tid < 64) {
    float adn = ad2[n];
    float mx = -1e30f;
    for (int e = start + tid; e < end; e += 64) {
      float v = as2[srcs[e]] + adn;
      v = v >= 0.f ? v : 0.2f * v;
      mx = fmaxf(mx, v);
    }
    #pragma unroll
    for (int off = 32; off >= 1; off >>= 1) mx = fmaxf(mx, __shfl_xor(mx, off, 64));
    float sum = 0.f;
    for (int e = start + tid; e < end; e += 64) {
      float v = as2[srcs[e]] + adn;
      v = v >= 0.f ? v : 0.2f * v;
      sum += __expf(v - mx);
    }
    #pragma unroll
    for (int off = 32; off >= 1; off >>= 1) sum += __shfl_xor(sum, off, 64);
    if (tid == 0) { sh_m = mx; sh_invd = 1.0f / (sum + 1e-16f); }
  }
  __syncthreads();
  float adn = ad2[n];
  float m = sh_m, invd = sh_invd;
  float acc = 0.f;
  for (int e = start; e < end; ++e) {
    int s = srcs[e];
    float v = as2[s] + adn;
    v = v >= 0.f ? v : 0.2f * v;
    float wgt = __expf(v - m) * invd;
    acc = fmaf(wgt, bf2f(h2[(size_t)s * 256 + tid]), acc);
  }
  out2[(size_t)n * 256 + tid] = acc + b2f[tid];
}

// ---------------- global mean + broadcast ----------------
__global__ __launch_bounds__(256) void k_reduce(const float* __restrict__ out2,
                                                float* __restrict__ g) {
  int c = threadIdx.x;
  float acc = 0.f;
  for (int n = blockIdx.x; n < N_NODES; n += 256)
    acc += out2[(size_t)n * 256 + c];
  atomicAdd(&g[c], acc);
}

__global__ void k_final(const float* __restrict__ g, float* __restrict__ out,
                        int out_size) {
  int i = blockIdx.x * 256 + threadIdx.x;
  if (i < out_size) out[i] = g[i & 255] * (1.0f / (float)N_NODES);  // fp32 output
}

// ---------------- launch ----------------
extern "C" void kernel_launch(void* const* d_in, const int* in_sizes, int n_in,
                              void* d_out, int out_size, void* d_ws, size_t ws_size,
                              hipStream_t stream) {
  (void)in_sizes; (void)n_in; (void)ws_size;
  const int* edge_index = (const int*)d_in[0];
  float* out = (float*)d_out;   // reference output dtype is float32

  char* w = (char*)d_ws;
  size_t off = 0;
  auto alloc = [&](size_t bytes) -> void* {
    void* p = w + off;
    off += (bytes + 255) & ~(size_t)255;
    return p;
  };
  float* ne_f    = (float*)alloc((size_t)N_NODES * 64 * 4);   // 12.8 MB
  float* W1_f    = (float*)alloc(32768 * 4);
  float* W2_f    = (float*)alloc(131072 * 4);
  float* as1v    = (float*)alloc(512 * 4);
  float* ad1v    = (float*)alloc(512 * 4);
  float* b1f     = (float*)alloc(512 * 4);
  float* as2v    = (float*)alloc(256 * 4);
  float* ad2v    = (float*)alloc(256 * 4);
  float* b2f     = (float*)alloc(256 * 4);
  u16*   h1      = (u16*)  alloc((size_t)N_NODES * 512 * 2);  // 51.2 MB (reused as h2)
  u16*   x2      = (u16*)  alloc((size_t)N_NODES * 512 * 2);  // 51.2 MB (reused as out2 fp32)
  float* as1     = (float*)alloc((size_t)N_NODES * 4 * 4);
  float* ad1     = (float*)alloc((size_t)N_NODES * 4 * 4);
  float* as2     = (float*)alloc((size_t)N_NODES * 4);
  float* ad2     = (float*)alloc((size_t)N_NODES * 4);
  int*   row_off = (int*)  alloc((size_t)(N_NODES + 1) * 4);
  int*   cursor  = (int*)  alloc((size_t)N_NODES * 4);
  int*   deg     = (int*)  alloc((size_t)N_NODES * 4);
  int*   srcs    = (int*)  alloc((size_t)ET * 4);
  int*   btot    = (int*)  alloc(64 * 4);
  int*   bbase   = (int*)  alloc(64 * 4);
  float* g       = (float*)alloc(256 * 4);
  int*   flag    = (int*)  alloc(64 * 4);
  u16*   h2   = h1;           // h1 dead after k_agg1
  float* out2 = (float*)x2;   // x2 dead after GEMM2 (both 51.2 MB)

  hipMemsetAsync(deg, 0, (size_t)N_NODES * 4, stream);
  hipMemsetAsync(g, 0, 256 * 4, stream);

  // dtype detect + canonicalize all float params to fp32
  k_detect<<<1, 64, 0, stream>>>((const u16*)d_in[2], flag);
  auto cvt = [&](const void* src, float* dst, int n) {
    k_convert<<<(n + 255) / 256, 256, 0, stream>>>(src, dst, n, flag);
  };
  cvt(d_in[2], ne_f, N_NODES * 64);
  cvt(d_in[3], W1_f, 32768);
  cvt(d_in[4], as1v, 512);
  cvt(d_in[5], ad1v, 512);
  cvt(d_in[6], b1f, 512);
  cvt(d_in[7], W2_f, 131072);
  cvt(d_in[8], as2v, 256);
  cvt(d_in[9], ad2v, 256);
  cvt(d_in[10], b2f, 256);

  // CSR by dst (incl. self-loops)
  k_degree <<<(ET + 255) / 256, 256, 0, stream>>>(edge_index, deg);
  k_partial<<<49, 1024, 0, stream>>>(deg, row_off, btot);
  k_bases  <<<1, 64, 0, stream>>>(btot, bbase, row_off, 49);
  k_add    <<<49, 1024, 0, stream>>>(row_off, cursor, bbase);
  k_scatter<<<(ET + 255) / 256, 256, 0, stream>>>(edge_index, cursor, srcs);

  // layer 1
  dim3 g1((N_NODES + 63) / 64, 4);
  k_gemm<false><<<g1, 256, 0, stream>>>(ne_f, W1_f, h1, N_NODES, 64, 512);
  k_alpha1<<<(N_NODES + 3) / 4, 256, 0, stream>>>(h1, as1v, ad1v, as1, ad1);
  k_agg1  <<<N_NODES, 256, 0, stream>>>(row_off, srcs, h1, as1, ad1, b1f, x2);

  // layer 2
  dim3 g2((N_NODES + 63) / 64, 2);
  k_gemm<true><<<g2, 256, 0, stream>>>(x2, W2_f, h2, N_NODES, 512, 256);
  k_alpha2<<<(N_NODES + 3) / 4, 256, 0, stream>>>(h2, as2v, ad2v, as2, ad2);
  k_agg2  <<<N_NODES, 256, 0, stream>>>(row_off, srcs, h2, as2, ad2, b2f, out2);

  // mean over nodes, broadcast to [batch, 256]
  k_reduce<<<256, 256, 0, stream>>>(out2, g);
  k_final <<<(out_size + 255) / 256, 256, 0, stream>>>(g, out, out_size);
}

// Round 4
// 626.889 us; speedup vs baseline: 1.3126x; 1.3126x over previous
//
#include <hip/hip_runtime.h>
#include <cstdint>

#define N_NODES 50000
#define N_EDGES 500000
#define ET (N_NODES + N_EDGES)   /* 550000 edges incl. self-loops */

typedef unsigned short u16;
typedef unsigned int   u32;
typedef __attribute__((ext_vector_type(8))) short short8;   // 8 bf16 (4 VGPRs)
typedef __attribute__((ext_vector_type(4))) float f32x4;

__device__ __forceinline__ float bf2f(u16 s) { return __uint_as_float((u32)s << 16); }
__device__ __forceinline__ u16 f2bf(float f) {          // round-to-nearest-even
  u32 u = __float_as_uint(f);
  u32 r = (u + 0x7FFFu + ((u >> 16) & 1u)) >> 16;
  return (u16)r;
}
__device__ __forceinline__ void unpack8(uint4 u, float* f) {  // 8 bf16 -> fp32
  f[0] = __uint_as_float(u.x << 16); f[1] = __uint_as_float(u.x & 0xffff0000u);
  f[2] = __uint_as_float(u.y << 16); f[3] = __uint_as_float(u.y & 0xffff0000u);
  f[4] = __uint_as_float(u.z << 16); f[5] = __uint_as_float(u.z & 0xffff0000u);
  f[6] = __uint_as_float(u.w << 16); f[7] = __uint_as_float(u.w & 0xffff0000u);
}

// ---------------- dtype detect + canonicalize ----------------
__global__ void k_detect(const u16* __restrict__ ne, int* __restrict__ flag) {
  int lane = threadIdx.x;  // 64 threads, one wave
  int bad = 0;
  #pragma unroll
  for (int j = 0; j < 2; ++j) {
    float v = fabsf(bf2f(ne[lane * 2 + j * 128]));  // even positions only
    bad += (!(v < 16.0f)) ? 1 : 0;                  // catches NaN too
  }
  #pragma unroll
  for (int off = 32; off >= 1; off >>= 1) bad += __shfl_xor(bad, off, 64);
  if (lane == 0) flag[0] = (bad > 16) ? 1 : 0;      // 1 => inputs are fp32
}

__global__ void k_convert(const void* __restrict__ src, float* __restrict__ dst,
                          int n, const int* __restrict__ flag) {
  int i = blockIdx.x * 256 + threadIdx.x;
  if (i >= n) return;
  if (flag[0]) dst[i] = ((const float*)src)[i];
  else         dst[i] = bf2f(((const u16*)src)[i]);
}

__global__ void k_cvt_bf16(const void* __restrict__ src, u16* __restrict__ dst,
                           int n, const int* __restrict__ flag) {
  int i = blockIdx.x * 256 + threadIdx.x;
  if (i >= n) return;
  if (flag[0]) dst[i] = f2bf(((const float*)src)[i]);
  else         dst[i] = ((const u16*)src)[i];
}

// W [K][N] -> Wt [N][K] bf16 (for MFMA B-operand staging)
__global__ void k_cvt_w_t(const void* __restrict__ src, u16* __restrict__ dst,
                          int K, int N, const int* __restrict__ flag) {
  int i = blockIdx.x * 256 + threadIdx.x;
  if (i >= K * N) return;
  int n = i / K, k = i - n * K;
  u16 v;
  if (flag[0]) v = f2bf(((const float*)src)[k * N + n]);
  else         v = ((const u16*)src)[k * N + n];
  dst[i] = v;
}

// ---------------- CSR build (dst-sorted) ----------------
__global__ void k_degree(const int* __restrict__ ei, int* __restrict__ deg) {
  int e = blockIdx.x * 256 + threadIdx.x;
  if (e >= ET) return;
  int d = (e < N_EDGES) ? ei[N_EDGES + e] : (e - N_EDGES);
  atomicAdd(&deg[d], 1);
}

__global__ __launch_bounds__(1024) void k_partial(const int* __restrict__ deg,
                                                  int* __restrict__ excl,
                                                  int* __restrict__ btot) {
  __shared__ int wsum[16];
  int tid = threadIdx.x;
  int i = blockIdx.x * 1024 + tid;
  int v = (i < N_NODES) ? deg[i] : 0;
  int lane = tid & 63, wid = tid >> 6;
  int incl = v;
  #pragma unroll
  for (int off = 1; off < 64; off <<= 1) {
    int t = __shfl_up(incl, off, 64);
    if (lane >= off) incl += t;
  }
  if (lane == 63) wsum[wid] = incl;
  __syncthreads();
  int prefix = 0;
  for (int w = 0; w < wid; ++w) prefix += wsum[w];
  if (i < N_NODES) excl[i] = prefix + incl - v;
  if (tid == 1023) btot[blockIdx.x] = prefix + incl;
}

__global__ void k_bases(const int* __restrict__ btot, int* __restrict__ bbase,
                        int* __restrict__ row_off, int nb) {
  int lane = threadIdx.x;  // 64 threads, single wave
  int v = (lane < nb) ? btot[lane] : 0;
  int incl = v;
  #pragma unroll
  for (int off = 1; off < 64; off <<= 1) {
    int t = __shfl_up(incl, off, 64);
    if (lane >= off) incl += t;
  }
  if (lane < nb) bbase[lane] = incl - v;
  if (lane == 0) row_off[N_NODES] = ET;
}

__global__ __launch_bounds__(1024) void k_add(int* __restrict__ row_off,
                                              int* __restrict__ cursor,
                                              const int* __restrict__ bbase) {
  int i = blockIdx.x * 1024 + threadIdx.x;
  if (i < N_NODES) {
    int r = row_off[i] + bbase[blockIdx.x];
    row_off[i] = r;
    cursor[i] = r;
  }
}

__global__ void k_scatter(const int* __restrict__ ei, int* __restrict__ cursor,
                          int* __restrict__ srcs) {
  int e = blockIdx.x * 256 + threadIdx.x;
  if (e >= ET) return;
  int s, d;
  if (e < N_EDGES) { s = ei[e]; d = ei[N_EDGES + e]; }
  else { s = d = e - N_EDGES; }
  int pos = atomicAdd(&cursor[d], 1);
  srcs[pos] = s;
}

// ---------------- MFMA GEMM: C[M,Nc](bf16) = A[M,K](bf16) * Bt[Nc,K](bf16)^T
// 128x128 tile, BK=32, 256 threads = 4 waves (2x2 of 64x64), fp32 acc.
// LDS rows padded to 40 u16 (80 B): max 2-way bank aliasing (free, m136).
#define LSTR 40
__global__ __launch_bounds__(256) void k_gemm_mfma(const u16* __restrict__ A,
                                                   const u16* __restrict__ Bt,
                                                   u16* __restrict__ C,
                                                   int M, int K, int Nc) {
  __shared__ __align__(16) u16 As[128 * LSTR];
  __shared__ __align__(16) u16 Bs[128 * LSTR];
  const int tid = threadIdx.x;
  const int lane = tid & 63, wid = tid >> 6;
  const int wr = (wid >> 1) * 64, wc = (wid & 1) * 64;
  const int m = lane & 15, q = lane >> 4;     // frag row/col + k-quad
  const int row0 = blockIdx.x * 128, col0 = blockIdx.y * 128;
  f32x4 acc[4][4] = {};
  for (int kk = 0; kk < K; kk += 32) {
    #pragma unroll
    for (int i = 0; i < 2; ++i) {             // stage A 128x32
      int v = tid + i * 256;
      int row = v >> 2, ch = (v & 3) * 8;
      uint4 u = make_uint4(0, 0, 0, 0);
      int gr = row0 + row;
      if (gr < M) u = *(const uint4*)(A + (size_t)gr * K + kk + ch);
      *(uint4*)(As + row * LSTR + ch) = u;
    }
    #pragma unroll
    for (int i = 0; i < 2; ++i) {             // stage Bt 128x32
      int v = tid + i * 256;
      int row = v >> 2, ch = (v & 3) * 8;
      uint4 u = *(const uint4*)(Bt + (size_t)(col0 + row) * K + kk + ch);
      *(uint4*)(Bs + row * LSTR + ch) = u;
    }
    __syncthreads();
    short8 af[4], bf[4];
    #pragma unroll
    for (int t = 0; t < 4; ++t) {
      af[t] = *(const short8*)(As + (wr + t * 16 + m) * LSTR + q * 8);
      bf[t] = *(const short8*)(Bs + (wc + t * 16 + m) * LSTR + q * 8);
    }
    #pragma unroll
    for (int mt = 0; mt < 4; ++mt)
      #pragma unroll
      for (int nt = 0; nt < 4; ++nt)
        acc[mt][nt] = __builtin_amdgcn_mfma_f32_16x16x32_bf16(
            af[mt], bf[nt], acc[mt][nt], 0, 0, 0);
    __syncthreads();
  }
  // C/D layout: col = lane&15, row = (lane>>4)*4 + reg  [m89/m91 verified]
  #pragma unroll
  for (int mt = 0; mt < 4; ++mt) {
    int grb = row0 + wr + mt * 16 + q * 4;
    #pragma unroll
    for (int nt = 0; nt < 4; ++nt) {
      int gc = col0 + wc + nt * 16 + m;
      #pragma unroll
      for (int r = 0; r < 4; ++r) {
        int gr = grb + r;
        if (gr < M) C[(size_t)gr * Nc + gc] = f2bf(acc[mt][nt][r]);
      }
    }
  }
}

// ---------------- attention logits ----------------
__global__ __launch_bounds__(256) void k_alpha1(const u16* __restrict__ h1,
                                                const float* __restrict__ a_src,
                                                const float* __restrict__ a_dst,
                                                float* __restrict__ as_o,
                                                float* __restrict__ ad_o) {
  int wid = threadIdx.x >> 6, lane = threadIdx.x & 63;
  int n = blockIdx.x * 4 + wid;
  if (n >= N_NODES) return;
  float f[8];
  unpack8(*(const uint4*)(h1 + (size_t)n * 512 + lane * 8), f);
  float4 a0 = *(const float4*)(a_src + lane * 8);
  float4 a1 = *(const float4*)(a_src + lane * 8 + 4);
  float4 d0 = *(const float4*)(a_dst + lane * 8);
  float4 d1 = *(const float4*)(a_dst + lane * 8 + 4);
  float fa[8] = {a0.x, a0.y, a0.z, a0.w, a1.x, a1.y, a1.z, a1.w};
  float fd[8] = {d0.x, d0.y, d0.z, d0.w, d1.x, d1.y, d1.z, d1.w};
  float s = 0.f, d = 0.f;
  #pragma unroll
  for (int j = 0; j < 8; ++j) { s = fmaf(f[j], fa[j], s); d = fmaf(f[j], fd[j], d); }
  #pragma unroll
  for (int off = 8; off >= 1; off >>= 1) {   // reduce within 16-lane head groups
    s += __shfl_xor(s, off, 64);
    d += __shfl_xor(d, off, 64);
  }
  if ((lane & 15) == 0) {
    int h = lane >> 4;
    as_o[n * 4 + h] = s;
    ad_o[n * 4 + h] = d;
  }
}

__global__ __launch_bounds__(256) void k_alpha2(const u16* __restrict__ h2,
                                                const float* __restrict__ a_src,
                                                const float* __restrict__ a_dst,
                                                float* __restrict__ as_o,
                                                float* __restrict__ ad_o) {
  int wid = threadIdx.x >> 6, lane = threadIdx.x & 63;
  int n = blockIdx.x * 4 + wid;
  if (n >= N_NODES) return;
  uint2 u = *(const uint2*)(h2 + (size_t)n * 256 + lane * 4);
  float f[4];
  f[0] = bf2f((u16)u.x); f[1] = bf2f((u16)(u.x >> 16));
  f[2] = bf2f((u16)u.y); f[3] = bf2f((u16)(u.y >> 16));
  float4 av = *(const float4*)(a_src + lane * 4);
  float4 dv = *(const float4*)(a_dst + lane * 4);
  float fa[4] = {av.x, av.y, av.z, av.w};
  float fd[4] = {dv.x, dv.y, dv.z, dv.w};
  float s = 0.f, d = 0.f;
  #pragma unroll
  for (int j = 0; j < 4; ++j) { s = fmaf(f[j], fa[j], s); d = fmaf(f[j], fd[j], d); }
  #pragma unroll
  for (int off = 32; off >= 1; off >>= 1) {
    s += __shfl_xor(s, off, 64);
    d += __shfl_xor(d, off, 64);
  }
  if (lane == 0) { as_o[n] = s; ad_o[n] = d; }
}

// ---------------- layer-1 aggregation (4 heads x 128 ch) + b1 + ELU ----
__global__ __launch_bounds__(256) void k_agg1(const int* __restrict__ row_off,
                                              const int* __restrict__ srcs,
                                              const u16* __restrict__ h1,
                                              const float* __restrict__ as1,
                                              const float* __restrict__ ad1,
                                              const float* __restrict__ b1f,
                                              u16* __restrict__ x2) {
  int n = blockIdx.x, tid = threadIdx.x;
  int start = row_off[n], end = row_off[n + 1];
  __shared__ float m_sh[4], invd_sh[4];
  int wid = tid >> 6, lane = tid & 63;
  {                                   // per-head softmax stats, one wave/head
    int h = wid;
    float adn = ad1[n * 4 + h];
    float mx = -1e30f;
    for (int e = start + lane; e < end; e += 64) {
      float v = as1[srcs[e] * 4 + h] + adn;
      v = v >= 0.f ? v : 0.2f * v;
      mx = fmaxf(mx, v);
    }
    #pragma unroll
    for (int off = 32; off >= 1; off >>= 1) mx = fmaxf(mx, __shfl_xor(mx, off, 64));
    float sum = 0.f;
    for (int e = start + lane; e < end; e += 64) {
      float v = as1[srcs[e] * 4 + h] + adn;
      v = v >= 0.f ? v : 0.2f * v;
      sum += __expf(v - mx);
    }
    #pragma unroll
    for (int off = 32; off >= 1; off >>= 1) sum += __shfl_xor(sum, off, 64);
    if (lane == 0) { m_sh[h] = mx; invd_sh[h] = 1.0f / (sum + 1e-16f); }
  }
  __syncthreads();
  int h = tid >> 6;                            // channels 2*tid, 2*tid+1
  float adn = ad1[n * 4 + h];
  float m = m_sh[h], invd = invd_sh[h];
  float acc0 = 0.f, acc1 = 0.f;
  for (int e = start; e < end; ++e) {
    int s = srcs[e];
    float v = as1[s * 4 + h] + adn;
    v = v >= 0.f ? v : 0.2f * v;
    float wgt = __expf(v - m) * invd;
    u32 u = *(const u32*)(h1 + (size_t)s * 512 + tid * 2);
    acc0 = fmaf(wgt, bf2f((u16)u), acc0);
    acc1 = fmaf(wgt, bf2f((u16)(u >> 16)), acc1);
  }
  float v0 = acc0 + b1f[tid * 2];
  float v1 = acc1 + b1f[tid * 2 + 1];
  v0 = v0 > 0.f ? v0 : (__expf(v0) - 1.0f);    // ELU
  v1 = v1 > 0.f ? v1 : (__expf(v1) - 1.0f);
  *(u32*)(x2 + (size_t)n * 512 + tid * 2) = (u32)f2bf(v0) | ((u32)f2bf(v1) << 16);
}

// ---------------- layer-2 aggregation (1 head x 256 ch) + b2 ----------
__global__ __launch_bounds__(256) void k_agg2(const int* __restrict__ row_off,
                                              const int* __restrict__ srcs,
                                              const u16* __restrict__ h2,
                                              const float* __restrict__ as2,
                                              const float* __restrict__ ad2,
                                              const float* __restrict__ b2f,
                                              float* __restrict__ out2) {
  int n = blockIdx.x, tid = threadIdx.x;
  int start = row_off[n], end = row_off[n + 1];
  __shared__ float sh_m, sh_invd;
  if (tid < 64) {
    float adn = ad2[n];
    float mx = -1e30f;
    for (int e = start + tid; e < end; e += 64) {
      float v = as2[srcs[e]] + adn;
      v = v >= 0.f ? v : 0.2f * v;
      mx = fmaxf(mx, v);
    }
    #pragma unroll
    for (int off = 32; off >= 1; off >>= 1) mx = fmaxf(mx, __shfl_xor(mx, off, 64));
    float sum = 0.f;
    for (int e = start + tid; e < end; e += 64) {
      float v = as2[srcs[e]] + adn;
      v = v >= 0.f ? v : 0.2f * v;
      sum += __expf(v - mx);
    }
    #pragma unroll
    for (int off = 32; off >= 1; off >>= 1) sum += __shfl_xor(sum, off, 64);
    if (tid == 0) { sh_m = mx; sh_invd = 1.0f / (sum + 1e-16f); }
  }
  __syncthreads();
  float adn = ad2[n];
  float m = sh_m, invd = sh_invd;
  float acc = 0.f;
  for (int e = start; e < end; ++e) {
    int s = srcs[e];
    float v = as2[s] + adn;
    v = v >= 0.f ? v : 0.2f * v;
    float wgt = __expf(v - m) * invd;
    acc = fmaf(wgt, bf2f(h2[(size_t)s * 256 + tid]), acc);
  }
  out2[(size_t)n * 256 + tid] = acc + b2f[tid];
}

// ---------------- global mean + broadcast ----------------
__global__ __launch_bounds__(256) void k_reduce(const float* __restrict__ out2,
                                                float* __restrict__ g) {
  int c = threadIdx.x;
  float acc = 0.f;
  for (int n = blockIdx.x; n < N_NODES; n += 256)
    acc += out2[(size_t)n * 256 + c];
  atomicAdd(&g[c], acc);
}

__global__ void k_final(const float* __restrict__ g, float* __restrict__ out,
                        int out_size) {
  int i = blockIdx.x * 256 + threadIdx.x;
  if (i < out_size) out[i] = g[i & 255] * (1.0f / (float)N_NODES);  // fp32 output
}

// ---------------- launch ----------------
extern "C" void kernel_launch(void* const* d_in, const int* in_sizes, int n_in,
                              void* d_out, int out_size, void* d_ws, size_t ws_size,
                              hipStream_t stream) {
  (void)in_sizes; (void)n_in; (void)ws_size;
  const int* edge_index = (const int*)d_in[0];
  float* out = (float*)d_out;   // reference output dtype is float32

  char* w = (char*)d_ws;
  size_t off = 0;
  auto alloc = [&](size_t bytes) -> void* {
    void* p = w + off;
    off += (bytes + 255) & ~(size_t)255;
    return p;
  };
  u16*   ne_b    = (u16*)  alloc((size_t)N_NODES * 64 * 2);   // 6.4 MB bf16
  u16*   W1t     = (u16*)  alloc(32768 * 2);                  // [512][64]
  u16*   W2t     = (u16*)  alloc(131072 * 2);                 // [256][512]
  float* as1v    = (float*)alloc(512 * 4);
  float* ad1v    = (float*)alloc(512 * 4);
  float* b1f     = (float*)alloc(512 * 4);
  float* as2v    = (float*)alloc(256 * 4);
  float* ad2v    = (float*)alloc(256 * 4);
  float* b2f     = (float*)alloc(256 * 4);
  u16*   h1      = (u16*)  alloc((size_t)N_NODES * 512 * 2);  // 51.2 MB (reused as h2)
  u16*   x2      = (u16*)  alloc((size_t)N_NODES * 512 * 2);  // 51.2 MB (reused as out2 fp32)
  float* as1     = (float*)alloc((size_t)N_NODES * 4 * 4);
  float* ad1     = (float*)alloc((size_t)N_NODES * 4 * 4);
  float* as2     = (float*)alloc((size_t)N_NODES * 4);
  float* ad2     = (float*)alloc((size_t)N_NODES * 4);
  int*   row_off = (int*)  alloc((size_t)(N_NODES + 1) * 4);
  int*   cursor  = (int*)  alloc((size_t)N_NODES * 4);
  int*   deg     = (int*)  alloc((size_t)N_NODES * 4);
  int*   srcs    = (int*)  alloc((size_t)ET * 4);
  int*   btot    = (int*)  alloc(64 * 4);
  int*   bbase   = (int*)  alloc(64 * 4);
  float* g       = (float*)alloc(256 * 4);
  int*   flag    = (int*)  alloc(64 * 4);
  u16*   h2   = h1;           // h1 dead after k_agg1
  float* out2 = (float*)x2;   // x2 dead after GEMM2 (both 51.2 MB)

  hipMemsetAsync(deg, 0, (size_t)N_NODES * 4, stream);
  hipMemsetAsync(g, 0, 256 * 4, stream);

  // dtype detect + canonicalize (weights -> transposed bf16 for MFMA B-operand)
  k_detect<<<1, 64, 0, stream>>>((const u16*)d_in[2], flag);
  auto cvtf = [&](const void* src, float* dst, int n) {
    k_convert<<<(n + 255) / 256, 256, 0, stream>>>(src, dst, n, flag);
  };
  k_cvt_bf16<<<(N_NODES * 64 + 255) / 256, 256, 0, stream>>>(d_in[2], ne_b,
                                                             N_NODES * 64, flag);
  k_cvt_w_t<<<(32768 + 255) / 256, 256, 0, stream>>>(d_in[3], W1t, 64, 512, flag);
  k_cvt_w_t<<<(131072 + 255) / 256, 256, 0, stream>>>(d_in[7], W2t, 512, 256, flag);
  cvtf(d_in[4], as1v, 512);
  cvtf(d_in[5], ad1v, 512);
  cvtf(d_in[6], b1f, 512);
  cvtf(d_in[8], as2v, 256);
  cvtf(d_in[9], ad2v, 256);
  cvtf(d_in[10], b2f, 256);

  // CSR by dst (incl. self-loops)
  k_degree <<<(ET + 255) / 256, 256, 0, stream>>>(edge_index, deg);
  k_partial<<<49, 1024, 0, stream>>>(deg, row_off, btot);
  k_bases  <<<1, 64, 0, stream>>>(btot, bbase, row_off, 49);
  k_add    <<<49, 1024, 0, stream>>>(row_off, cursor, bbase);
  k_scatter<<<(ET + 255) / 256, 256, 0, stream>>>(edge_index, cursor, srcs);

  // layer 1 (MFMA GEMM: h1 = ne_b @ W1)
  dim3 g1((N_NODES + 127) / 128, 4);
  k_gemm_mfma<<<g1, 256, 0, stream>>>(ne_b, W1t, h1, N_NODES, 64, 512);
  k_alpha1<<<(N_NODES + 3) / 4, 256, 0, stream>>>(h1, as1v, ad1v, as1, ad1);
  k_agg1  <<<N_NODES, 256, 0, stream>>>(row_off, srcs, h1, as1, ad1, b1f, x2);

  // layer 2 (MFMA GEMM: h2 = x2 @ W2)
  dim3 g2((N_NODES + 127) / 128, 2);
  k_gemm_mfma<<<g2, 256, 0, stream>>>(x2, W2t, h2, N_NODES, 512, 256);
  k_alpha2<<<(N_NODES + 3) / 4, 256, 0, stream>>>(h2, as2v, ad2v, as2, ad2);
  k_agg2  <<<N_NODES, 256, 0, stream>>>(row_off, srcs, h2, as2, ad2, b2f, out2);

  // mean over nodes, broadcast to [batch, 256]
  k_reduce<<<256, 256, 0, stream>>>(out2, g);
  k_final <<<(out_size + 255) / 256, 256, 0, stream>>>(g, out, out_size);
}

// Round 5
// 504.863 us; speedup vs baseline: 1.6299x; 1.2417x over previous
//
#include <hip/hip_runtime.h>
#include <cstdint>

#define N_NODES 50000
#define N_EDGES 500000
#define ET (N_NODES + N_EDGES)   /* 550000 edges incl. self-loops */

typedef unsigned short u16;
typedef unsigned int   u32;
typedef __attribute__((ext_vector_type(8))) short short8;   // 8 bf16 (4 VGPRs)
typedef __attribute__((ext_vector_type(4))) float f32x4;

__device__ __forceinline__ float bf2f(u16 s) { return __uint_as_float((u32)s << 16); }
__device__ __forceinline__ u16 f2bf(float f) {          // round-to-nearest-even
  u32 u = __float_as_uint(f);
  u32 r = (u + 0x7FFFu + ((u >> 16) & 1u)) >> 16;
  return (u16)r;
}
__device__ __forceinline__ void unpack8(uint4 u, float* f) {  // 8 bf16 -> fp32
  f[0] = __uint_as_float(u.x << 16); f[1] = __uint_as_float(u.x & 0xffff0000u);
  f[2] = __uint_as_float(u.y << 16); f[3] = __uint_as_float(u.y & 0xffff0000u);
  f[4] = __uint_as_float(u.z << 16); f[5] = __uint_as_float(u.z & 0xffff0000u);
  f[6] = __uint_as_float(u.w << 16); f[7] = __uint_as_float(u.w & 0xffff0000u);
}
__device__ __forceinline__ float lrelu(float v) { return v >= 0.f ? v : 0.2f * v; }

// ---------------- dtype detect + canonicalize ----------------
__global__ void k_detect(const u16* __restrict__ ne, int* __restrict__ flag) {
  int lane = threadIdx.x;  // 64 threads, one wave
  int bad = 0;
  #pragma unroll
  for (int j = 0; j < 2; ++j) {
    float v = fabsf(bf2f(ne[lane * 2 + j * 128]));  // even positions only
    bad += (!(v < 16.0f)) ? 1 : 0;                  // catches NaN too
  }
  #pragma unroll
  for (int off = 32; off >= 1; off >>= 1) bad += __shfl_xor(bad, off, 64);
  if (lane == 0) flag[0] = (bad > 16) ? 1 : 0;      // 1 => inputs are fp32
}

__global__ void k_convert(const void* __restrict__ src, float* __restrict__ dst,
                          int n, const int* __restrict__ flag) {
  int i = blockIdx.x * 256 + threadIdx.x;
  if (i >= n) return;
  if (flag[0]) dst[i] = ((const float*)src)[i];
  else         dst[i] = bf2f(((const u16*)src)[i]);
}

__global__ void k_cvt_bf16(const void* __restrict__ src, u16* __restrict__ dst,
                           int n, const int* __restrict__ flag) {
  int i = blockIdx.x * 256 + threadIdx.x;
  if (i >= n) return;
  if (flag[0]) dst[i] = f2bf(((const float*)src)[i]);
  else         dst[i] = ((const u16*)src)[i];
}

// W [K][N] -> Wt [N][K] bf16 (for MFMA B-operand staging)
__global__ void k_cvt_w_t(const void* __restrict__ src, u16* __restrict__ dst,
                          int K, int N, const int* __restrict__ flag) {
  int i = blockIdx.x * 256 + threadIdx.x;
  if (i >= K * N) return;
  int n = i / K, k = i - n * K;
  u16 v;
  if (flag[0]) v = f2bf(((const float*)src)[k * N + n]);
  else         v = ((const u16*)src)[k * N + n];
  dst[i] = v;
}

// ---------------- CSR build (dst-sorted) ----------------
__global__ void k_degree(const int* __restrict__ ei, int* __restrict__ deg) {
  int e = blockIdx.x * 256 + threadIdx.x;
  if (e >= ET) return;
  int d = (e < N_EDGES) ? ei[N_EDGES + e] : (e - N_EDGES);
  atomicAdd(&deg[d], 1);
}

__global__ __launch_bounds__(1024) void k_partial(const int* __restrict__ deg,
                                                  int* __restrict__ excl,
                                                  int* __restrict__ btot) {
  __shared__ int wsum[16];
  int tid = threadIdx.x;
  int i = blockIdx.x * 1024 + tid;
  int v = (i < N_NODES) ? deg[i] : 0;
  int lane = tid & 63, wid = tid >> 6;
  int incl = v;
  #pragma unroll
  for (int off = 1; off < 64; off <<= 1) {
    int t = __shfl_up(incl, off, 64);
    if (lane >= off) incl += t;
  }
  if (lane == 63) wsum[wid] = incl;
  __syncthreads();
  int prefix = 0;
  for (int w = 0; w < wid; ++w) prefix += wsum[w];
  if (i < N_NODES) excl[i] = prefix + incl - v;
  if (tid == 1023) btot[blockIdx.x] = prefix + incl;
}

__global__ void k_bases(const int* __restrict__ btot, int* __restrict__ bbase,
                        int* __restrict__ row_off, int nb) {
  int lane = threadIdx.x;  // 64 threads, single wave
  int v = (lane < nb) ? btot[lane] : 0;
  int incl = v;
  #pragma unroll
  for (int off = 1; off < 64; off <<= 1) {
    int t = __shfl_up(incl, off, 64);
    if (lane >= off) incl += t;
  }
  if (lane < nb) bbase[lane] = incl - v;
  if (lane == 0) row_off[N_NODES] = ET;
}

__global__ __launch_bounds__(1024) void k_add(int* __restrict__ row_off,
                                              int* __restrict__ cursor,
                                              const int* __restrict__ bbase) {
  int i = blockIdx.x * 1024 + threadIdx.x;
  if (i < N_NODES) {
    int r = row_off[i] + bbase[blockIdx.x];
    row_off[i] = r;
    cursor[i] = r;
  }
}

__global__ void k_scatter(const int* __restrict__ ei, int* __restrict__ cursor,
                          int* __restrict__ srcs, int* __restrict__ dsts) {
  int e = blockIdx.x * 256 + threadIdx.x;
  if (e >= ET) return;
  int s, d;
  if (e < N_EDGES) { s = ei[e]; d = ei[N_EDGES + e]; }
  else { s = d = e - N_EDGES; }
  int pos = atomicAdd(&cursor[d], 1);
  srcs[pos] = s;
  dsts[pos] = d;
}

// ---------------- MFMA GEMM: C[M,Nc](bf16) = A[M,K](bf16) * Bt[Nc,K](bf16)^T
// 128x128 tile, BK=32, 256 threads = 4 waves (2x2 of 64x64), fp32 acc.
#define LSTR 40
__global__ __launch_bounds__(256) void k_gemm_mfma(const u16* __restrict__ A,
                                                   const u16* __restrict__ Bt,
                                                   u16* __restrict__ C,
                                                   int M, int K, int Nc) {
  __shared__ __align__(16) u16 As[128 * LSTR];
  __shared__ __align__(16) u16 Bs[128 * LSTR];
  const int tid = threadIdx.x;
  const int lane = tid & 63, wid = tid >> 6;
  const int wr = (wid >> 1) * 64, wc = (wid & 1) * 64;
  const int m = lane & 15, q = lane >> 4;     // frag row/col + k-quad
  const int row0 = blockIdx.x * 128, col0 = blockIdx.y * 128;
  f32x4 acc[4][4] = {};
  for (int kk = 0; kk < K; kk += 32) {
    #pragma unroll
    for (int i = 0; i < 2; ++i) {             // stage A 128x32
      int v = tid + i * 256;
      int row = v >> 2, ch = (v & 3) * 8;
      uint4 u = make_uint4(0, 0, 0, 0);
      int gr = row0 + row;
      if (gr < M) u = *(const uint4*)(A + (size_t)gr * K + kk + ch);
      *(uint4*)(As + row * LSTR + ch) = u;
    }
    #pragma unroll
    for (int i = 0; i < 2; ++i) {             // stage Bt 128x32
      int v = tid + i * 256;
      int row = v >> 2, ch = (v & 3) * 8;
      uint4 u = *(const uint4*)(Bt + (size_t)(col0 + row) * K + kk + ch);
      *(uint4*)(Bs + row * LSTR + ch) = u;
    }
    __syncthreads();
    short8 af[4], bfr[4];
    #pragma unroll
    for (int t = 0; t < 4; ++t) {
      af[t]  = *(const short8*)(As + (wr + t * 16 + m) * LSTR + q * 8);
      bfr[t] = *(const short8*)(Bs + (wc + t * 16 + m) * LSTR + q * 8);
    }
    #pragma unroll
    for (int mt = 0; mt < 4; ++mt)
      #pragma unroll
      for (int nt = 0; nt < 4; ++nt)
        acc[mt][nt] = __builtin_amdgcn_mfma_f32_16x16x32_bf16(
            af[mt], bfr[nt], acc[mt][nt], 0, 0, 0);
    __syncthreads();
  }
  // C/D layout: col = lane&15, row = (lane>>4)*4 + reg  [m89/m91 verified]
  #pragma unroll
  for (int mt = 0; mt < 4; ++mt) {
    int grb = row0 + wr + mt * 16 + q * 4;
    #pragma unroll
    for (int nt = 0; nt < 4; ++nt) {
      int gc = col0 + wc + nt * 16 + m;
      #pragma unroll
      for (int r = 0; r < 4; ++r) {
        int gr = grb + r;
        if (gr < M) C[(size_t)gr * Nc + gc] = f2bf(acc[mt][nt][r]);
      }
    }
  }
}

// ---------------- attention logits ----------------
__global__ __launch_bounds__(256) void k_alpha1(const u16* __restrict__ h1,
                                                const float* __restrict__ a_src,
                                                const float* __restrict__ a_dst,
                                                float* __restrict__ as_o,
                                                float* __restrict__ ad_o) {
  int wid = threadIdx.x >> 6, lane = threadIdx.x & 63;
  int n = blockIdx.x * 4 + wid;
  if (n >= N_NODES) return;
  float f[8];
  unpack8(*(const uint4*)(h1 + (size_t)n * 512 + lane * 8), f);
  float4 a0 = *(const float4*)(a_src + lane * 8);
  float4 a1 = *(const float4*)(a_src + lane * 8 + 4);
  float4 d0 = *(const float4*)(a_dst + lane * 8);
  float4 d1 = *(const float4*)(a_dst + lane * 8 + 4);
  float fa[8] = {a0.x, a0.y, a0.z, a0.w, a1.x, a1.y, a1.z, a1.w};
  float fd[8] = {d0.x, d0.y, d0.z, d0.w, d1.x, d1.y, d1.z, d1.w};
  float s = 0.f, d = 0.f;
  #pragma unroll
  for (int j = 0; j < 8; ++j) { s = fmaf(f[j], fa[j], s); d = fmaf(f[j], fd[j], d); }
  #pragma unroll
  for (int off = 8; off >= 1; off >>= 1) {   // reduce within 16-lane head groups
    s += __shfl_xor(s, off, 64);
    d += __shfl_xor(d, off, 64);
  }
  if ((lane & 15) == 0) {
    int h = lane >> 4;
    as_o[n * 4 + h] = s;
    ad_o[n * 4 + h] = d;
  }
}

__global__ __launch_bounds__(256) void k_alpha2(const u16* __restrict__ h2,
                                                const float* __restrict__ a_src,
                                                const float* __restrict__ a_dst,
                                                float* __restrict__ as_o,
                                                float* __restrict__ ad_o) {
  int wid = threadIdx.x >> 6, lane = threadIdx.x & 63;
  int n = blockIdx.x * 4 + wid;
  if (n >= N_NODES) return;
  uint2 u = *(const uint2*)(h2 + (size_t)n * 256 + lane * 4);
  float f[4];
  f[0] = bf2f((u16)u.x); f[1] = bf2f((u16)(u.x >> 16));
  f[2] = bf2f((u16)u.y); f[3] = bf2f((u16)(u.y >> 16));
  float4 av = *(const float4*)(a_src + lane * 4);
  float4 dv = *(const float4*)(a_dst + lane * 4);
  float fa[4] = {av.x, av.y, av.z, av.w};
  float fd[4] = {dv.x, dv.y, dv.z, dv.w};
  float s = 0.f, d = 0.f;
  #pragma unroll
  for (int j = 0; j < 4; ++j) { s = fmaf(f[j], fa[j], s); d = fmaf(f[j], fd[j], d); }
  #pragma unroll
  for (int off = 32; off >= 1; off >>= 1) {
    s += __shfl_xor(s, off, 64);
    d += __shfl_xor(d, off, 64);
  }
  if (lane == 0) { as_o[n] = s; ad_o[n] = d; }
}

// ---------------- softmax stats (per node) ----------------
// layer 1: one wave per node, 16-lane group per head
__global__ __launch_bounds__(256) void k_stats1(const int* __restrict__ row_off,
                                                const int* __restrict__ srcs,
                                                const float* __restrict__ as1,
                                                const float* __restrict__ ad1,
                                                float* __restrict__ m1,
                                                float* __restrict__ i1) {
  int wid = threadIdx.x >> 6, lane = threadIdx.x & 63;
  int n = blockIdx.x * 4 + wid;
  if (n >= N_NODES) return;
  int g = lane >> 4, il = lane & 15;
  int start = row_off[n], end = row_off[n + 1];
  float adn = ad1[n * 4 + g];
  float mx = -1e30f;
  for (int e = start + il; e < end; e += 16)
    mx = fmaxf(mx, lrelu(as1[srcs[e] * 4 + g] + adn));
  #pragma unroll
  for (int off = 8; off >= 1; off >>= 1) mx = fmaxf(mx, __shfl_xor(mx, off, 64));
  float sum = 0.f;
  for (int e = start + il; e < end; e += 16)
    sum += __expf(lrelu(as1[srcs[e] * 4 + g] + adn) - mx);
  #pragma unroll
  for (int off = 8; off >= 1; off >>= 1) sum += __shfl_xor(sum, off, 64);
  if (il == 0) { m1[n * 4 + g] = mx; i1[n * 4 + g] = 1.0f / (sum + 1e-16f); }
}

// layer 2: one wave per node
__global__ __launch_bounds__(256) void k_stats2(const int* __restrict__ row_off,
                                                const int* __restrict__ srcs,
                                                const float* __restrict__ as2,
                                                const float* __restrict__ ad2,
                                                float* __restrict__ m2,
                                                float* __restrict__ i2) {
  int wid = threadIdx.x >> 6, lane = threadIdx.x & 63;
  int n = blockIdx.x * 4 + wid;
  if (n >= N_NODES) return;
  int start = row_off[n], end = row_off[n + 1];
  float adn = ad2[n];
  float mx = -1e30f;
  for (int e = start + lane; e < end; e += 64)
    mx = fmaxf(mx, lrelu(as2[srcs[e]] + adn));
  #pragma unroll
  for (int off = 32; off >= 1; off >>= 1) mx = fmaxf(mx, __shfl_xor(mx, off, 64));
  float sum = 0.f;
  for (int e = start + lane; e < end; e += 64)
    sum += __expf(lrelu(as2[srcs[e]] + adn) - mx);
  #pragma unroll
  for (int off = 32; off >= 1; off >>= 1) sum += __shfl_xor(sum, off, 64);
  if (lane == 0) { m2[n] = mx; i2[n] = 1.0f / (sum + 1e-16f); }
}

// ---------------- per-edge softmax weights (edge-parallel) ----------------
__global__ void k_edgew1(const int* __restrict__ srcs, const int* __restrict__ dsts,
                         const float* __restrict__ as1, const float* __restrict__ ad1,
                         const float* __restrict__ m1, const float* __restrict__ i1,
                         float* __restrict__ w1) {
  int e = blockIdx.x * 256 + threadIdx.x;
  if (e >= ET) return;
  int s = srcs[e], d = dsts[e];
  float4 a  = *(const float4*)(as1 + s * 4);
  float4 b  = *(const float4*)(ad1 + d * 4);
  float4 m  = *(const float4*)(m1 + d * 4);
  float4 iv = *(const float4*)(i1 + d * 4);
  float4 w;
  w.x = __expf(lrelu(a.x + b.x) - m.x) * iv.x;
  w.y = __expf(lrelu(a.y + b.y) - m.y) * iv.y;
  w.z = __expf(lrelu(a.z + b.z) - m.z) * iv.z;
  w.w = __expf(lrelu(a.w + b.w) - m.w) * iv.w;
  *(float4*)(w1 + (size_t)e * 4) = w;
}

__global__ void k_edgew2(const int* __restrict__ srcs, const int* __restrict__ dsts,
                         const float* __restrict__ as2, const float* __restrict__ ad2,
                         const float* __restrict__ m2, const float* __restrict__ i2,
                         float* __restrict__ w2) {
  int e = blockIdx.x * 256 + threadIdx.x;
  if (e >= ET) return;
  int s = srcs[e], d = dsts[e];
  w2[e] = __expf(lrelu(as2[s] + ad2[d]) - m2[d]) * i2[d];
}

// ---------------- layer-1 aggregation: wave covers 512 ch, 1/4 of edges ----
__global__ __launch_bounds__(256) void k_agg1(const int* __restrict__ row_off,
                                              const int* __restrict__ srcs,
                                              const u16* __restrict__ h1,
                                              const float* __restrict__ w1,
                                              const float* __restrict__ b1f,
                                              u16* __restrict__ x2) {
  __shared__ float part[4 * 512];
  int n = blockIdx.x, tid = threadIdx.x;
  int wid = tid >> 6, lane = tid & 63;
  int start = row_off[n], end = row_off[n + 1];
  int g = lane >> 4;                     // head of this lane's 8 channels
  float acc[8] = {};
  for (int e = start + wid; e < end; e += 4) {
    int s = srcs[e];
    float wgt = w1[(size_t)e * 4 + g];
    uint4 u = *(const uint4*)(h1 + (size_t)s * 512 + lane * 8);
    float f[8];
    unpack8(u, f);
    #pragma unroll
    for (int j = 0; j < 8; ++j) acc[j] = fmaf(wgt, f[j], acc[j]);
  }
  *(float4*)&part[wid * 512 + lane * 8]     = make_float4(acc[0], acc[1], acc[2], acc[3]);
  *(float4*)&part[wid * 512 + lane * 8 + 4] = make_float4(acc[4], acc[5], acc[6], acc[7]);
  __syncthreads();
  int c0 = tid * 2;
  float s0 = part[c0]     + part[512 + c0]     + part[1024 + c0]     + part[1536 + c0];
  float s1 = part[c0 + 1] + part[512 + c0 + 1] + part[1024 + c0 + 1] + part[1536 + c0 + 1];
  s0 += b1f[c0];
  s1 += b1f[c0 + 1];
  s0 = s0 > 0.f ? s0 : (__expf(s0) - 1.0f);    // ELU
  s1 = s1 > 0.f ? s1 : (__expf(s1) - 1.0f);
  *(u32*)(x2 + (size_t)n * 512 + c0) = (u32)f2bf(s0) | ((u32)f2bf(s1) << 16);
}

// ---------------- layer-2 aggregation: wave covers 256 ch, 1/4 of edges ----
__global__ __launch_bounds__(256) void k_agg2(const int* __restrict__ row_off,
                                              const int* __restrict__ srcs,
                                              const u16* __restrict__ h2,
                                              const float* __restrict__ w2,
                                              const float* __restrict__ b2f,
                                              float* __restrict__ out2) {
  __shared__ float part[4 * 256];
  int n = blockIdx.x, tid = threadIdx.x;
  int wid = tid >> 6, lane = tid & 63;
  int start = row_off[n], end = row_off[n + 1];
  float acc[4] = {};
  for (int e = start + wid; e < end; e += 4) {
    int s = srcs[e];
    float wgt = w2[e];
    uint2 u = *(const uint2*)(h2 + (size_t)s * 256 + lane * 4);
    acc[0] = fmaf(wgt, bf2f((u16)u.x), acc[0]);
    acc[1] = fmaf(wgt, bf2f((u16)(u.x >> 16)), acc[1]);
    acc[2] = fmaf(wgt, bf2f((u16)u.y), acc[2]);
    acc[3] = fmaf(wgt, bf2f((u16)(u.y >> 16)), acc[3]);
  }
  *(float4*)&part[wid * 256 + lane * 4] = make_float4(acc[0], acc[1], acc[2], acc[3]);
  __syncthreads();
  float s0 = part[tid] + part[256 + tid] + part[512 + tid] + part[768 + tid];
  out2[(size_t)n * 256 + tid] = s0 + b2f[tid];
}

// ---------------- global mean + broadcast ----------------
__global__ __launch_bounds__(256) void k_reduce(const float* __restrict__ out2,
                                                float* __restrict__ g) {
  int c = threadIdx.x;
  float acc = 0.f;
  for (int n = blockIdx.x; n < N_NODES; n += 256)
    acc += out2[(size_t)n * 256 + c];
  atomicAdd(&g[c], acc);
}

__global__ void k_final(const float* __restrict__ g, float* __restrict__ out,
                        int out_size) {
  int i = blockIdx.x * 256 + threadIdx.x;
  if (i < out_size) out[i] = g[i & 255] * (1.0f / (float)N_NODES);  // fp32 output
}

// ---------------- launch ----------------
extern "C" void kernel_launch(void* const* d_in, const int* in_sizes, int n_in,
                              void* d_out, int out_size, void* d_ws, size_t ws_size,
                              hipStream_t stream) {
  (void)in_sizes; (void)n_in; (void)ws_size;
  const int* edge_index = (const int*)d_in[0];
  float* out = (float*)d_out;   // reference output dtype is float32

  char* w = (char*)d_ws;
  size_t off = 0;
  auto alloc = [&](size_t bytes) -> void* {
    void* p = w + off;
    off += (bytes + 255) & ~(size_t)255;
    return p;
  };
  u16*   ne_b    = (u16*)  alloc((size_t)N_NODES * 64 * 2);   // 6.4 MB bf16
  u16*   W1t     = (u16*)  alloc(32768 * 2);                  // [512][64]
  u16*   W2t     = (u16*)  alloc(131072 * 2);                 // [256][512]
  float* as1v    = (float*)alloc(512 * 4);
  float* ad1v    = (float*)alloc(512 * 4);
  float* b1f     = (float*)alloc(512 * 4);
  float* as2v    = (float*)alloc(256 * 4);
  float* ad2v    = (float*)alloc(256 * 4);
  float* b2f     = (float*)alloc(256 * 4);
  u16*   h1      = (u16*)  alloc((size_t)N_NODES * 512 * 2);  // 51.2 MB (reused as h2)
  u16*   x2      = (u16*)  alloc((size_t)N_NODES * 512 * 2);  // 51.2 MB (reused as out2 fp32)
  float* as1     = (float*)alloc((size_t)N_NODES * 4 * 4);
  float* ad1     = (float*)alloc((size_t)N_NODES * 4 * 4);
  float* as2     = (float*)alloc((size_t)N_NODES * 4);
  float* ad2     = (float*)alloc((size_t)N_NODES * 4);
  float* m1      = (float*)alloc((size_t)N_NODES * 4 * 4);
  float* i1      = (float*)alloc((size_t)N_NODES * 4 * 4);
  float* m2      = (float*)alloc((size_t)N_NODES * 4);
  float* i2      = (float*)alloc((size_t)N_NODES * 4);
  float* w1      = (float*)alloc((size_t)ET * 4 * 4);         // 8.8 MB
  float* w2      = (float*)alloc((size_t)ET * 4);             // 2.2 MB
  int*   row_off = (int*)  alloc((size_t)(N_NODES + 1) * 4);
  int*   cursor  = (int*)  alloc((size_t)N_NODES * 4);
  int*   deg     = (int*)  alloc((size_t)N_NODES * 4);
  int*   srcs    = (int*)  alloc((size_t)ET * 4);
  int*   dsts    = (int*)  alloc((size_t)ET * 4);
  int*   btot    = (int*)  alloc(64 * 4);
  int*   bbase   = (int*)  alloc(64 * 4);
  float* g       = (float*)alloc(256 * 4);
  int*   flag    = (int*)  alloc(64 * 4);
  u16*   h2   = h1;           // h1 dead after k_agg1
  float* out2 = (float*)x2;   // x2 dead after GEMM2 (both 51.2 MB)

  hipMemsetAsync(deg, 0, (size_t)N_NODES * 4, stream);
  hipMemsetAsync(g, 0, 256 * 4, stream);

  // dtype detect + canonicalize (weights -> transposed bf16 for MFMA B-operand)
  k_detect<<<1, 64, 0, stream>>>((const u16*)d_in[2], flag);
  auto cvtf = [&](const void* src, float* dst, int n) {
    k_convert<<<(n + 255) / 256, 256, 0, stream>>>(src, dst, n, flag);
  };
  k_cvt_bf16<<<(N_NODES * 64 + 255) / 256, 256, 0, stream>>>(d_in[2], ne_b,
                                                             N_NODES * 64, flag);
  k_cvt_w_t<<<(32768 + 255) / 256, 256, 0, stream>>>(d_in[3], W1t, 64, 512, flag);
  k_cvt_w_t<<<(131072 + 255) / 256, 256, 0, stream>>>(d_in[7], W2t, 512, 256, flag);
  cvtf(d_in[4], as1v, 512);
  cvtf(d_in[5], ad1v, 512);
  cvtf(d_in[6], b1f, 512);
  cvtf(d_in[8], as2v, 256);
  cvtf(d_in[9], ad2v, 256);
  cvtf(d_in[10], b2f, 256);

  // CSR by dst (incl. self-loops)
  k_degree <<<(ET + 255) / 256, 256, 0, stream>>>(edge_index, deg);
  k_partial<<<49, 1024, 0, stream>>>(deg, row_off, btot);
  k_bases  <<<1, 64, 0, stream>>>(btot, bbase, row_off, 49);
  k_add    <<<49, 1024, 0, stream>>>(row_off, cursor, bbase);
  k_scatter<<<(ET + 255) / 256, 256, 0, stream>>>(edge_index, cursor, srcs, dsts);

  // layer 1
  dim3 g1((N_NODES + 127) / 128, 4);
  k_gemm_mfma<<<g1, 256, 0, stream>>>(ne_b, W1t, h1, N_NODES, 64, 512);
  k_alpha1<<<(N_NODES + 3) / 4, 256, 0, stream>>>(h1, as1v, ad1v, as1, ad1);
  k_stats1<<<(N_NODES + 3) / 4, 256, 0, stream>>>(row_off, srcs, as1, ad1, m1, i1);
  k_edgew1<<<(ET + 255) / 256, 256, 0, stream>>>(srcs, dsts, as1, ad1, m1, i1, w1);
  k_agg1  <<<N_NODES, 256, 0, stream>>>(row_off, srcs, h1, w1, b1f, x2);

  // layer 2
  dim3 g2((N_NODES + 127) / 128, 2);
  k_gemm_mfma<<<g2, 256, 0, stream>>>(x2, W2t, h2, N_NODES, 512, 256);
  k_alpha2<<<(N_NODES + 3) / 4, 256, 0, stream>>>(h2, as2v, ad2v, as2, ad2);
  k_stats2<<<(N_NODES + 3) / 4, 256, 0, stream>>>(row_off, srcs, as2, ad2, m2, i2);
  k_edgew2<<<(ET + 255) / 256, 256, 0, stream>>>(srcs, dsts, as2, ad2, m2, i2, w2);
  k_agg2  <<<N_NODES, 256, 0, stream>>>(row_off, srcs, h2, w2, b2f, out2);

  // mean over nodes, broadcast to [batch, 256]
  k_reduce<<<256, 256, 0, stream>>>(out2, g);
  k_final <<<(out_size + 255) / 256, 256, 0, stream>>>(g, out, out_size);
}

// Round 6
// 501.672 us; speedup vs baseline: 1.6402x; 1.0064x over previous
//
#include <hip/hip_runtime.h>
#include <cstdint>

#define N_NODES 50000
#define N_EDGES 500000
#define ET (N_NODES + N_EDGES)   /* 550000 edges incl. self-loops */

typedef unsigned short u16;
typedef unsigned int   u32;
typedef __attribute__((ext_vector_type(8))) short short8;   // 8 bf16 (4 VGPRs)
typedef __attribute__((ext_vector_type(4))) float f32x4;

__device__ __forceinline__ float bf2f(u16 s) { return __uint_as_float((u32)s << 16); }
__device__ __forceinline__ u16 f2bf(float f) {          // round-to-nearest-even
  u32 u = __float_as_uint(f);
  u32 r = (u + 0x7FFFu + ((u >> 16) & 1u)) >> 16;
  return (u16)r;
}
__device__ __forceinline__ float lrelu(float v) { return v >= 0.f ? v : 0.2f * v; }

// ---------------- dtype detect + canonicalize ----------------
__global__ void k_detect(const u16* __restrict__ ne, int* __restrict__ flag) {
  int lane = threadIdx.x;  // 64 threads, one wave
  int bad = 0;
  #pragma unroll
  for (int j = 0; j < 2; ++j) {
    float v = fabsf(bf2f(ne[lane * 2 + j * 128]));  // even positions only
    bad += (!(v < 16.0f)) ? 1 : 0;                  // catches NaN too
  }
  #pragma unroll
  for (int off = 32; off >= 1; off >>= 1) bad += __shfl_xor(bad, off, 64);
  if (lane == 0) flag[0] = (bad > 16) ? 1 : 0;      // 1 => inputs are fp32
}

__global__ void k_cvt_bf16(const void* __restrict__ src, u16* __restrict__ dst,
                           int n, const int* __restrict__ flag) {
  int i = blockIdx.x * 256 + threadIdx.x;
  if (i >= n) return;
  if (flag[0]) dst[i] = f2bf(((const float*)src)[i]);
  else         dst[i] = ((const u16*)src)[i];
}

// W [K][N] -> Wt [N][K] bf16 (for MFMA B-operand staging)
__global__ void k_cvt_w_t(const void* __restrict__ src, u16* __restrict__ dst,
                          int K, int N, const int* __restrict__ flag) {
  int i = blockIdx.x * 256 + threadIdx.x;
  if (i >= K * N) return;
  int n = i / K, k = i - n * K;
  u16 v;
  if (flag[0]) v = f2bf(((const float*)src)[k * N + n]);
  else         v = ((const u16*)src)[k * N + n];
  dst[i] = v;
}

// all 6 small fp32 param vectors in one launch (2304 elements total)
__global__ void k_cvt_params(const void* s0, const void* s1, const void* s2,
                             const void* s3, const void* s4, const void* s5,
                             float* d0, float* d1, float* d2,
                             float* d3, float* d4, float* d5,
                             const int* __restrict__ flag) {
  int i = blockIdx.x * 256 + threadIdx.x;
  const void* s; float* d; int j;
  if      (i < 512)  { s = s0; d = d0; j = i; }
  else if (i < 1024) { s = s1; d = d1; j = i - 512; }
  else if (i < 1536) { s = s2; d = d2; j = i - 1024; }
  else if (i < 1792) { s = s3; d = d3; j = i - 1536; }
  else if (i < 2048) { s = s4; d = d4; j = i - 1792; }
  else if (i < 2304) { s = s5; d = d5; j = i - 2048; }
  else return;
  if (flag[0]) d[j] = ((const float*)s)[j];
  else         d[j] = bf2f(((const u16*)s)[j]);
}

// ---------------- CSR build (dst-sorted) ----------------
__global__ void k_degree(const int* __restrict__ ei, int* __restrict__ deg) {
  int e = blockIdx.x * 256 + threadIdx.x;
  if (e >= ET) return;
  int d = (e < N_EDGES) ? ei[N_EDGES + e] : (e - N_EDGES);
  atomicAdd(&deg[d], 1);
}

__global__ __launch_bounds__(1024) void k_partial(const int* __restrict__ deg,
                                                  int* __restrict__ excl,
                                                  int* __restrict__ btot) {
  __shared__ int wsum[16];
  int tid = threadIdx.x;
  int i = blockIdx.x * 1024 + tid;
  int v = (i < N_NODES) ? deg[i] : 0;
  int lane = tid & 63, wid = tid >> 6;
  int incl = v;
  #pragma unroll
  for (int off = 1; off < 64; off <<= 1) {
    int t = __shfl_up(incl, off, 64);
    if (lane >= off) incl += t;
  }
  if (lane == 63) wsum[wid] = incl;
  __syncthreads();
  int prefix = 0;
  for (int w = 0; w < wid; ++w) prefix += wsum[w];
  if (i < N_NODES) excl[i] = prefix + incl - v;
  if (tid == 1023) btot[blockIdx.x] = prefix + incl;
}

__global__ void k_bases(const int* __restrict__ btot, int* __restrict__ bbase,
                        int* __restrict__ row_off, int nb) {
  int lane = threadIdx.x;  // 64 threads, single wave
  int v = (lane < nb) ? btot[lane] : 0;
  int incl = v;
  #pragma unroll
  for (int off = 1; off < 64; off <<= 1) {
    int t = __shfl_up(incl, off, 64);
    if (lane >= off) incl += t;
  }
  if (lane < nb) bbase[lane] = incl - v;
  if (lane == 0) row_off[N_NODES] = ET;
}

__global__ __launch_bounds__(1024) void k_add(int* __restrict__ row_off,
                                              int* __restrict__ cursor,
                                              const int* __restrict__ bbase) {
  int i = blockIdx.x * 1024 + threadIdx.x;
  if (i < N_NODES) {
    int r = row_off[i] + bbase[blockIdx.x];
    row_off[i] = r;
    cursor[i] = r;
  }
}

__global__ void k_scatter(const int* __restrict__ ei, int* __restrict__ cursor,
                          int* __restrict__ srcs, int* __restrict__ dsts) {
  int e = blockIdx.x * 256 + threadIdx.x;
  if (e >= ET) return;
  int s, d;
  if (e < N_EDGES) { s = ei[e]; d = ei[N_EDGES + e]; }
  else { s = d = e - N_EDGES; }
  int pos = atomicAdd(&cursor[d], 1);
  srcs[pos] = s;
  dsts[pos] = d;
}

// ---------------- MFMA GEMM (layer 2): C = A[M,K] * Bt[Nc,K]^T, bf16 ----
#define LSTR 40
__global__ __launch_bounds__(256) void k_gemm_mfma(const u16* __restrict__ A,
                                                   const u16* __restrict__ Bt,
                                                   u16* __restrict__ C,
                                                   int M, int K, int Nc) {
  __shared__ __align__(16) u16 As[128 * LSTR];
  __shared__ __align__(16) u16 Bs[128 * LSTR];
  const int tid = threadIdx.x;
  const int lane = tid & 63, wid = tid >> 6;
  const int wr = (wid >> 1) * 64, wc = (wid & 1) * 64;
  const int m = lane & 15, q = lane >> 4;     // frag row/col + k-quad
  const int row0 = blockIdx.x * 128, col0 = blockIdx.y * 128;
  f32x4 acc[4][4] = {};
  for (int kk = 0; kk < K; kk += 32) {
    #pragma unroll
    for (int i = 0; i < 2; ++i) {             // stage A 128x32
      int v = tid + i * 256;
      int row = v >> 2, ch = (v & 3) * 8;
      uint4 u = make_uint4(0, 0, 0, 0);
      int gr = row0 + row;
      if (gr < M) u = *(const uint4*)(A + (size_t)gr * K + kk + ch);
      *(uint4*)(As + row * LSTR + ch) = u;
    }
    #pragma unroll
    for (int i = 0; i < 2; ++i) {             // stage Bt 128x32
      int v = tid + i * 256;
      int row = v >> 2, ch = (v & 3) * 8;
      uint4 u = *(const uint4*)(Bt + (size_t)(col0 + row) * K + kk + ch);
      *(uint4*)(Bs + row * LSTR + ch) = u;
    }
    __syncthreads();
    short8 af[4], bfr[4];
    #pragma unroll
    for (int t = 0; t < 4; ++t) {
      af[t]  = *(const short8*)(As + (wr + t * 16 + m) * LSTR + q * 8);
      bfr[t] = *(const short8*)(Bs + (wc + t * 16 + m) * LSTR + q * 8);
    }
    #pragma unroll
    for (int mt = 0; mt < 4; ++mt)
      #pragma unroll
      for (int nt = 0; nt < 4; ++nt)
        acc[mt][nt] = __builtin_amdgcn_mfma_f32_16x16x32_bf16(
            af[mt], bfr[nt], acc[mt][nt], 0, 0, 0);
    __syncthreads();
  }
  #pragma unroll
  for (int mt = 0; mt < 4; ++mt) {
    int grb = row0 + wr + mt * 16 + q * 4;
    #pragma unroll
    for (int nt = 0; nt < 4; ++nt) {
      int gc = col0 + wc + nt * 16 + m;
      #pragma unroll
      for (int r = 0; r < 4; ++r) {
        int gr = grb + r;
        if (gr < M) C[(size_t)gr * Nc + gc] = f2bf(acc[mt][nt][r]);
      }
    }
  }
}

// ---------------- layer-1 GEMM on aggregated ne, fused bias+ELU ----
// x2[:, h*128 : h*128+128] = ELU(aggne[:, h*64 : h*64+64] @ W1t_h^T + b1_h)
__global__ __launch_bounds__(256) void k_gemm_l1(const u16* __restrict__ aggne,
                                                 const u16* __restrict__ W1t,
                                                 const float* __restrict__ b1f,
                                                 u16* __restrict__ x2, int M) {
  __shared__ __align__(16) u16 As[128 * LSTR];
  __shared__ __align__(16) u16 Bs[128 * LSTR];
  const int tid = threadIdx.x;
  const int lane = tid & 63, wid = tid >> 6;
  const int wr = (wid >> 1) * 64, wc = (wid & 1) * 64;
  const int m = lane & 15, q = lane >> 4;
  const int row0 = blockIdx.x * 128, head = blockIdx.y;
  const u16* Bt = W1t + (size_t)head * 128 * 64;   // [128 rows][64]
  f32x4 acc[4][4] = {};
  #pragma unroll
  for (int kk = 0; kk < 64; kk += 32) {
    #pragma unroll
    for (int i = 0; i < 2; ++i) {             // stage A 128x32 (lda=256)
      int v = tid + i * 256;
      int row = v >> 2, ch = (v & 3) * 8;
      uint4 u = make_uint4(0, 0, 0, 0);
      int gr = row0 + row;
      if (gr < M) u = *(const uint4*)(aggne + (size_t)gr * 256 + head * 64 + kk + ch);
      *(uint4*)(As + row * LSTR + ch) = u;
    }
    #pragma unroll
    for (int i = 0; i < 2; ++i) {             // stage Bt 128x32 (stride 64)
      int v = tid + i * 256;
      int row = v >> 2, ch = (v & 3) * 8;
      uint4 u = *(const uint4*)(Bt + (size_t)row * 64 + kk + ch);
      *(uint4*)(Bs + row * LSTR + ch) = u;
    }
    __syncthreads();
    short8 af[4], bfr[4];
    #pragma unroll
    for (int t = 0; t < 4; ++t) {
      af[t]  = *(const short8*)(As + (wr + t * 16 + m) * LSTR + q * 8);
      bfr[t] = *(const short8*)(Bs + (wc + t * 16 + m) * LSTR + q * 8);
    }
    #pragma unroll
    for (int mt = 0; mt < 4; ++mt)
      #pragma unroll
      for (int nt = 0; nt < 4; ++nt)
        acc[mt][nt] = __builtin_amdgcn_mfma_f32_16x16x32_bf16(
            af[mt], bfr[nt], acc[mt][nt], 0, 0, 0);
    __syncthreads();
  }
  #pragma unroll
  for (int mt = 0; mt < 4; ++mt) {
    int grb = row0 + wr + mt * 16 + q * 4;
    #pragma unroll
    for (int nt = 0; nt < 4; ++nt) {
      int lc = wc + nt * 16 + m;              // local col in [0,128)
      float bias = b1f[head * 128 + lc];
      #pragma unroll
      for (int r = 0; r < 4; ++r) {
        int gr = grb + r;
        if (gr < M) {
          float v = acc[mt][nt][r] + bias;
          v = v > 0.f ? v : (__expf(v) - 1.0f);   // ELU
          x2[(size_t)gr * 512 + head * 128 + lc] = f2bf(v);
        }
      }
    }
  }
}

// ---------------- va vectors: va[h][k] = sum_c a[h*128+c] * W1t[(h*128+c)][k]
__global__ void k_valpha(const u16* __restrict__ W1t,
                         const float* __restrict__ as1v, const float* __restrict__ ad1v,
                         float* __restrict__ va_s, float* __restrict__ va_d) {
  int t = threadIdx.x;           // 256 threads: h = t>>6, k = t&63
  int h = t >> 6, k = t & 63;
  float s = 0.f, d = 0.f;
  for (int c = 0; c < 128; ++c) {
    float w = bf2f(W1t[(size_t)(h * 128 + c) * 64 + k]);
    s = fmaf(as1v[h * 128 + c], w, s);
    d = fmaf(ad1v[h * 128 + c], w, d);
  }
  va_s[t] = s;
  va_d[t] = d;
}

// ---------------- layer-1 attention logits straight from ne ----------------
__global__ __launch_bounds__(256) void k_alpha1_ne(const u16* __restrict__ ne_b,
                                                   const float* __restrict__ va_s,
                                                   const float* __restrict__ va_d,
                                                   float* __restrict__ as_o,
                                                   float* __restrict__ ad_o) {
  int wid = threadIdx.x >> 6, lane = threadIdx.x & 63;
  int n = blockIdx.x * 4 + wid;
  if (n >= N_NODES) return;
  float v = bf2f(ne_b[(size_t)n * 64 + lane]);
  #pragma unroll
  for (int h = 0; h < 4; ++h) {
    float s = v * va_s[h * 64 + lane];
    float d = v * va_d[h * 64 + lane];
    #pragma unroll
    for (int off = 32; off >= 1; off >>= 1) {
      s += __shfl_xor(s, off, 64);
      d += __shfl_xor(d, off, 64);
    }
    if (lane == 0) { as_o[n * 4 + h] = s; ad_o[n * 4 + h] = d; }
  }
}

__global__ __launch_bounds__(256) void k_alpha2(const u16* __restrict__ h2,
                                                const float* __restrict__ a_src,
                                                const float* __restrict__ a_dst,
                                                float* __restrict__ as_o,
                                                float* __restrict__ ad_o) {
  int wid = threadIdx.x >> 6, lane = threadIdx.x & 63;
  int n = blockIdx.x * 4 + wid;
  if (n >= N_NODES) return;
  uint2 u = *(const uint2*)(h2 + (size_t)n * 256 + lane * 4);
  float f[4];
  f[0] = bf2f((u16)u.x); f[1] = bf2f((u16)(u.x >> 16));
  f[2] = bf2f((u16)u.y); f[3] = bf2f((u16)(u.y >> 16));
  float4 av = *(const float4*)(a_src + lane * 4);
  float4 dv = *(const float4*)(a_dst + lane * 4);
  float fa[4] = {av.x, av.y, av.z, av.w};
  float fd[4] = {dv.x, dv.y, dv.z, dv.w};
  float s = 0.f, d = 0.f;
  #pragma unroll
  for (int j = 0; j < 4; ++j) { s = fmaf(f[j], fa[j], s); d = fmaf(f[j], fd[j], d); }
  #pragma unroll
  for (int off = 32; off >= 1; off >>= 1) {
    s += __shfl_xor(s, off, 64);
    d += __shfl_xor(d, off, 64);
  }
  if (lane == 0) { as_o[n] = s; ad_o[n] = d; }
}

// ---------------- softmax stats (per node) ----------------
__global__ __launch_bounds__(256) void k_stats1(const int* __restrict__ row_off,
                                                const int* __restrict__ srcs,
                                                const float* __restrict__ as1,
                                                const float* __restrict__ ad1,
                                                float* __restrict__ m1,
                                                float* __restrict__ i1) {
  int wid = threadIdx.x >> 6, lane = threadIdx.x & 63;
  int n = blockIdx.x * 4 + wid;
  if (n >= N_NODES) return;
  int g = lane >> 4, il = lane & 15;
  int start = row_off[n], end = row_off[n + 1];
  float adn = ad1[n * 4 + g];
  float mx = -1e30f;
  for (int e = start + il; e < end; e += 16)
    mx = fmaxf(mx, lrelu(as1[srcs[e] * 4 + g] + adn));
  #pragma unroll
  for (int off = 8; off >= 1; off >>= 1) mx = fmaxf(mx, __shfl_xor(mx, off, 64));
  float sum = 0.f;
  for (int e = start + il; e < end; e += 16)
    sum += __expf(lrelu(as1[srcs[e] * 4 + g] + adn) - mx);
  #pragma unroll
  for (int off = 8; off >= 1; off >>= 1) sum += __shfl_xor(sum, off, 64);
  if (il == 0) { m1[n * 4 + g] = mx; i1[n * 4 + g] = 1.0f / (sum + 1e-16f); }
}

__global__ __launch_bounds__(256) void k_stats2(const int* __restrict__ row_off,
                                                const int* __restrict__ srcs,
                                                const float* __restrict__ as2,
                                                const float* __restrict__ ad2,
                                                float* __restrict__ m2,
                                                float* __restrict__ i2) {
  int wid = threadIdx.x >> 6, lane = threadIdx.x & 63;
  int n = blockIdx.x * 4 + wid;
  if (n >= N_NODES) return;
  int start = row_off[n], end = row_off[n + 1];
  float adn = ad2[n];
  float mx = -1e30f;
  for (int e = start + lane; e < end; e += 64)
    mx = fmaxf(mx, lrelu(as2[srcs[e]] + adn));
  #pragma unroll
  for (int off = 32; off >= 1; off >>= 1) mx = fmaxf(mx, __shfl_xor(mx, off, 64));
  float sum = 0.f;
  for (int e = start + lane; e < end; e += 64)
    sum += __expf(lrelu(as2[srcs[e]] + adn) - mx);
  #pragma unroll
  for (int off = 32; off >= 1; off >>= 1) sum += __shfl_xor(sum, off, 64);
  if (lane == 0) { m2[n] = mx; i2[n] = 1.0f / (sum + 1e-16f); }
}

// ---------------- per-edge softmax weights ----------------
__global__ void k_edgew1(const int* __restrict__ srcs, const int* __restrict__ dsts,
                         const float* __restrict__ as1, const float* __restrict__ ad1,
                         const float* __restrict__ m1, const float* __restrict__ i1,
                         float* __restrict__ w1) {
  int e = blockIdx.x * 256 + threadIdx.x;
  if (e >= ET) return;
  int s = srcs[e], d = dsts[e];
  float4 a  = *(const float4*)(as1 + s * 4);
  float4 b  = *(const float4*)(ad1 + d * 4);
  float4 m  = *(const float4*)(m1 + d * 4);
  float4 iv = *(const float4*)(i1 + d * 4);
  float4 w;
  w.x = __expf(lrelu(a.x + b.x) - m.x) * iv.x;
  w.y = __expf(lrelu(a.y + b.y) - m.y) * iv.y;
  w.z = __expf(lrelu(a.z + b.z) - m.z) * iv.z;
  w.w = __expf(lrelu(a.w + b.w) - m.w) * iv.w;
  *(float4*)(w1 + (size_t)e * 4) = w;
}

__global__ void k_edgew2(const int* __restrict__ srcs, const int* __restrict__ dsts,
                         const float* __restrict__ as2, const float* __restrict__ ad2,
                         const float* __restrict__ m2, const float* __restrict__ i2,
                         float* __restrict__ w2) {
  int e = blockIdx.x * 256 + threadIdx.x;
  if (e >= ET) return;
  int s = srcs[e], d = dsts[e];
  w2[e] = __expf(lrelu(as2[s] + ad2[d]) - m2[d]) * i2[d];
}

// ---------------- layer-1 aggregation over ne (64 ch x 4 heads) ----
// aggne[n][h*64+ch] = sum_e w1[e][h] * ne[src[e]][ch]
__global__ __launch_bounds__(256) void k_aggne(const int* __restrict__ row_off,
                                               const int* __restrict__ srcs,
                                               const u16* __restrict__ ne_b,
                                               const float* __restrict__ w1,
                                               u16* __restrict__ aggne) {
  __shared__ float part[4][256];
  int n = blockIdx.x, tid = threadIdx.x;
  int wid = tid >> 6, lane = tid & 63;
  int start = row_off[n], end = row_off[n + 1];
  int chp = (lane & 31) * 2;        // channel pair base
  int hb = (lane >> 5) * 2;         // head base: 0 or 2
  float a00 = 0.f, a01 = 0.f, a10 = 0.f, a11 = 0.f;
  for (int e = start + wid; e < end; e += 4) {
    int s = srcs[e];
    u32 u = *(const u32*)(ne_b + (size_t)s * 64 + chp);   // 128B/row, bcast halves
    float f0 = bf2f((u16)u), f1 = bf2f((u16)(u >> 16));
    float w0 = w1[(size_t)e * 4 + hb];
    float w1v = w1[(size_t)e * 4 + hb + 1];
    a00 = fmaf(w0, f0, a00); a01 = fmaf(w0, f1, a01);
    a10 = fmaf(w1v, f0, a10); a11 = fmaf(w1v, f1, a11);
  }
  part[wid][(hb + 0) * 64 + chp]     = a00;
  part[wid][(hb + 0) * 64 + chp + 1] = a01;
  part[wid][(hb + 1) * 64 + chp]     = a10;
  part[wid][(hb + 1) * 64 + chp + 1] = a11;
  __syncthreads();
  float sum = part[0][tid] + part[1][tid] + part[2][tid] + part[3][tid];
  aggne[(size_t)n * 256 + tid] = f2bf(sum);
}

// ---------------- layer-2 aggregation: wave covers 256 ch, 1/4 of edges ----
__global__ __launch_bounds__(256) void k_agg2(const int* __restrict__ row_off,
                                              const int* __restrict__ srcs,
                                              const u16* __restrict__ h2,
                                              const float* __restrict__ w2,
                                              const float* __restrict__ b2f,
                                              float* __restrict__ out2) {
  __shared__ float part[4 * 256];
  int n = blockIdx.x, tid = threadIdx.x;
  int wid = tid >> 6, lane = tid & 63;
  int start = row_off[n], end = row_off[n + 1];
  float acc[4] = {};
  for (int e = start + wid; e < end; e += 4) {
    int s = srcs[e];
    float wgt = w2[e];
    uint2 u = *(const uint2*)(h2 + (size_t)s * 256 + lane * 4);
    acc[0] = fmaf(wgt, bf2f((u16)u.x), acc[0]);
    acc[1] = fmaf(wgt, bf2f((u16)(u.x >> 16)), acc[1]);
    acc[2] = fmaf(wgt, bf2f((u16)u.y), acc[2]);
    acc[3] = fmaf(wgt, bf2f((u16)(u.y >> 16)), acc[3]);
  }
  *(float4*)&part[wid * 256 + lane * 4] = make_float4(acc[0], acc[1], acc[2], acc[3]);
  __syncthreads();
  float s0 = part[tid] + part[256 + tid] + part[512 + tid] + part[768 + tid];
  out2[(size_t)n * 256 + tid] = s0 + b2f[tid];
}

// ---------------- global mean + broadcast ----------------
__global__ __launch_bounds__(256) void k_reduce(const float* __restrict__ out2,
                                                float* __restrict__ g) {
  int c = threadIdx.x;
  float acc = 0.f;
  for (int n = blockIdx.x; n < N_NODES; n += 256)
    acc += out2[(size_t)n * 256 + c];
  atomicAdd(&g[c], acc);
}

__global__ void k_final(const float* __restrict__ g, float* __restrict__ out,
                        int out_size) {
  int i = blockIdx.x * 256 + threadIdx.x;
  if (i < out_size) out[i] = g[i & 255] * (1.0f / (float)N_NODES);
}

// ---------------- launch ----------------
extern "C" void kernel_launch(void* const* d_in, const int* in_sizes, int n_in,
                              void* d_out, int out_size, void* d_ws, size_t ws_size,
                              hipStream_t stream) {
  (void)in_sizes; (void)n_in; (void)ws_size;
  const int* edge_index = (const int*)d_in[0];
  float* out = (float*)d_out;   // reference output dtype is float32

  char* w = (char*)d_ws;
  size_t off = 0;
  auto alloc = [&](size_t bytes) -> void* {
    void* p = w + off;
    off += (bytes + 255) & ~(size_t)255;
    return p;
  };
  u16*   ne_b    = (u16*)  alloc((size_t)N_NODES * 64 * 2);   // 6.4 MB bf16
  u16*   W1t     = (u16*)  alloc(32768 * 2);                  // [512][64]
  u16*   W2t     = (u16*)  alloc(131072 * 2);                 // [256][512]
  float* as1v    = (float*)alloc(512 * 4);
  float* ad1v    = (float*)alloc(512 * 4);
  float* b1f     = (float*)alloc(512 * 4);
  float* as2v    = (float*)alloc(256 * 4);
  float* ad2v    = (float*)alloc(256 * 4);
  float* b2f     = (float*)alloc(256 * 4);
  float* va_s    = (float*)alloc(256 * 4);
  float* va_d    = (float*)alloc(256 * 4);
  u16*   aggne   = (u16*)  alloc((size_t)N_NODES * 256 * 2);  // 25.6 MB
  u16*   x2      = (u16*)  alloc((size_t)N_NODES * 512 * 2);  // 51.2 MB (reused as out2 fp32)
  u16*   h2      = (u16*)  alloc((size_t)N_NODES * 256 * 2);  // 25.6 MB
  float* as1     = (float*)alloc((size_t)N_NODES * 4 * 4);
  float* ad1     = (float*)alloc((size_t)N_NODES * 4 * 4);
  float* as2     = (float*)alloc((size_t)N_NODES * 4);
  float* ad2     = (float*)alloc((size_t)N_NODES * 4);
  float* m1      = (float*)alloc((size_t)N_NODES * 4 * 4);
  float* i1      = (float*)alloc((size_t)N_NODES * 4 * 4);
  float* m2      = (float*)alloc((size_t)N_NODES * 4);
  float* i2      = (float*)alloc((size_t)N_NODES * 4);
  float* w1      = (float*)alloc((size_t)ET * 4 * 4);         // 8.8 MB
  float* w2      = (float*)alloc((size_t)ET * 4);             // 2.2 MB
  int*   row_off = (int*)  alloc((size_t)(N_NODES + 1) * 4);
  int*   cursor  = (int*)  alloc((size_t)N_NODES * 4);
  int*   deg     = (int*)  alloc((size_t)N_NODES * 4);
  int*   srcs    = (int*)  alloc((size_t)ET * 4);
  int*   dsts    = (int*)  alloc((size_t)ET * 4);
  int*   btot    = (int*)  alloc(64 * 4);
  int*   bbase   = (int*)  alloc(64 * 4);
  float* g       = (float*)alloc(256 * 4);
  int*   flag    = (int*)  alloc(64 * 4);
  float* out2 = (float*)x2;   // x2 dead after GEMM2 (both 51.2 MB)

  hipMemsetAsync(deg, 0, (size_t)N_NODES * 4, stream);
  hipMemsetAsync(g, 0, 256 * 4, stream);

  // dtype detect + canonicalize
  k_detect<<<1, 64, 0, stream>>>((const u16*)d_in[2], flag);
  k_cvt_bf16<<<(N_NODES * 64 + 255) / 256, 256, 0, stream>>>(d_in[2], ne_b,
                                                             N_NODES * 64, flag);
  k_cvt_w_t<<<(32768 + 255) / 256, 256, 0, stream>>>(d_in[3], W1t, 64, 512, flag);
  k_cvt_w_t<<<(131072 + 255) / 256, 256, 0, stream>>>(d_in[7], W2t, 512, 256, flag);
  k_cvt_params<<<9, 256, 0, stream>>>(d_in[4], d_in[5], d_in[6], d_in[8], d_in[9],
                                      d_in[10], as1v, ad1v, b1f, as2v, ad2v, b2f,
                                      flag);
  k_valpha<<<1, 256, 0, stream>>>(W1t, as1v, ad1v, va_s, va_d);

  // CSR by dst (incl. self-loops)
  k_degree <<<(ET + 255) / 256, 256, 0, stream>>>(edge_index, deg);
  k_partial<<<49, 1024, 0, stream>>>(deg, row_off, btot);
  k_bases  <<<1, 64, 0, stream>>>(btot, bbase, row_off, 49);
  k_add    <<<49, 1024, 0, stream>>>(row_off, cursor, bbase);
  k_scatter<<<(ET + 255) / 256, 256, 0, stream>>>(edge_index, cursor, srcs, dsts);

  // layer 1: alphas from ne, aggregate ne, then GEMM (+bias+ELU) -> x2
  k_alpha1_ne<<<(N_NODES + 3) / 4, 256, 0, stream>>>(ne_b, va_s, va_d, as1, ad1);
  k_stats1<<<(N_NODES + 3) / 4, 256, 0, stream>>>(row_off, srcs, as1, ad1, m1, i1);
  k_edgew1<<<(ET + 255) / 256, 256, 0, stream>>>(srcs, dsts, as1, ad1, m1, i1, w1);
  k_aggne <<<N_NODES, 256, 0, stream>>>(row_off, srcs, ne_b, w1, aggne);
  dim3 gl1((N_NODES + 127) / 128, 4);
  k_gemm_l1<<<gl1, 256, 0, stream>>>(aggne, W1t, b1f, x2, N_NODES);

  // layer 2
  dim3 g2((N_NODES + 127) / 128, 2);
  k_gemm_mfma<<<g2, 256, 0, stream>>>(x2, W2t, h2, N_NODES, 512, 256);
  k_alpha2<<<(N_NODES + 3) / 4, 256, 0, stream>>>(h2, as2v, ad2v, as2, ad2);
  k_stats2<<<(N_NODES + 3) / 4, 256, 0, stream>>>(row_off, srcs, as2, ad2, m2, i2);
  k_edgew2<<<(ET + 255) / 256, 256, 0, stream>>>(srcs, dsts, as2, ad2, m2, i2, w2);
  k_agg2  <<<N_NODES, 256, 0, stream>>>(row_off, srcs, h2, w2, b2f, out2);

  // mean over nodes, broadcast to [batch, 256]
  k_reduce<<<256, 256, 0, stream>>>(out2, g);
  k_final <<<(out_size + 255) / 256, 256, 0, stream>>>(g, out, out_size);
}

// Round 7
// 419.785 us; speedup vs baseline: 1.9602x; 1.1951x over previous
//
#include <hip/hip_runtime.h>
#include <cstdint>

#define N_NODES 50000
#define N_EDGES 500000
#define ET (N_NODES + N_EDGES)   /* 550000 edges incl. self-loops */

typedef unsigned short u16;
typedef unsigned int   u32;
typedef __attribute__((ext_vector_type(8))) short short8;   // 8 bf16 (4 VGPRs)
typedef __attribute__((ext_vector_type(4))) float f32x4;

__device__ __forceinline__ float bf2f(u16 s) { return __uint_as_float((u32)s << 16); }
__device__ __forceinline__ u16 f2bf(float f) {          // round-to-nearest-even
  u32 u = __float_as_uint(f);
  u32 r = (u + 0x7FFFu + ((u >> 16) & 1u)) >> 16;
  return (u16)r;
}
__device__ __forceinline__ float lrelu(float v) { return v >= 0.f ? v : 0.2f * v; }

// ---------------- dtype detect + canonicalize ----------------
__global__ void k_detect(const u16* __restrict__ ne, int* __restrict__ flag) {
  int lane = threadIdx.x;  // 64 threads, one wave
  int bad = 0;
  #pragma unroll
  for (int j = 0; j < 2; ++j) {
    float v = fabsf(bf2f(ne[lane * 2 + j * 128]));  // even positions only
    bad += (!(v < 16.0f)) ? 1 : 0;                  // catches NaN too
  }
  #pragma unroll
  for (int off = 32; off >= 1; off >>= 1) bad += __shfl_xor(bad, off, 64);
  if (lane == 0) flag[0] = (bad > 16) ? 1 : 0;      // 1 => inputs are fp32
}

__global__ void k_cvt_bf16(const void* __restrict__ src, u16* __restrict__ dst,
                           int n, const int* __restrict__ flag) {
  int i = blockIdx.x * 256 + threadIdx.x;
  if (i >= n) return;
  if (flag[0]) dst[i] = f2bf(((const float*)src)[i]);
  else         dst[i] = ((const u16*)src)[i];
}

// W [K][N] -> Wt [N][K] bf16 (for MFMA B-operand staging)
__global__ void k_cvt_w_t(const void* __restrict__ src, u16* __restrict__ dst,
                          int K, int N, const int* __restrict__ flag) {
  int i = blockIdx.x * 256 + threadIdx.x;
  if (i >= K * N) return;
  int n = i / K, k = i - n * K;
  u16 v;
  if (flag[0]) v = f2bf(((const float*)src)[k * N + n]);
  else         v = ((const u16*)src)[k * N + n];
  dst[i] = v;
}

// all 6 small fp32 param vectors in one launch (2304 elements total)
__global__ void k_cvt_params(const void* s0, const void* s1, const void* s2,
                             const void* s3, const void* s4, const void* s5,
                             float* d0, float* d1, float* d2,
                             float* d3, float* d4, float* d5,
                             const int* __restrict__ flag) {
  int i = blockIdx.x * 256 + threadIdx.x;
  const void* s; float* d; int j;
  if      (i < 512)  { s = s0; d = d0; j = i; }
  else if (i < 1024) { s = s1; d = d1; j = i - 512; }
  else if (i < 1536) { s = s2; d = d2; j = i - 1024; }
  else if (i < 1792) { s = s3; d = d3; j = i - 1536; }
  else if (i < 2048) { s = s4; d = d4; j = i - 1792; }
  else if (i < 2304) { s = s5; d = d5; j = i - 2048; }
  else return;
  if (flag[0]) d[j] = ((const float*)s)[j];
  else         d[j] = bf2f(((const u16*)s)[j]);
}

// ---------------- CSR build (dst-sorted) ----------------
__global__ void k_degree(const int* __restrict__ ei, int* __restrict__ deg) {
  int e = blockIdx.x * 256 + threadIdx.x;
  if (e >= ET) return;
  int d = (e < N_EDGES) ? ei[N_EDGES + e] : (e - N_EDGES);
  atomicAdd(&deg[d], 1);
}

__global__ __launch_bounds__(1024) void k_partial(const int* __restrict__ deg,
                                                  int* __restrict__ excl,
                                                  int* __restrict__ btot) {
  __shared__ int wsum[16];
  int tid = threadIdx.x;
  int i = blockIdx.x * 1024 + tid;
  int v = (i < N_NODES) ? deg[i] : 0;
  int lane = tid & 63, wid = tid >> 6;
  int incl = v;
  #pragma unroll
  for (int off = 1; off < 64; off <<= 1) {
    int t = __shfl_up(incl, off, 64);
    if (lane >= off) incl += t;
  }
  if (lane == 63) wsum[wid] = incl;
  __syncthreads();
  int prefix = 0;
  for (int w = 0; w < wid; ++w) prefix += wsum[w];
  if (i < N_NODES) excl[i] = prefix + incl - v;
  if (tid == 1023) btot[blockIdx.x] = prefix + incl;
}

__global__ void k_bases(const int* __restrict__ btot, int* __restrict__ bbase,
                        int* __restrict__ row_off, int nb) {
  int lane = threadIdx.x;  // 64 threads, single wave
  int v = (lane < nb) ? btot[lane] : 0;
  int incl = v;
  #pragma unroll
  for (int off = 1; off < 64; off <<= 1) {
    int t = __shfl_up(incl, off, 64);
    if (lane >= off) incl += t;
  }
  if (lane < nb) bbase[lane] = incl - v;
  if (lane == 0) row_off[N_NODES] = ET;
}

__global__ __launch_bounds__(1024) void k_add(int* __restrict__ row_off,
                                              int* __restrict__ cursor,
                                              const int* __restrict__ bbase) {
  int i = blockIdx.x * 1024 + threadIdx.x;
  if (i < N_NODES) {
    int r = row_off[i] + bbase[blockIdx.x];
    row_off[i] = r;
    cursor[i] = r;
  }
}

__global__ void k_scatter(const int* __restrict__ ei, int* __restrict__ cursor,
                          int* __restrict__ srcs) {
  int e = blockIdx.x * 256 + threadIdx.x;
  if (e >= ET) return;
  int s, d;
  if (e < N_EDGES) { s = ei[e]; d = ei[N_EDGES + e]; }
  else { s = d = e - N_EDGES; }
  int pos = atomicAdd(&cursor[d], 1);
  srcs[pos] = s;
}

// ---------------- MFMA GEMM (layer 2): C = A[M,K] * Bt[Nc,K]^T, bf16 ----
#define LSTR 40
__global__ __launch_bounds__(256) void k_gemm_mfma(const u16* __restrict__ A,
                                                   const u16* __restrict__ Bt,
                                                   u16* __restrict__ C,
                                                   int M, int K, int Nc) {
  __shared__ __align__(16) u16 As[128 * LSTR];
  __shared__ __align__(16) u16 Bs[128 * LSTR];
  const int tid = threadIdx.x;
  const int lane = tid & 63, wid = tid >> 6;
  const int wr = (wid >> 1) * 64, wc = (wid & 1) * 64;
  const int m = lane & 15, q = lane >> 4;     // frag row/col + k-quad
  const int row0 = blockIdx.x * 128, col0 = blockIdx.y * 128;
  f32x4 acc[4][4] = {};
  for (int kk = 0; kk < K; kk += 32) {
    #pragma unroll
    for (int i = 0; i < 2; ++i) {             // stage A 128x32
      int v = tid + i * 256;
      int row = v >> 2, ch = (v & 3) * 8;
      uint4 u = make_uint4(0, 0, 0, 0);
      int gr = row0 + row;
      if (gr < M) u = *(const uint4*)(A + (size_t)gr * K + kk + ch);
      *(uint4*)(As + row * LSTR + ch) = u;
    }
    #pragma unroll
    for (int i = 0; i < 2; ++i) {             // stage Bt 128x32
      int v = tid + i * 256;
      int row = v >> 2, ch = (v & 3) * 8;
      uint4 u = *(const uint4*)(Bt + (size_t)(col0 + row) * K + kk + ch);
      *(uint4*)(Bs + row * LSTR + ch) = u;
    }
    __syncthreads();
    short8 af[4], bfr[4];
    #pragma unroll
    for (int t = 0; t < 4; ++t) {
      af[t]  = *(const short8*)(As + (wr + t * 16 + m) * LSTR + q * 8);
      bfr[t] = *(const short8*)(Bs + (wc + t * 16 + m) * LSTR + q * 8);
    }
    #pragma unroll
    for (int mt = 0; mt < 4; ++mt)
      #pragma unroll
      for (int nt = 0; nt < 4; ++nt)
        acc[mt][nt] = __builtin_amdgcn_mfma_f32_16x16x32_bf16(
            af[mt], bfr[nt], acc[mt][nt], 0, 0, 0);
    __syncthreads();
  }
  #pragma unroll
  for (int mt = 0; mt < 4; ++mt) {
    int grb = row0 + wr + mt * 16 + q * 4;
    #pragma unroll
    for (int nt = 0; nt < 4; ++nt) {
      int gc = col0 + wc + nt * 16 + m;
      #pragma unroll
      for (int r = 0; r < 4; ++r) {
        int gr = grb + r;
        if (gr < M) C[(size_t)gr * Nc + gc] = f2bf(acc[mt][nt][r]);
      }
    }
  }
}

// ---------------- layer-1 GEMM on aggregated ne, fused bias+ELU ----
__global__ __launch_bounds__(256) void k_gemm_l1(const u16* __restrict__ aggne,
                                                 const u16* __restrict__ W1t,
                                                 const float* __restrict__ b1f,
                                                 u16* __restrict__ x2, int M) {
  __shared__ __align__(16) u16 As[128 * LSTR];
  __shared__ __align__(16) u16 Bs[128 * LSTR];
  const int tid = threadIdx.x;
  const int lane = tid & 63, wid = tid >> 6;
  const int wr = (wid >> 1) * 64, wc = (wid & 1) * 64;
  const int m = lane & 15, q = lane >> 4;
  const int row0 = blockIdx.x * 128, head = blockIdx.y;
  const u16* Bt = W1t + (size_t)head * 128 * 64;   // [128 rows][64]
  f32x4 acc[4][4] = {};
  #pragma unroll
  for (int kk = 0; kk < 64; kk += 32) {
    #pragma unroll
    for (int i = 0; i < 2; ++i) {             // stage A 128x32 (lda=256)
      int v = tid + i * 256;
      int row = v >> 2, ch = (v & 3) * 8;
      uint4 u = make_uint4(0, 0, 0, 0);
      int gr = row0 + row;
      if (gr < M) u = *(const uint4*)(aggne + (size_t)gr * 256 + head * 64 + kk + ch);
      *(uint4*)(As + row * LSTR + ch) = u;
    }
    #pragma unroll
    for (int i = 0; i < 2; ++i) {             // stage Bt 128x32 (stride 64)
      int v = tid + i * 256;
      int row = v >> 2, ch = (v & 3) * 8;
      uint4 u = *(const uint4*)(Bt + (size_t)row * 64 + kk + ch);
      *(uint4*)(Bs + row * LSTR + ch) = u;
    }
    __syncthreads();
    short8 af[4], bfr[4];
    #pragma unroll
    for (int t = 0; t < 4; ++t) {
      af[t]  = *(const short8*)(As + (wr + t * 16 + m) * LSTR + q * 8);
      bfr[t] = *(const short8*)(Bs + (wc + t * 16 + m) * LSTR + q * 8);
    }
    #pragma unroll
    for (int mt = 0; mt < 4; ++mt)
      #pragma unroll
      for (int nt = 0; nt < 4; ++nt)
        acc[mt][nt] = __builtin_amdgcn_mfma_f32_16x16x32_bf16(
            af[mt], bfr[nt], acc[mt][nt], 0, 0, 0);
    __syncthreads();
  }
  #pragma unroll
  for (int mt = 0; mt < 4; ++mt) {
    int grb = row0 + wr + mt * 16 + q * 4;
    #pragma unroll
    for (int nt = 0; nt < 4; ++nt) {
      int lc = wc + nt * 16 + m;              // local col in [0,128)
      float bias = b1f[head * 128 + lc];
      #pragma unroll
      for (int r = 0; r < 4; ++r) {
        int gr = grb + r;
        if (gr < M) {
          float v = acc[mt][nt][r] + bias;
          v = v > 0.f ? v : (__expf(v) - 1.0f);   // ELU
          x2[(size_t)gr * 512 + head * 128 + lc] = f2bf(v);
        }
      }
    }
  }
}

// ---------------- va vectors: va[h][k] = sum_c a[h*128+c] * W1t[(h*128+c)][k]
__global__ void k_valpha(const u16* __restrict__ W1t,
                         const float* __restrict__ as1v, const float* __restrict__ ad1v,
                         float* __restrict__ va_s, float* __restrict__ va_d) {
  int t = threadIdx.x;           // 256 threads: h = t>>6, k = t&63
  int h = t >> 6, k = t & 63;
  float s = 0.f, d = 0.f;
  for (int c = 0; c < 128; ++c) {
    float w = bf2f(W1t[(size_t)(h * 128 + c) * 64 + k]);
    s = fmaf(as1v[h * 128 + c], w, s);
    d = fmaf(ad1v[h * 128 + c], w, d);
  }
  va_s[t] = s;
  va_d[t] = d;
}

// ---------------- layer-1 attention logits straight from ne ----------------
__global__ __launch_bounds__(256) void k_alpha1_ne(const u16* __restrict__ ne_b,
                                                   const float* __restrict__ va_s,
                                                   const float* __restrict__ va_d,
                                                   float* __restrict__ as_o,
                                                   float* __restrict__ ad_o) {
  int wid = threadIdx.x >> 6, lane = threadIdx.x & 63;
  int n = blockIdx.x * 4 + wid;
  if (n >= N_NODES) return;
  float v = bf2f(ne_b[(size_t)n * 64 + lane]);
  #pragma unroll
  for (int h = 0; h < 4; ++h) {
    float s = v * va_s[h * 64 + lane];
    float d = v * va_d[h * 64 + lane];
    #pragma unroll
    for (int off = 32; off >= 1; off >>= 1) {
      s += __shfl_xor(s, off, 64);
      d += __shfl_xor(d, off, 64);
    }
    if (lane == 0) { as_o[n * 4 + h] = s; ad_o[n * 4 + h] = d; }
  }
}

__global__ __launch_bounds__(256) void k_alpha2(const u16* __restrict__ h2,
                                                const float* __restrict__ a_src,
                                                const float* __restrict__ a_dst,
                                                float* __restrict__ as_o,
                                                float* __restrict__ ad_o) {
  int wid = threadIdx.x >> 6, lane = threadIdx.x & 63;
  int n = blockIdx.x * 4 + wid;
  if (n >= N_NODES) return;
  uint2 u = *(const uint2*)(h2 + (size_t)n * 256 + lane * 4);
  float f[4];
  f[0] = bf2f((u16)u.x); f[1] = bf2f((u16)(u.x >> 16));
  f[2] = bf2f((u16)u.y); f[3] = bf2f((u16)(u.y >> 16));
  float4 av = *(const float4*)(a_src + lane * 4);
  float4 dv = *(const float4*)(a_dst + lane * 4);
  float fa[4] = {av.x, av.y, av.z, av.w};
  float fd[4] = {dv.x, dv.y, dv.z, dv.w};
  float s = 0.f, d = 0.f;
  #pragma unroll
  for (int j = 0; j < 4; ++j) { s = fmaf(f[j], fa[j], s); d = fmaf(f[j], fd[j], d); }
  #pragma unroll
  for (int off = 32; off >= 1; off >>= 1) {
    s += __shfl_xor(s, off, 64);
    d += __shfl_xor(d, off, 64);
  }
  if (lane == 0) { as_o[n] = s; ad_o[n] = d; }
}

// ---------------- fused layer-1 aggregation: one wave per node ----------
// softmax stats in-wave, weights inline, edge idx shfl-broadcast, no LDS.
// aggne[n][h*64+lane] = sum_e softmax1(e,h) * ne[src[e]][lane]
__global__ __launch_bounds__(256) void k_fagg1(const int* __restrict__ row_off,
                                               const int* __restrict__ srcs,
                                               const u16* __restrict__ ne_b,
                                               const float* __restrict__ as1,
                                               const float* __restrict__ ad1,
                                               u16* __restrict__ aggne) {
  int wid = threadIdx.x >> 6, lane = threadIdx.x & 63;
  int n = blockIdx.x * 4 + wid;
  if (n >= N_NODES) return;
  int start = row_off[n], end = row_off[n + 1];
  int g = lane >> 4, il = lane & 15;     // head group g, lane-in-group
  float adn_g = ad1[n * 4 + g];
  // per-head stats: max, then sum-exp (16-lane group per head)
  float mx = -1e30f;
  for (int e0 = start; e0 < end; e0 += 16) {
    int e = e0 + il;
    if (e < end) mx = fmaxf(mx, lrelu(as1[srcs[e] * 4 + g] + adn_g));
  }
  #pragma unroll
  for (int off = 8; off >= 1; off >>= 1) mx = fmaxf(mx, __shfl_xor(mx, off, 64));
  float sum = 0.f;
  for (int e0 = start; e0 < end; e0 += 16) {
    int e = e0 + il;
    if (e < end) sum += __expf(lrelu(as1[srcs[e] * 4 + g] + adn_g) - mx);
  }
  #pragma unroll
  for (int off = 8; off >= 1; off >>= 1) sum += __shfl_xor(sum, off, 64);
  float inv = 1.0f / (sum + 1e-16f);
  // broadcast all-head stats to every lane
  float m_[4], i_[4], d_[4];
  #pragma unroll
  for (int h = 0; h < 4; ++h) {
    m_[h] = __shfl(mx, h * 16, 64);
    i_[h] = __shfl(inv, h * 16, 64);
    d_[h] = __shfl(adn_g, h * 16, 64);
  }
  // gather: chunk edge indices into a register, shfl-broadcast
  float acc[4] = {};
  for (int e0 = start; e0 < end; e0 += 64) {
    int lim = end - e0; if (lim > 64) lim = 64;
    int es = e0 + lane;
    int sreg = srcs[es < end ? es : end - 1];
    int j = 0;
    for (; j + 1 < lim; j += 2) {
      int s0 = __shfl(sreg, j, 64), s1 = __shfl(sreg, j + 1, 64);
      float4 a0 = *(const float4*)(as1 + s0 * 4);
      float4 a1 = *(const float4*)(as1 + s1 * 4);
      float f0 = bf2f(ne_b[(size_t)s0 * 64 + lane]);
      float f1 = bf2f(ne_b[(size_t)s1 * 64 + lane]);
      float la0[4] = {a0.x, a0.y, a0.z, a0.w};
      float la1[4] = {a1.x, a1.y, a1.z, a1.w};
      #pragma unroll
      for (int h = 0; h < 4; ++h) {
        float w0 = __expf(lrelu(la0[h] + d_[h]) - m_[h]) * i_[h];
        float w1 = __expf(lrelu(la1[h] + d_[h]) - m_[h]) * i_[h];
        acc[h] = fmaf(w0, f0, acc[h]);
        acc[h] = fmaf(w1, f1, acc[h]);
      }
    }
    if (j < lim) {
      int s0 = __shfl(sreg, j, 64);
      float4 a0 = *(const float4*)(as1 + s0 * 4);
      float f0 = bf2f(ne_b[(size_t)s0 * 64 + lane]);
      float la0[4] = {a0.x, a0.y, a0.z, a0.w};
      #pragma unroll
      for (int h = 0; h < 4; ++h) {
        float w0 = __expf(lrelu(la0[h] + d_[h]) - m_[h]) * i_[h];
        acc[h] = fmaf(w0, f0, acc[h]);
      }
    }
  }
  #pragma unroll
  for (int h = 0; h < 4; ++h)
    aggne[(size_t)n * 256 + h * 64 + lane] = f2bf(acc[h]);
}

// ---------------- fused layer-2 aggregation: one wave per node ----------
// out2[n][lane*4..+3] = b2 + sum_e softmax2(e) * h2[src[e]][lane*4..+3]
__global__ __launch_bounds__(256) void k_fagg2(const int* __restrict__ row_off,
                                               const int* __restrict__ srcs,
                                               const u16* __restrict__ h2,
                                               const float* __restrict__ as2,
                                               const float* __restrict__ ad2,
                                               const float* __restrict__ b2f,
                                               float* __restrict__ out2) {
  int wid = threadIdx.x >> 6, lane = threadIdx.x & 63;
  int n = blockIdx.x * 4 + wid;
  if (n >= N_NODES) return;
  int start = row_off[n], end = row_off[n + 1];
  float adn = ad2[n];
  // stats: lane-parallel over edges
  float mx = -1e30f;
  for (int e0 = start; e0 < end; e0 += 64) {
    int e = e0 + lane;
    if (e < end) mx = fmaxf(mx, lrelu(as2[srcs[e]] + adn));
  }
  #pragma unroll
  for (int off = 32; off >= 1; off >>= 1) mx = fmaxf(mx, __shfl_xor(mx, off, 64));
  float sum = 0.f;
  for (int e0 = start; e0 < end; e0 += 64) {
    int e = e0 + lane;
    if (e < end) sum += __expf(lrelu(as2[srcs[e]] + adn) - mx);
  }
  #pragma unroll
  for (int off = 32; off >= 1; off >>= 1) sum += __shfl_xor(sum, off, 64);
  float inv = 1.0f / (sum + 1e-16f);
  // gather
  float a0 = 0.f, a1 = 0.f, a2 = 0.f, a3 = 0.f;
  for (int e0 = start; e0 < end; e0 += 64) {
    int lim = end - e0; if (lim > 64) lim = 64;
    int es = e0 + lane;
    int sreg = srcs[es < end ? es : end - 1];
    int j = 0;
    for (; j + 1 < lim; j += 2) {
      int s0 = __shfl(sreg, j, 64), s1 = __shfl(sreg, j + 1, 64);
      float w0 = __expf(lrelu(as2[s0] + adn) - mx) * inv;
      float w1 = __expf(lrelu(as2[s1] + adn) - mx) * inv;
      uint2 u0 = *(const uint2*)(h2 + (size_t)s0 * 256 + lane * 4);
      uint2 u1 = *(const uint2*)(h2 + (size_t)s1 * 256 + lane * 4);
      a0 = fmaf(w0, bf2f((u16)u0.x), a0); a0 = fmaf(w1, bf2f((u16)u1.x), a0);
      a1 = fmaf(w0, bf2f((u16)(u0.x >> 16)), a1); a1 = fmaf(w1, bf2f((u16)(u1.x >> 16)), a1);
      a2 = fmaf(w0, bf2f((u16)u0.y), a2); a2 = fmaf(w1, bf2f((u16)u1.y), a2);
      a3 = fmaf(w0, bf2f((u16)(u0.y >> 16)), a3); a3 = fmaf(w1, bf2f((u16)(u1.y >> 16)), a3);
    }
    if (j < lim) {
      int s0 = __shfl(sreg, j, 64);
      float w0 = __expf(lrelu(as2[s0] + adn) - mx) * inv;
      uint2 u0 = *(const uint2*)(h2 + (size_t)s0 * 256 + lane * 4);
      a0 = fmaf(w0, bf2f((u16)u0.x), a0);
      a1 = fmaf(w0, bf2f((u16)(u0.x >> 16)), a1);
      a2 = fmaf(w0, bf2f((u16)u0.y), a2);
      a3 = fmaf(w0, bf2f((u16)(u0.y >> 16)), a3);
    }
  }
  float4 bb = *(const float4*)(b2f + lane * 4);
  *(float4*)(out2 + (size_t)n * 256 + lane * 4) =
      make_float4(a0 + bb.x, a1 + bb.y, a2 + bb.z, a3 + bb.w);
}

// ---------------- global mean + broadcast ----------------
__global__ __launch_bounds__(256) void k_reduce(const float* __restrict__ out2,
                                                float* __restrict__ g) {
  int c = threadIdx.x;
  float acc = 0.f;
  for (int n = blockIdx.x; n < N_NODES; n += 256)
    acc += out2[(size_t)n * 256 + c];
  atomicAdd(&g[c], acc);
}

__global__ void k_final(const float* __restrict__ g, float* __restrict__ out,
                        int out_size) {
  int i = blockIdx.x * 256 + threadIdx.x;
  if (i < out_size) out[i] = g[i & 255] * (1.0f / (float)N_NODES);
}

// ---------------- launch ----------------
extern "C" void kernel_launch(void* const* d_in, const int* in_sizes, int n_in,
                              void* d_out, int out_size, void* d_ws, size_t ws_size,
                              hipStream_t stream) {
  (void)in_sizes; (void)n_in; (void)ws_size;
  const int* edge_index = (const int*)d_in[0];
  float* out = (float*)d_out;   // reference output dtype is float32

  char* w = (char*)d_ws;
  size_t off = 0;
  auto alloc = [&](size_t bytes) -> void* {
    void* p = w + off;
    off += (bytes + 255) & ~(size_t)255;
    return p;
  };
  u16*   ne_b    = (u16*)  alloc((size_t)N_NODES * 64 * 2);   // 6.4 MB bf16
  u16*   W1t     = (u16*)  alloc(32768 * 2);                  // [512][64]
  u16*   W2t     = (u16*)  alloc(131072 * 2);                 // [256][512]
  float* as1v    = (float*)alloc(512 * 4);
  float* ad1v    = (float*)alloc(512 * 4);
  float* b1f     = (float*)alloc(512 * 4);
  float* as2v    = (float*)alloc(256 * 4);
  float* ad2v    = (float*)alloc(256 * 4);
  float* b2f     = (float*)alloc(256 * 4);
  float* va_s    = (float*)alloc(256 * 4);
  float* va_d    = (float*)alloc(256 * 4);
  u16*   aggne   = (u16*)  alloc((size_t)N_NODES * 256 * 2);  // 25.6 MB
  u16*   x2      = (u16*)  alloc((size_t)N_NODES * 512 * 2);  // 51.2 MB (reused as out2 fp32)
  u16*   h2      = (u16*)  alloc((size_t)N_NODES * 256 * 2);  // 25.6 MB
  float* as1     = (float*)alloc((size_t)N_NODES * 4 * 4);
  float* ad1     = (float*)alloc((size_t)N_NODES * 4 * 4);
  float* as2     = (float*)alloc((size_t)N_NODES * 4);
  float* ad2     = (float*)alloc((size_t)N_NODES * 4);
  int*   row_off = (int*)  alloc((size_t)(N_NODES + 1) * 4);
  int*   cursor  = (int*)  alloc((size_t)N_NODES * 4);
  int*   deg     = (int*)  alloc((size_t)N_NODES * 4);
  int*   srcs    = (int*)  alloc((size_t)ET * 4);
  int*   btot    = (int*)  alloc(64 * 4);
  int*   bbase   = (int*)  alloc(64 * 4);
  float* g       = (float*)alloc(256 * 4);
  int*   flag    = (int*)  alloc(64 * 4);
  float* out2 = (float*)x2;   // x2 dead after GEMM2 (both 51.2 MB)

  hipMemsetAsync(deg, 0, (size_t)N_NODES * 4, stream);
  hipMemsetAsync(g, 0, 256 * 4, stream);

  // dtype detect + canonicalize
  k_detect<<<1, 64, 0, stream>>>((const u16*)d_in[2], flag);
  k_cvt_bf16<<<(N_NODES * 64 + 255) / 256, 256, 0, stream>>>(d_in[2], ne_b,
                                                             N_NODES * 64, flag);
  k_cvt_w_t<<<(32768 + 255) / 256, 256, 0, stream>>>(d_in[3], W1t, 64, 512, flag);
  k_cvt_w_t<<<(131072 + 255) / 256, 256, 0, stream>>>(d_in[7], W2t, 512, 256, flag);
  k_cvt_params<<<9, 256, 0, stream>>>(d_in[4], d_in[5], d_in[6], d_in[8], d_in[9],
                                      d_in[10], as1v, ad1v, b1f, as2v, ad2v, b2f,
                                      flag);
  k_valpha<<<1, 256, 0, stream>>>(W1t, as1v, ad1v, va_s, va_d);

  // CSR by dst (incl. self-loops)
  k_degree <<<(ET + 255) / 256, 256, 0, stream>>>(edge_index, deg);
  k_partial<<<49, 1024, 0, stream>>>(deg, row_off, btot);
  k_bases  <<<1, 64, 0, stream>>>(btot, bbase, row_off, 49);
  k_add    <<<49, 1024, 0, stream>>>(row_off, cursor, bbase);
  k_scatter<<<(ET + 255) / 256, 256, 0, stream>>>(edge_index, cursor, srcs);

  // layer 1: alphas from ne, fused agg over ne, then GEMM (+bias+ELU) -> x2
  k_alpha1_ne<<<(N_NODES + 3) / 4, 256, 0, stream>>>(ne_b, va_s, va_d, as1, ad1);
  k_fagg1<<<(N_NODES + 3) / 4, 256, 0, stream>>>(row_off, srcs, ne_b, as1, ad1, aggne);
  dim3 gl1((N_NODES + 127) / 128, 4);
  k_gemm_l1<<<gl1, 256, 0, stream>>>(aggne, W1t, b1f, x2, N_NODES);

  // layer 2
  dim3 g2((N_NODES + 127) / 128, 2);
  k_gemm_mfma<<<g2, 256, 0, stream>>>(x2, W2t, h2, N_NODES, 512, 256);
  k_alpha2<<<(N_NODES + 3) / 4, 256, 0, stream>>>(h2, as2v, ad2v, as2, ad2);
  k_fagg2<<<(N_NODES + 3) / 4, 256, 0, stream>>>(row_off, srcs, h2, as2, ad2, b2f, out2);

  // mean over nodes, broadcast to [batch, 256]
  k_reduce<<<256, 256, 0, stream>>>(out2, g);
  k_final <<<(out_size + 255) / 256, 256, 0, stream>>>(g, out, out_size);
}

// Round 8
// 415.332 us; speedup vs baseline: 1.9812x; 1.0107x over previous
//
#include <hip/hip_runtime.h>
#include <cstdint>

#define N_NODES 50000
#define N_EDGES 500000
#define ET (N_NODES + N_EDGES)   /* 550000 edges incl. self-loops */
#define NBLK 12500               /* fagg2 blocks = N_NODES/4 */

typedef unsigned short u16;
typedef unsigned int   u32;
typedef __attribute__((ext_vector_type(8))) short short8;   // 8 bf16 (4 VGPRs)
typedef __attribute__((ext_vector_type(4))) float f32x4;

__device__ __forceinline__ float bf2f(u16 s) { return __uint_as_float((u32)s << 16); }
__device__ __forceinline__ u16 f2bf(float f) {          // round-to-nearest-even
  u32 u = __float_as_uint(f);
  u32 r = (u + 0x7FFFu + ((u >> 16) & 1u)) >> 16;
  return (u16)r;
}
__device__ __forceinline__ float lrelu(float v) { return v >= 0.f ? v : 0.2f * v; }

// ---------------- dtype detect + canonicalize ----------------
__global__ void k_detect(const u16* __restrict__ ne, int* __restrict__ flag) {
  int lane = threadIdx.x;  // 64 threads, one wave
  int bad = 0;
  #pragma unroll
  for (int j = 0; j < 2; ++j) {
    float v = fabsf(bf2f(ne[lane * 2 + j * 128]));  // even positions only
    bad += (!(v < 16.0f)) ? 1 : 0;                  // catches NaN too
  }
  #pragma unroll
  for (int off = 32; off >= 1; off >>= 1) bad += __shfl_xor(bad, off, 64);
  if (lane == 0) flag[0] = (bad > 16) ? 1 : 0;      // 1 => inputs are fp32
}

__global__ void k_cvt_bf16(const void* __restrict__ src, u16* __restrict__ dst,
                           int n, const int* __restrict__ flag) {
  int i = blockIdx.x * 256 + threadIdx.x;
  if (i >= n) return;
  if (flag[0]) dst[i] = f2bf(((const float*)src)[i]);
  else         dst[i] = ((const u16*)src)[i];
}

// W [K][N] -> Wt [N][K] bf16 (for MFMA B-operand staging)
__global__ void k_cvt_w_t(const void* __restrict__ src, u16* __restrict__ dst,
                          int K, int N, const int* __restrict__ flag) {
  int i = blockIdx.x * 256 + threadIdx.x;
  if (i >= K * N) return;
  int n = i / K, k = i - n * K;
  u16 v;
  if (flag[0]) v = f2bf(((const float*)src)[k * N + n]);
  else         v = ((const u16*)src)[k * N + n];
  dst[i] = v;
}

// all 6 small fp32 param vectors in one launch (2304 elements total)
__global__ void k_cvt_params(const void* s0, const void* s1, const void* s2,
                             const void* s3, const void* s4, const void* s5,
                             float* d0, float* d1, float* d2,
                             float* d3, float* d4, float* d5,
                             const int* __restrict__ flag) {
  int i = blockIdx.x * 256 + threadIdx.x;
  const void* s; float* d; int j;
  if      (i < 512)  { s = s0; d = d0; j = i; }
  else if (i < 1024) { s = s1; d = d1; j = i - 512; }
  else if (i < 1536) { s = s2; d = d2; j = i - 1024; }
  else if (i < 1792) { s = s3; d = d3; j = i - 1536; }
  else if (i < 2048) { s = s4; d = d4; j = i - 1792; }
  else if (i < 2304) { s = s5; d = d5; j = i - 2048; }
  else return;
  if (flag[0]) d[j] = ((const float*)s)[j];
  else         d[j] = bf2f(((const u16*)s)[j]);
}

// ---------------- CSR build (dst-sorted) ----------------
__global__ void k_degree(const int* __restrict__ ei, int* __restrict__ deg) {
  int e = blockIdx.x * 256 + threadIdx.x;
  if (e >= ET) return;
  int d = (e < N_EDGES) ? ei[N_EDGES + e] : (e - N_EDGES);
  atomicAdd(&deg[d], 1);
}

__global__ __launch_bounds__(1024) void k_partial(const int* __restrict__ deg,
                                                  int* __restrict__ excl,
                                                  int* __restrict__ btot) {
  __shared__ int wsum[16];
  int tid = threadIdx.x;
  int i = blockIdx.x * 1024 + tid;
  int v = (i < N_NODES) ? deg[i] : 0;
  int lane = tid & 63, wid = tid >> 6;
  int incl = v;
  #pragma unroll
  for (int off = 1; off < 64; off <<= 1) {
    int t = __shfl_up(incl, off, 64);
    if (lane >= off) incl += t;
  }
  if (lane == 63) wsum[wid] = incl;
  __syncthreads();
  int prefix = 0;
  for (int w = 0; w < wid; ++w) prefix += wsum[w];
  if (i < N_NODES) excl[i] = prefix + incl - v;
  if (tid == 1023) btot[blockIdx.x] = prefix + incl;
}

__global__ void k_bases(const int* __restrict__ btot, int* __restrict__ bbase,
                        int* __restrict__ row_off, int nb) {
  int lane = threadIdx.x;  // 64 threads, single wave
  int v = (lane < nb) ? btot[lane] : 0;
  int incl = v;
  #pragma unroll
  for (int off = 1; off < 64; off <<= 1) {
    int t = __shfl_up(incl, off, 64);
    if (lane >= off) incl += t;
  }
  if (lane < nb) bbase[lane] = incl - v;
  if (lane == 0) row_off[N_NODES] = ET;
}

__global__ __launch_bounds__(1024) void k_add(int* __restrict__ row_off,
                                              int* __restrict__ cursor,
                                              const int* __restrict__ bbase) {
  int i = blockIdx.x * 1024 + threadIdx.x;
  if (i < N_NODES) {
    int r = row_off[i] + bbase[blockIdx.x];
    row_off[i] = r;
    cursor[i] = r;
  }
}

__global__ void k_scatter(const int* __restrict__ ei, int* __restrict__ cursor,
                          int* __restrict__ srcs) {
  int e = blockIdx.x * 256 + threadIdx.x;
  if (e >= ET) return;
  int s, d;
  if (e < N_EDGES) { s = ei[e]; d = ei[N_EDGES + e]; }
  else { s = d = e - N_EDGES; }
  int pos = atomicAdd(&cursor[d], 1);
  srcs[pos] = s;
}

// ---------------- MFMA GEMM (layer 2): C = A[M,K] * Bt[Nc,K]^T, bf16 ----
#define LSTR 40
__global__ __launch_bounds__(256) void k_gemm_mfma(const u16* __restrict__ A,
                                                   const u16* __restrict__ Bt,
                                                   u16* __restrict__ C,
                                                   int M, int K, int Nc) {
  __shared__ __align__(16) u16 As[128 * LSTR];
  __shared__ __align__(16) u16 Bs[128 * LSTR];
  const int tid = threadIdx.x;
  const int lane = tid & 63, wid = tid >> 6;
  const int wr = (wid >> 1) * 64, wc = (wid & 1) * 64;
  const int m = lane & 15, q = lane >> 4;     // frag row/col + k-quad
  const int row0 = blockIdx.x * 128, col0 = blockIdx.y * 128;
  f32x4 acc[4][4] = {};
  for (int kk = 0; kk < K; kk += 32) {
    #pragma unroll
    for (int i = 0; i < 2; ++i) {             // stage A 128x32
      int v = tid + i * 256;
      int row = v >> 2, ch = (v & 3) * 8;
      uint4 u = make_uint4(0, 0, 0, 0);
      int gr = row0 + row;
      if (gr < M) u = *(const uint4*)(A + (size_t)gr * K + kk + ch);
      *(uint4*)(As + row * LSTR + ch) = u;
    }
    #pragma unroll
    for (int i = 0; i < 2; ++i) {             // stage Bt 128x32
      int v = tid + i * 256;
      int row = v >> 2, ch = (v & 3) * 8;
      uint4 u = *(const uint4*)(Bt + (size_t)(col0 + row) * K + kk + ch);
      *(uint4*)(Bs + row * LSTR + ch) = u;
    }
    __syncthreads();
    short8 af[4], bfr[4];
    #pragma unroll
    for (int t = 0; t < 4; ++t) {
      af[t]  = *(const short8*)(As + (wr + t * 16 + m) * LSTR + q * 8);
      bfr[t] = *(const short8*)(Bs + (wc + t * 16 + m) * LSTR + q * 8);
    }
    #pragma unroll
    for (int mt = 0; mt < 4; ++mt)
      #pragma unroll
      for (int nt = 0; nt < 4; ++nt)
        acc[mt][nt] = __builtin_amdgcn_mfma_f32_16x16x32_bf16(
            af[mt], bfr[nt], acc[mt][nt], 0, 0, 0);
    __syncthreads();
  }
  #pragma unroll
  for (int mt = 0; mt < 4; ++mt) {
    int grb = row0 + wr + mt * 16 + q * 4;
    #pragma unroll
    for (int nt = 0; nt < 4; ++nt) {
      int gc = col0 + wc + nt * 16 + m;
      #pragma unroll
      for (int r = 0; r < 4; ++r) {
        int gr = grb + r;
        if (gr < M) C[(size_t)gr * Nc + gc] = f2bf(acc[mt][nt][r]);
      }
    }
  }
}

// ---------------- layer-1 GEMM on aggregated ne, fused bias+ELU ----
__global__ __launch_bounds__(256) void k_gemm_l1(const u16* __restrict__ aggne,
                                                 const u16* __restrict__ W1t,
                                                 const float* __restrict__ b1f,
                                                 u16* __restrict__ x2, int M) {
  __shared__ __align__(16) u16 As[128 * LSTR];
  __shared__ __align__(16) u16 Bs[128 * LSTR];
  const int tid = threadIdx.x;
  const int lane = tid & 63, wid = tid >> 6;
  const int wr = (wid >> 1) * 64, wc = (wid & 1) * 64;
  const int m = lane & 15, q = lane >> 4;
  const int row0 = blockIdx.x * 128, head = blockIdx.y;
  const u16* Bt = W1t + (size_t)head * 128 * 64;   // [128 rows][64]
  f32x4 acc[4][4] = {};
  #pragma unroll
  for (int kk = 0; kk < 64; kk += 32) {
    #pragma unroll
    for (int i = 0; i < 2; ++i) {             // stage A 128x32 (lda=256)
      int v = tid + i * 256;
      int row = v >> 2, ch = (v & 3) * 8;
      uint4 u = make_uint4(0, 0, 0, 0);
      int gr = row0 + row;
      if (gr < M) u = *(const uint4*)(aggne + (size_t)gr * 256 + head * 64 + kk + ch);
      *(uint4*)(As + row * LSTR + ch) = u;
    }
    #pragma unroll
    for (int i = 0; i < 2; ++i) {             // stage Bt 128x32 (stride 64)
      int v = tid + i * 256;
      int row = v >> 2, ch = (v & 3) * 8;
      uint4 u = *(const uint4*)(Bt + (size_t)row * 64 + kk + ch);
      *(uint4*)(Bs + row * LSTR + ch) = u;
    }
    __syncthreads();
    short8 af[4], bfr[4];
    #pragma unroll
    for (int t = 0; t < 4; ++t) {
      af[t]  = *(const short8*)(As + (wr + t * 16 + m) * LSTR + q * 8);
      bfr[t] = *(const short8*)(Bs + (wc + t * 16 + m) * LSTR + q * 8);
    }
    #pragma unroll
    for (int mt = 0; mt < 4; ++mt)
      #pragma unroll
      for (int nt = 0; nt < 4; ++nt)
        acc[mt][nt] = __builtin_amdgcn_mfma_f32_16x16x32_bf16(
            af[mt], bfr[nt], acc[mt][nt], 0, 0, 0);
    __syncthreads();
  }
  #pragma unroll
  for (int mt = 0; mt < 4; ++mt) {
    int grb = row0 + wr + mt * 16 + q * 4;
    #pragma unroll
    for (int nt = 0; nt < 4; ++nt) {
      int lc = wc + nt * 16 + m;              // local col in [0,128)
      float bias = b1f[head * 128 + lc];
      #pragma unroll
      for (int r = 0; r < 4; ++r) {
        int gr = grb + r;
        if (gr < M) {
          float v = acc[mt][nt][r] + bias;
          v = v > 0.f ? v : (__expf(v) - 1.0f);   // ELU
          x2[(size_t)gr * 512 + head * 128 + lc] = f2bf(v);
        }
      }
    }
  }
}

// ---------------- va vectors: va[h][k] = sum_c a[h*128+c] * W1t[(h*128+c)][k]
__global__ void k_valpha(const u16* __restrict__ W1t,
                         const float* __restrict__ as1v, const float* __restrict__ ad1v,
                         float* __restrict__ va_s, float* __restrict__ va_d) {
  int t = threadIdx.x;           // 256 threads: h = t>>6, k = t&63
  int h = t >> 6, k = t & 63;
  float s = 0.f, d = 0.f;
  for (int c = 0; c < 128; ++c) {
    float w = bf2f(W1t[(size_t)(h * 128 + c) * 64 + k]);
    s = fmaf(as1v[h * 128 + c], w, s);
    d = fmaf(ad1v[h * 128 + c], w, d);
  }
  va_s[t] = s;
  va_d[t] = d;
}

// ---------------- layer-1 attention logits straight from ne ----------------
__global__ __launch_bounds__(256) void k_alpha1_ne(const u16* __restrict__ ne_b,
                                                   const float* __restrict__ va_s,
                                                   const float* __restrict__ va_d,
                                                   float* __restrict__ as_o,
                                                   float* __restrict__ ad_o) {
  int wid = threadIdx.x >> 6, lane = threadIdx.x & 63;
  int n = blockIdx.x * 4 + wid;
  if (n >= N_NODES) return;
  float v = bf2f(ne_b[(size_t)n * 64 + lane]);
  #pragma unroll
  for (int h = 0; h < 4; ++h) {
    float s = v * va_s[h * 64 + lane];
    float d = v * va_d[h * 64 + lane];
    #pragma unroll
    for (int off = 32; off >= 1; off >>= 1) {
      s += __shfl_xor(s, off, 64);
      d += __shfl_xor(d, off, 64);
    }
    if (lane == 0) { as_o[n * 4 + h] = s; ad_o[n * 4 + h] = d; }
  }
}

__global__ __launch_bounds__(256) void k_alpha2(const u16* __restrict__ h2,
                                                const float* __restrict__ a_src,
                                                const float* __restrict__ a_dst,
                                                float* __restrict__ as_o,
                                                float* __restrict__ ad_o) {
  int wid = threadIdx.x >> 6, lane = threadIdx.x & 63;
  int n = blockIdx.x * 4 + wid;
  if (n >= N_NODES) return;
  uint2 u = *(const uint2*)(h2 + (size_t)n * 256 + lane * 4);
  float f[4];
  f[0] = bf2f((u16)u.x); f[1] = bf2f((u16)(u.x >> 16));
  f[2] = bf2f((u16)u.y); f[3] = bf2f((u16)(u.y >> 16));
  float4 av = *(const float4*)(a_src + lane * 4);
  float4 dv = *(const float4*)(a_dst + lane * 4);
  float fa[4] = {av.x, av.y, av.z, av.w};
  float fd[4] = {dv.x, dv.y, dv.z, dv.w};
  float s = 0.f, d = 0.f;
  #pragma unroll
  for (int j = 0; j < 4; ++j) { s = fmaf(f[j], fa[j], s); d = fmaf(f[j], fd[j], d); }
  #pragma unroll
  for (int off = 32; off >= 1; off >>= 1) {
    s += __shfl_xor(s, off, 64);
    d += __shfl_xor(d, off, 64);
  }
  if (lane == 0) { as_o[n] = s; ad_o[n] = d; }
}

// ---------------- fused layer-1 aggregation: one wave per node ----------
// weights computed ONCE per edge (lane-parallel, 4 exp/edge) then
// shfl-broadcast in the gather loop. No LDS, no per-lane exp.
__global__ __launch_bounds__(256) void k_fagg1(const int* __restrict__ row_off,
                                               const int* __restrict__ srcs,
                                               const u16* __restrict__ ne_b,
                                               const float* __restrict__ as1,
                                               const float* __restrict__ ad1,
                                               u16* __restrict__ aggne) {
  int wid = threadIdx.x >> 6, lane = threadIdx.x & 63;
  int n = blockIdx.x * 4 + wid;
  if (n >= N_NODES) return;
  int start = row_off[n], end = row_off[n + 1];
  int g = lane >> 4, il = lane & 15;     // head group g, lane-in-group
  float adn_g = ad1[n * 4 + g];
  // per-head stats: max, then sum-exp (16-lane group per head)
  float mx = -1e30f;
  for (int e0 = start; e0 < end; e0 += 16) {
    int e = e0 + il;
    if (e < end) mx = fmaxf(mx, lrelu(as1[srcs[e] * 4 + g] + adn_g));
  }
  #pragma unroll
  for (int off = 8; off >= 1; off >>= 1) mx = fmaxf(mx, __shfl_xor(mx, off, 64));
  float sum = 0.f;
  for (int e0 = start; e0 < end; e0 += 16) {
    int e = e0 + il;
    if (e < end) sum += __expf(lrelu(as1[srcs[e] * 4 + g] + adn_g) - mx);
  }
  #pragma unroll
  for (int off = 8; off >= 1; off >>= 1) sum += __shfl_xor(sum, off, 64);
  float inv = 1.0f / (sum + 1e-16f);
  // broadcast all-head stats to every lane
  float m_[4], i_[4], d_[4];
  #pragma unroll
  for (int h = 0; h < 4; ++h) {
    m_[h] = __shfl(mx, h * 16, 64);
    i_[h] = __shfl(inv, h * 16, 64);
    d_[h] = __shfl(adn_g, h * 16, 64);
  }
  float acc[4] = {};
  for (int e0 = start; e0 < end; e0 += 64) {
    int lim = end - e0; if (lim > 64) lim = 64;
    int es = e0 + lane;
    int sreg = srcs[es < end ? es : end - 1];
    // lane-parallel: this lane's edge weights for all 4 heads (4 exp/edge)
    float4 a = *(const float4*)(as1 + sreg * 4);
    float wreg[4];
    wreg[0] = __expf(lrelu(a.x + d_[0]) - m_[0]) * i_[0];
    wreg[1] = __expf(lrelu(a.y + d_[1]) - m_[1]) * i_[1];
    wreg[2] = __expf(lrelu(a.z + d_[2]) - m_[2]) * i_[2];
    wreg[3] = __expf(lrelu(a.w + d_[3]) - m_[3]) * i_[3];
    int j = 0;
    for (; j + 1 < lim; j += 2) {
      int s0 = __shfl(sreg, j, 64), s1 = __shfl(sreg, j + 1, 64);
      float f0 = bf2f(ne_b[(size_t)s0 * 64 + lane]);
      float f1 = bf2f(ne_b[(size_t)s1 * 64 + lane]);
      #pragma unroll
      for (int h = 0; h < 4; ++h) {
        float w0 = __shfl(wreg[h], j, 64);
        float w1 = __shfl(wreg[h], j + 1, 64);
        acc[h] = fmaf(w0, f0, acc[h]);
        acc[h] = fmaf(w1, f1, acc[h]);
      }
    }
    if (j < lim) {
      int s0 = __shfl(sreg, j, 64);
      float f0 = bf2f(ne_b[(size_t)s0 * 64 + lane]);
      #pragma unroll
      for (int h = 0; h < 4; ++h)
        acc[h] = fmaf(__shfl(wreg[h], j, 64), f0, acc[h]);
    }
  }
  #pragma unroll
  for (int h = 0; h < 4; ++h)
    aggne[(size_t)n * 256 + h * 64 + lane] = f2bf(acc[h]);
}

// ---------------- fused layer-2 aggregation + block-level mean partial ----
// Per wave: node aggregate (no bias). Block reduces its 4 nodes in LDS and
// writes ONE 256-float partial row  ->  pblk[blockIdx][256].
__global__ __launch_bounds__(256) void k_fagg2(const int* __restrict__ row_off,
                                               const int* __restrict__ srcs,
                                               const u16* __restrict__ h2,
                                               const float* __restrict__ as2,
                                               const float* __restrict__ ad2,
                                               float* __restrict__ pblk) {
  __shared__ float part[4][256];
  int wid = threadIdx.x >> 6, lane = threadIdx.x & 63;
  int n = blockIdx.x * 4 + wid;
  float a0 = 0.f, a1 = 0.f, a2 = 0.f, a3 = 0.f;
  if (n < N_NODES) {
    int start = row_off[n], end = row_off[n + 1];
    float adn = ad2[n];
    float mx = -1e30f;
    for (int e0 = start; e0 < end; e0 += 64) {
      int e = e0 + lane;
      if (e < end) mx = fmaxf(mx, lrelu(as2[srcs[e]] + adn));
    }
    #pragma unroll
    for (int off = 32; off >= 1; off >>= 1) mx = fmaxf(mx, __shfl_xor(mx, off, 64));
    float sum = 0.f;
    for (int e0 = start; e0 < end; e0 += 64) {
      int e = e0 + lane;
      if (e < end) sum += __expf(lrelu(as2[srcs[e]] + adn) - mx);
    }
    #pragma unroll
    for (int off = 32; off >= 1; off >>= 1) sum += __shfl_xor(sum, off, 64);
    float inv = 1.0f / (sum + 1e-16f);
    for (int e0 = start; e0 < end; e0 += 64) {
      int lim = end - e0; if (lim > 64) lim = 64;
      int es = e0 + lane;
      int sreg = srcs[es < end ? es : end - 1];
      // lane-parallel weight for this lane's edge (1 exp/edge)
      float wlane = __expf(lrelu(as2[sreg] + adn) - mx) * inv;
      int j = 0;
      for (; j + 1 < lim; j += 2) {
        int s0 = __shfl(sreg, j, 64), s1 = __shfl(sreg, j + 1, 64);
        float w0 = __shfl(wlane, j, 64), w1 = __shfl(wlane, j + 1, 64);
        uint2 u0 = *(const uint2*)(h2 + (size_t)s0 * 256 + lane * 4);
        uint2 u1 = *(const uint2*)(h2 + (size_t)s1 * 256 + lane * 4);
        a0 = fmaf(w0, bf2f((u16)u0.x), a0); a0 = fmaf(w1, bf2f((u16)u1.x), a0);
        a1 = fmaf(w0, bf2f((u16)(u0.x >> 16)), a1); a1 = fmaf(w1, bf2f((u16)(u1.x >> 16)), a1);
        a2 = fmaf(w0, bf2f((u16)u0.y), a2); a2 = fmaf(w1, bf2f((u16)u1.y), a2);
        a3 = fmaf(w0, bf2f((u16)(u0.y >> 16)), a3); a3 = fmaf(w1, bf2f((u16)(u1.y >> 16)), a3);
      }
      if (j < lim) {
        int s0 = __shfl(sreg, j, 64);
        float w0 = __shfl(wlane, j, 64);
        uint2 u0 = *(const uint2*)(h2 + (size_t)s0 * 256 + lane * 4);
        a0 = fmaf(w0, bf2f((u16)u0.x), a0);
        a1 = fmaf(w0, bf2f((u16)(u0.x >> 16)), a1);
        a2 = fmaf(w0, bf2f((u16)u0.y), a2);
        a3 = fmaf(w0, bf2f((u16)(u0.y >> 16)), a3);
      }
    }
  }
  *(float4*)&part[wid][lane * 4] = make_float4(a0, a1, a2, a3);
  __syncthreads();
  int c = threadIdx.x;
  pblk[(size_t)blockIdx.x * 256 + c] =
      part[0][c] + part[1][c] + part[2][c] + part[3][c];
}

// ---------------- mean over block partials ----------------
__global__ __launch_bounds__(256) void k_reduce(const float* __restrict__ pblk,
                                                float* __restrict__ g, int rows) {
  int c = threadIdx.x;
  float acc = 0.f;
  for (int r = blockIdx.x; r < rows; r += 64)
    acc += pblk[(size_t)r * 256 + c];
  atomicAdd(&g[c], acc);
}

__global__ void k_final(const float* __restrict__ g, const float* __restrict__ b2f,
                        float* __restrict__ out, int out_size) {
  int i = blockIdx.x * 256 + threadIdx.x;
  if (i < out_size)
    out[i] = g[i & 255] * (1.0f / (float)N_NODES) + b2f[i & 255];
}

// ---------------- launch ----------------
extern "C" void kernel_launch(void* const* d_in, const int* in_sizes, int n_in,
                              void* d_out, int out_size, void* d_ws, size_t ws_size,
                              hipStream_t stream) {
  (void)in_sizes; (void)n_in; (void)ws_size;
  const int* edge_index = (const int*)d_in[0];
  float* out = (float*)d_out;   // reference output dtype is float32

  char* w = (char*)d_ws;
  size_t off = 0;
  auto alloc = [&](size_t bytes) -> void* {
    void* p = w + off;
    off += (bytes + 255) & ~(size_t)255;
    return p;
  };
  u16*   ne_b    = (u16*)  alloc((size_t)N_NODES * 64 * 2);   // 6.4 MB bf16
  u16*   W1t     = (u16*)  alloc(32768 * 2);                  // [512][64]
  u16*   W2t     = (u16*)  alloc(131072 * 2);                 // [256][512]
  float* as1v    = (float*)alloc(512 * 4);
  float* ad1v    = (float*)alloc(512 * 4);
  float* b1f     = (float*)alloc(512 * 4);
  float* as2v    = (float*)alloc(256 * 4);
  float* ad2v    = (float*)alloc(256 * 4);
  float* b2f     = (float*)alloc(256 * 4);
  float* va_s    = (float*)alloc(256 * 4);
  float* va_d    = (float*)alloc(256 * 4);
  u16*   aggne   = (u16*)  alloc((size_t)N_NODES * 256 * 2);  // 25.6 MB
  u16*   x2      = (u16*)  alloc((size_t)N_NODES * 512 * 2);  // 51.2 MB
  u16*   h2      = (u16*)  alloc((size_t)N_NODES * 256 * 2);  // 25.6 MB
  float* as1     = (float*)alloc((size_t)N_NODES * 4 * 4);
  float* ad1     = (float*)alloc((size_t)N_NODES * 4 * 4);
  float* as2     = (float*)alloc((size_t)N_NODES * 4);
  float* ad2     = (float*)alloc((size_t)N_NODES * 4);
  float* pblk    = (float*)alloc((size_t)NBLK * 256 * 4);     // 12.8 MB
  int*   row_off = (int*)  alloc((size_t)(N_NODES + 1) * 4);
  int*   cursor  = (int*)  alloc((size_t)N_NODES * 4);
  int*   deg     = (int*)  alloc((size_t)N_NODES * 4);
  int*   srcs    = (int*)  alloc((size_t)ET * 4);
  int*   btot    = (int*)  alloc(64 * 4);
  int*   bbase   = (int*)  alloc(64 * 4);
  float* g       = (float*)alloc(256 * 4);
  int*   flag    = (int*)  alloc(64 * 4);

  hipMemsetAsync(deg, 0, (size_t)N_NODES * 4, stream);
  hipMemsetAsync(g, 0, 256 * 4, stream);

  // dtype detect + canonicalize
  k_detect<<<1, 64, 0, stream>>>((const u16*)d_in[2], flag);
  k_cvt_bf16<<<(N_NODES * 64 + 255) / 256, 256, 0, stream>>>(d_in[2], ne_b,
                                                             N_NODES * 64, flag);
  k_cvt_w_t<<<(32768 + 255) / 256, 256, 0, stream>>>(d_in[3], W1t, 64, 512, flag);
  k_cvt_w_t<<<(131072 + 255) / 256, 256, 0, stream>>>(d_in[7], W2t, 512, 256, flag);
  k_cvt_params<<<9, 256, 0, stream>>>(d_in[4], d_in[5], d_in[6], d_in[8], d_in[9],
                                      d_in[10], as1v, ad1v, b1f, as2v, ad2v, b2f,
                                      flag);
  k_valpha<<<1, 256, 0, stream>>>(W1t, as1v, ad1v, va_s, va_d);

  // CSR by dst (incl. self-loops)
  k_degree <<<(ET + 255) / 256, 256, 0, stream>>>(edge_index, deg);
  k_partial<<<49, 1024, 0, stream>>>(deg, row_off, btot);
  k_bases  <<<1, 64, 0, stream>>>(btot, bbase, row_off, 49);
  k_add    <<<49, 1024, 0, stream>>>(row_off, cursor, bbase);
  k_scatter<<<(ET + 255) / 256, 256, 0, stream>>>(edge_index, cursor, srcs);

  // layer 1: alphas from ne, fused agg over ne, then GEMM (+bias+ELU) -> x2
  k_alpha1_ne<<<(N_NODES + 3) / 4, 256, 0, stream>>>(ne_b, va_s, va_d, as1, ad1);
  k_fagg1<<<(N_NODES + 3) / 4, 256, 0, stream>>>(row_off, srcs, ne_b, as1, ad1, aggne);
  dim3 gl1((N_NODES + 127) / 128, 4);
  k_gemm_l1<<<gl1, 256, 0, stream>>>(aggne, W1t, b1f, x2, N_NODES);

  // layer 2
  dim3 g2((N_NODES + 127) / 128, 2);
  k_gemm_mfma<<<g2, 256, 0, stream>>>(x2, W2t, h2, N_NODES, 512, 256);
  k_alpha2<<<(N_NODES + 3) / 4, 256, 0, stream>>>(h2, as2v, ad2v, as2, ad2);
  k_fagg2<<<NBLK, 256, 0, stream>>>(row_off, srcs, h2, as2, ad2, pblk);

  // mean over block partials, add bias, broadcast to [batch, 256]
  k_reduce<<<64, 256, 0, stream>>>(pblk, g, NBLK);
  k_final <<<(out_size + 255) / 256, 256, 0, stream>>>(g, b2f, out, out_size);
}

// Round 9
// 394.635 us; speedup vs baseline: 2.0851x; 1.0524x over previous
//
#include <hip/hip_runtime.h>
#include <cstdint>

#define N_NODES 50000
#define N_EDGES 500000
#define ET (N_NODES + N_EDGES)   /* 550000 edges incl. self-loops */

typedef unsigned short u16;
typedef unsigned int   u32;
typedef __attribute__((ext_vector_type(8))) short short8;   // 8 bf16 (4 VGPRs)
typedef __attribute__((ext_vector_type(4))) float f32x4;

__device__ __forceinline__ float bf2f(u16 s) { return __uint_as_float((u32)s << 16); }
__device__ __forceinline__ u16 f2bf(float f) {          // round-to-nearest-even
  u32 u = __float_as_uint(f);
  u32 r = (u + 0x7FFFu + ((u >> 16) & 1u)) >> 16;
  return (u16)r;
}
__device__ __forceinline__ void unpack8(uint4 u, float* f) {  // 8 bf16 -> fp32
  f[0] = __uint_as_float(u.x << 16); f[1] = __uint_as_float(u.x & 0xffff0000u);
  f[2] = __uint_as_float(u.y << 16); f[3] = __uint_as_float(u.y & 0xffff0000u);
  f[4] = __uint_as_float(u.z << 16); f[5] = __uint_as_float(u.z & 0xffff0000u);
  f[6] = __uint_as_float(u.w << 16); f[7] = __uint_as_float(u.w & 0xffff0000u);
}
__device__ __forceinline__ float lrelu(float v) { return v >= 0.f ? v : 0.2f * v; }

// ---------------- dtype detect + canonicalize ----------------
__global__ void k_detect(const u16* __restrict__ ne, int* __restrict__ flag) {
  int lane = threadIdx.x;  // 64 threads, one wave
  int bad = 0;
  #pragma unroll
  for (int j = 0; j < 2; ++j) {
    float v = fabsf(bf2f(ne[lane * 2 + j * 128]));  // even positions only
    bad += (!(v < 16.0f)) ? 1 : 0;                  // catches NaN too
  }
  #pragma unroll
  for (int off = 32; off >= 1; off >>= 1) bad += __shfl_xor(bad, off, 64);
  if (lane == 0) flag[0] = (bad > 16) ? 1 : 0;      // 1 => inputs are fp32
}

__global__ void k_cvt_bf16(const void* __restrict__ src, u16* __restrict__ dst,
                           int n, const int* __restrict__ flag) {
  int i = blockIdx.x * 256 + threadIdx.x;
  if (i >= n) return;
  if (flag[0]) dst[i] = f2bf(((const float*)src)[i]);
  else         dst[i] = ((const u16*)src)[i];
}

// W [K][N] -> Wt [N][K] bf16
__global__ void k_cvt_w_t(const void* __restrict__ src, u16* __restrict__ dst,
                          int K, int N, const int* __restrict__ flag) {
  int i = blockIdx.x * 256 + threadIdx.x;
  if (i >= K * N) return;
  int n = i / K, k = i - n * K;
  u16 v;
  if (flag[0]) v = f2bf(((const float*)src)[k * N + n]);
  else         v = ((const u16*)src)[k * N + n];
  dst[i] = v;
}

// all 6 small fp32 param vectors in one launch (2304 elements total)
__global__ void k_cvt_params(const void* s0, const void* s1, const void* s2,
                             const void* s3, const void* s4, const void* s5,
                             float* d0, float* d1, float* d2,
                             float* d3, float* d4, float* d5,
                             const int* __restrict__ flag) {
  int i = blockIdx.x * 256 + threadIdx.x;
  const void* s; float* d; int j;
  if      (i < 512)  { s = s0; d = d0; j = i; }
  else if (i < 1024) { s = s1; d = d1; j = i - 512; }
  else if (i < 1536) { s = s2; d = d2; j = i - 1024; }
  else if (i < 1792) { s = s3; d = d3; j = i - 1536; }
  else if (i < 2048) { s = s4; d = d4; j = i - 1792; }
  else if (i < 2304) { s = s5; d = d5; j = i - 2048; }
  else return;
  if (flag[0]) d[j] = ((const float*)s)[j];
  else         d[j] = bf2f(((const u16*)s)[j]);
}

// ---------------- CSR build (dst-sorted) ----------------
__global__ void k_degree(const int* __restrict__ ei, int* __restrict__ deg) {
  int e = blockIdx.x * 256 + threadIdx.x;
  if (e >= ET) return;
  int d = (e < N_EDGES) ? ei[N_EDGES + e] : (e - N_EDGES);
  atomicAdd(&deg[d], 1);
}

__global__ __launch_bounds__(1024) void k_partial(const int* __restrict__ deg,
                                                  int* __restrict__ excl,
                                                  int* __restrict__ btot) {
  __shared__ int wsum[16];
  int tid = threadIdx.x;
  int i = blockIdx.x * 1024 + tid;
  int v = (i < N_NODES) ? deg[i] : 0;
  int lane = tid & 63, wid = tid >> 6;
  int incl = v;
  #pragma unroll
  for (int off = 1; off < 64; off <<= 1) {
    int t = __shfl_up(incl, off, 64);
    if (lane >= off) incl += t;
  }
  if (lane == 63) wsum[wid] = incl;
  __syncthreads();
  int prefix = 0;
  for (int w = 0; w < wid; ++w) prefix += wsum[w];
  if (i < N_NODES) excl[i] = prefix + incl - v;
  if (tid == 1023) btot[blockIdx.x] = prefix + incl;
}

__global__ void k_bases(const int* __restrict__ btot, int* __restrict__ bbase,
                        int* __restrict__ row_off, int nb) {
  int lane = threadIdx.x;  // 64 threads, single wave
  int v = (lane < nb) ? btot[lane] : 0;
  int incl = v;
  #pragma unroll
  for (int off = 1; off < 64; off <<= 1) {
    int t = __shfl_up(incl, off, 64);
    if (lane >= off) incl += t;
  }
  if (lane < nb) bbase[lane] = incl - v;
  if (lane == 0) row_off[N_NODES] = ET;
}

__global__ __launch_bounds__(1024) void k_add(int* __restrict__ row_off,
                                              int* __restrict__ cursor,
                                              const int* __restrict__ bbase) {
  int i = blockIdx.x * 1024 + threadIdx.x;
  if (i < N_NODES) {
    int r = row_off[i] + bbase[blockIdx.x];
    row_off[i] = r;
    cursor[i] = r;
  }
}

__global__ void k_scatter(const int* __restrict__ ei, int* __restrict__ cursor,
                          int* __restrict__ srcs) {
  int e = blockIdx.x * 256 + threadIdx.x;
  if (e >= ET) return;
  int s, d;
  if (e < N_EDGES) { s = ei[e]; d = ei[N_EDGES + e]; }
  else { s = d = e - N_EDGES; }
  int pos = atomicAdd(&cursor[d], 1);
  srcs[pos] = s;
}

// ---------------- layer-1 GEMM on aggregated ne, fused bias+ELU ----
#define LSTR 40
__global__ __launch_bounds__(256) void k_gemm_l1(const u16* __restrict__ aggne,
                                                 const u16* __restrict__ W1t,
                                                 const float* __restrict__ b1f,
                                                 u16* __restrict__ x2, int M) {
  __shared__ __align__(16) u16 As[128 * LSTR];
  __shared__ __align__(16) u16 Bs[128 * LSTR];
  const int tid = threadIdx.x;
  const int lane = tid & 63, wid = tid >> 6;
  const int wr = (wid >> 1) * 64, wc = (wid & 1) * 64;
  const int m = lane & 15, q = lane >> 4;
  const int row0 = blockIdx.x * 128, head = blockIdx.y;
  const u16* Bt = W1t + (size_t)head * 128 * 64;   // [128 rows][64]
  f32x4 acc[4][4] = {};
  #pragma unroll
  for (int kk = 0; kk < 64; kk += 32) {
    #pragma unroll
    for (int i = 0; i < 2; ++i) {             // stage A 128x32 (lda=256)
      int v = tid + i * 256;
      int row = v >> 2, ch = (v & 3) * 8;
      uint4 u = make_uint4(0, 0, 0, 0);
      int gr = row0 + row;
      if (gr < M) u = *(const uint4*)(aggne + (size_t)gr * 256 + head * 64 + kk + ch);
      *(uint4*)(As + row * LSTR + ch) = u;
    }
    #pragma unroll
    for (int i = 0; i < 2; ++i) {             // stage Bt 128x32 (stride 64)
      int v = tid + i * 256;
      int row = v >> 2, ch = (v & 3) * 8;
      uint4 u = *(const uint4*)(Bt + (size_t)row * 64 + kk + ch);
      *(uint4*)(Bs + row * LSTR + ch) = u;
    }
    __syncthreads();
    short8 af[4], bfr[4];
    #pragma unroll
    for (int t = 0; t < 4; ++t) {
      af[t]  = *(const short8*)(As + (wr + t * 16 + m) * LSTR + q * 8);
      bfr[t] = *(const short8*)(Bs + (wc + t * 16 + m) * LSTR + q * 8);
    }
    #pragma unroll
    for (int mt = 0; mt < 4; ++mt)
      #pragma unroll
      for (int nt = 0; nt < 4; ++nt)
        acc[mt][nt] = __builtin_amdgcn_mfma_f32_16x16x32_bf16(
            af[mt], bfr[nt], acc[mt][nt], 0, 0, 0);
    __syncthreads();
  }
  #pragma unroll
  for (int mt = 0; mt < 4; ++mt) {
    int grb = row0 + wr + mt * 16 + q * 4;
    #pragma unroll
    for (int nt = 0; nt < 4; ++nt) {
      int lc = wc + nt * 16 + m;              // local col in [0,128)
      float bias = b1f[head * 128 + lc];
      #pragma unroll
      for (int r = 0; r < 4; ++r) {
        int gr = grb + r;
        if (gr < M) {
          float v = acc[mt][nt][r] + bias;
          v = v > 0.f ? v : (__expf(v) - 1.0f);   // ELU
          x2[(size_t)gr * 512 + head * 128 + lc] = f2bf(v);
        }
      }
    }
  }
}

// ---------------- va vectors (layer1): va[h][k] = sum_c a1[h*128+c]*W1t[h*128+c][k]
__global__ void k_valpha(const u16* __restrict__ W1t,
                         const float* __restrict__ as1v, const float* __restrict__ ad1v,
                         float* __restrict__ va_s, float* __restrict__ va_d) {
  int t = threadIdx.x;           // 256 threads: h = t>>6, k = t&63
  int h = t >> 6, k = t & 63;
  float s = 0.f, d = 0.f;
  for (int c = 0; c < 128; ++c) {
    float w = bf2f(W1t[(size_t)(h * 128 + c) * 64 + k]);
    s = fmaf(as1v[h * 128 + c], w, s);
    d = fmaf(ad1v[h * 128 + c], w, d);
  }
  va_s[t] = s;
  va_d[t] = d;
}

// ---------------- va2 vectors (layer2): va2[k] = sum_c a2[c]*W2t[c][k], k<512
__global__ void k_va2(const u16* __restrict__ W2t,
                      const float* __restrict__ as2v, const float* __restrict__ ad2v,
                      float* __restrict__ va2_s, float* __restrict__ va2_d) {
  int k = blockIdx.x * 256 + threadIdx.x;
  if (k >= 512) return;
  float s = 0.f, d = 0.f;
  for (int c = 0; c < 256; ++c) {
    float w = bf2f(W2t[(size_t)c * 512 + k]);
    s = fmaf(as2v[c], w, s);
    d = fmaf(ad2v[c], w, d);
  }
  va2_s[k] = s;
  va2_d[k] = d;
}

// ---------------- layer-1 attention logits straight from ne ----------------
__global__ __launch_bounds__(256) void k_alpha1_ne(const u16* __restrict__ ne_b,
                                                   const float* __restrict__ va_s,
                                                   const float* __restrict__ va_d,
                                                   float* __restrict__ as_o,
                                                   float* __restrict__ ad_o) {
  int wid = threadIdx.x >> 6, lane = threadIdx.x & 63;
  int n = blockIdx.x * 4 + wid;
  if (n >= N_NODES) return;
  float v = bf2f(ne_b[(size_t)n * 64 + lane]);
  #pragma unroll
  for (int h = 0; h < 4; ++h) {
    float s = v * va_s[h * 64 + lane];
    float d = v * va_d[h * 64 + lane];
    #pragma unroll
    for (int off = 32; off >= 1; off >>= 1) {
      s += __shfl_xor(s, off, 64);
      d += __shfl_xor(d, off, 64);
    }
    if (lane == 0) { as_o[n * 4 + h] = s; ad_o[n * 4 + h] = d; }
  }
}

// ---------------- layer-2 attention logits straight from x2 ----------------
__global__ __launch_bounds__(256) void k_alpha2_x2(const u16* __restrict__ x2,
                                                   const float* __restrict__ va2_s,
                                                   const float* __restrict__ va2_d,
                                                   float* __restrict__ as_o,
                                                   float* __restrict__ ad_o) {
  int wid = threadIdx.x >> 6, lane = threadIdx.x & 63;
  int n = blockIdx.x * 4 + wid;
  if (n >= N_NODES) return;
  float f[8];
  unpack8(*(const uint4*)(x2 + (size_t)n * 512 + lane * 8), f);
  float4 s0 = *(const float4*)(va2_s + lane * 8);
  float4 s1 = *(const float4*)(va2_s + lane * 8 + 4);
  float4 d0 = *(const float4*)(va2_d + lane * 8);
  float4 d1 = *(const float4*)(va2_d + lane * 8 + 4);
  float fs[8] = {s0.x, s0.y, s0.z, s0.w, s1.x, s1.y, s1.z, s1.w};
  float fd[8] = {d0.x, d0.y, d0.z, d0.w, d1.x, d1.y, d1.z, d1.w};
  float s = 0.f, d = 0.f;
  #pragma unroll
  for (int j = 0; j < 8; ++j) { s = fmaf(f[j], fs[j], s); d = fmaf(f[j], fd[j], d); }
  #pragma unroll
  for (int off = 32; off >= 1; off >>= 1) {
    s += __shfl_xor(s, off, 64);
    d += __shfl_xor(d, off, 64);
  }
  if (lane == 0) { as_o[n] = s; ad_o[n] = d; }
}

// ---------------- fused layer-1 aggregation: one wave per node ----------
__global__ __launch_bounds__(256) void k_fagg1(const int* __restrict__ row_off,
                                               const int* __restrict__ srcs,
                                               const u16* __restrict__ ne_b,
                                               const float* __restrict__ as1,
                                               const float* __restrict__ ad1,
                                               u16* __restrict__ aggne) {
  int wid = threadIdx.x >> 6, lane = threadIdx.x & 63;
  int n = blockIdx.x * 4 + wid;
  if (n >= N_NODES) return;
  int start = row_off[n], end = row_off[n + 1];
  int g = lane >> 4, il = lane & 15;     // head group g, lane-in-group
  float adn_g = ad1[n * 4 + g];
  float mx = -1e30f;
  for (int e0 = start; e0 < end; e0 += 16) {
    int e = e0 + il;
    if (e < end) mx = fmaxf(mx, lrelu(as1[srcs[e] * 4 + g] + adn_g));
  }
  #pragma unroll
  for (int off = 8; off >= 1; off >>= 1) mx = fmaxf(mx, __shfl_xor(mx, off, 64));
  float sum = 0.f;
  for (int e0 = start; e0 < end; e0 += 16) {
    int e = e0 + il;
    if (e < end) sum += __expf(lrelu(as1[srcs[e] * 4 + g] + adn_g) - mx);
  }
  #pragma unroll
  for (int off = 8; off >= 1; off >>= 1) sum += __shfl_xor(sum, off, 64);
  float inv = 1.0f / (sum + 1e-16f);
  float m_[4], i_[4], d_[4];
  #pragma unroll
  for (int h = 0; h < 4; ++h) {
    m_[h] = __shfl(mx, h * 16, 64);
    i_[h] = __shfl(inv, h * 16, 64);
    d_[h] = __shfl(adn_g, h * 16, 64);
  }
  float acc[4] = {};
  for (int e0 = start; e0 < end; e0 += 64) {
    int lim = end - e0; if (lim > 64) lim = 64;
    int es = e0 + lane;
    int sreg = srcs[es < end ? es : end - 1];
    float4 a = *(const float4*)(as1 + sreg * 4);
    float wreg[4];
    wreg[0] = __expf(lrelu(a.x + d_[0]) - m_[0]) * i_[0];
    wreg[1] = __expf(lrelu(a.y + d_[1]) - m_[1]) * i_[1];
    wreg[2] = __expf(lrelu(a.z + d_[2]) - m_[2]) * i_[2];
    wreg[3] = __expf(lrelu(a.w + d_[3]) - m_[3]) * i_[3];
    int j = 0;
    for (; j + 1 < lim; j += 2) {
      int s0 = __shfl(sreg, j, 64), s1 = __shfl(sreg, j + 1, 64);
      float f0 = bf2f(ne_b[(size_t)s0 * 64 + lane]);
      float f1 = bf2f(ne_b[(size_t)s1 * 64 + lane]);
      #pragma unroll
      for (int h = 0; h < 4; ++h) {
        float w0 = __shfl(wreg[h], j, 64);
        float w1 = __shfl(wreg[h], j + 1, 64);
        acc[h] = fmaf(w0, f0, acc[h]);
        acc[h] = fmaf(w1, f1, acc[h]);
      }
    }
    if (j < lim) {
      int s0 = __shfl(sreg, j, 64);
      float f0 = bf2f(ne_b[(size_t)s0 * 64 + lane]);
      #pragma unroll
      for (int h = 0; h < 4; ++h)
        acc[h] = fmaf(__shfl(wreg[h], j, 64), f0, acc[h]);
    }
  }
  #pragma unroll
  for (int h = 0; h < 4; ++h)
    aggne[(size_t)n * 256 + h * 64 + lane] = f2bf(acc[h]);
}

// ---------------- layer-2: per-src total softmax weight c[s] ----------
// c[s] = sum over edges (s -> n) of softmax2 weight. One wave per dst node.
__global__ __launch_bounds__(256) void k_nodew(const int* __restrict__ row_off,
                                               const int* __restrict__ srcs,
                                               const float* __restrict__ as2,
                                               const float* __restrict__ ad2,
                                               float* __restrict__ c) {
  int wid = threadIdx.x >> 6, lane = threadIdx.x & 63;
  int n = blockIdx.x * 4 + wid;
  if (n >= N_NODES) return;
  int start = row_off[n], end = row_off[n + 1];
  float adn = ad2[n];
  float mx = -1e30f;
  for (int e = start + lane; e < end; e += 64)
    mx = fmaxf(mx, lrelu(as2[srcs[e]] + adn));
  #pragma unroll
  for (int off = 32; off >= 1; off >>= 1) mx = fmaxf(mx, __shfl_xor(mx, off, 64));
  float sum = 0.f;
  for (int e = start + lane; e < end; e += 64)
    sum += __expf(lrelu(as2[srcs[e]] + adn) - mx);
  #pragma unroll
  for (int off = 32; off >= 1; off >>= 1) sum += __shfl_xor(sum, off, 64);
  float inv = 1.0f / (sum + 1e-16f);
  for (int e = start + lane; e < end; e += 64) {
    int s = srcs[e];
    float w = __expf(lrelu(as2[s] + adn) - mx) * inv;
    atomicAdd(&c[s], w);
  }
}

// ---------------- weighted column sum: s_vec[ch] = sum_n c[n]*x2[n][ch] ----
__global__ __launch_bounds__(256) void k_wsum(const u16* __restrict__ x2,
                                              const float* __restrict__ c,
                                              float* __restrict__ s_vec) {
  int tid = threadIdx.x;
  int n0 = blockIdx.x * 64;
  float a0 = 0.f, a1 = 0.f;
  int lim = N_NODES - n0; if (lim > 64) lim = 64;
  for (int i = 0; i < lim; ++i) {
    int n = n0 + i;
    float cn = c[n];
    u32 u = *(const u32*)(x2 + (size_t)n * 512 + tid * 2);
    a0 = fmaf(cn, bf2f((u16)u), a0);
    a1 = fmaf(cn, bf2f((u16)(u >> 16)), a1);
  }
  atomicAdd(&s_vec[tid * 2], a0);
  atomicAdd(&s_vec[tid * 2 + 1], a1);
}

// ---------------- tiny GEMM: out_g[cc] = sum_k s_vec[k] * W2t[cc][k] ----
__global__ void k_gemm_tiny(const float* __restrict__ s_vec,
                            const u16* __restrict__ W2t,
                            float* __restrict__ out_g) {
  int cc = threadIdx.x;  // 256 threads
  float acc = 0.f;
  for (int k = 0; k < 512; ++k)
    acc = fmaf(s_vec[k], bf2f(W2t[(size_t)cc * 512 + k]), acc);
  out_g[cc] = acc;
}

__global__ void k_final(const float* __restrict__ out_g, const float* __restrict__ b2f,
                        float* __restrict__ out, int out_size) {
  int i = blockIdx.x * 256 + threadIdx.x;
  if (i < out_size)
    out[i] = out_g[i & 255] * (1.0f / (float)N_NODES) + b2f[i & 255];
}

// ---------------- launch ----------------
extern "C" void kernel_launch(void* const* d_in, const int* in_sizes, int n_in,
                              void* d_out, int out_size, void* d_ws, size_t ws_size,
                              hipStream_t stream) {
  (void)in_sizes; (void)n_in; (void)ws_size;
  const int* edge_index = (const int*)d_in[0];
  float* out = (float*)d_out;   // reference output dtype is float32

  char* w = (char*)d_ws;
  size_t off = 0;
  auto alloc = [&](size_t bytes) -> void* {
    void* p = w + off;
    off += (bytes + 255) & ~(size_t)255;
    return p;
  };
  u16*   ne_b    = (u16*)  alloc((size_t)N_NODES * 64 * 2);   // 6.4 MB bf16
  u16*   W1t     = (u16*)  alloc(32768 * 2);                  // [512][64]
  u16*   W2t     = (u16*)  alloc(131072 * 2);                 // [256][512]
  float* as1v    = (float*)alloc(512 * 4);
  float* ad1v    = (float*)alloc(512 * 4);
  float* b1f     = (float*)alloc(512 * 4);
  float* as2v    = (float*)alloc(256 * 4);
  float* ad2v    = (float*)alloc(256 * 4);
  float* b2f     = (float*)alloc(256 * 4);
  float* va_s    = (float*)alloc(256 * 4);
  float* va_d    = (float*)alloc(256 * 4);
  float* va2_s   = (float*)alloc(512 * 4);
  float* va2_d   = (float*)alloc(512 * 4);
  u16*   aggne   = (u16*)  alloc((size_t)N_NODES * 256 * 2);  // 25.6 MB
  u16*   x2      = (u16*)  alloc((size_t)N_NODES * 512 * 2);  // 51.2 MB
  float* as1     = (float*)alloc((size_t)N_NODES * 4 * 4);
  float* ad1     = (float*)alloc((size_t)N_NODES * 4 * 4);
  float* as2     = (float*)alloc((size_t)N_NODES * 4);
  float* ad2     = (float*)alloc((size_t)N_NODES * 4);
  float* cwt     = (float*)alloc((size_t)N_NODES * 4);
  float* s_vec   = (float*)alloc(512 * 4);
  float* out_g   = (float*)alloc(256 * 4);
  int*   row_off = (int*)  alloc((size_t)(N_NODES + 1) * 4);
  int*   cursor  = (int*)  alloc((size_t)N_NODES * 4);
  int*   deg     = (int*)  alloc((size_t)N_NODES * 4);
  int*   srcs    = (int*)  alloc((size_t)ET * 4);
  int*   btot    = (int*)  alloc(64 * 4);
  int*   bbase   = (int*)  alloc(64 * 4);
  int*   flag    = (int*)  alloc(64 * 4);

  hipMemsetAsync(deg, 0, (size_t)N_NODES * 4, stream);
  hipMemsetAsync(cwt, 0, (size_t)N_NODES * 4, stream);
  hipMemsetAsync(s_vec, 0, 512 * 4, stream);

  // dtype detect + canonicalize
  k_detect<<<1, 64, 0, stream>>>((const u16*)d_in[2], flag);
  k_cvt_bf16<<<(N_NODES * 64 + 255) / 256, 256, 0, stream>>>(d_in[2], ne_b,
                                                             N_NODES * 64, flag);
  k_cvt_w_t<<<(32768 + 255) / 256, 256, 0, stream>>>(d_in[3], W1t, 64, 512, flag);
  k_cvt_w_t<<<(131072 + 255) / 256, 256, 0, stream>>>(d_in[7], W2t, 512, 256, flag);
  k_cvt_params<<<9, 256, 0, stream>>>(d_in[4], d_in[5], d_in[6], d_in[8], d_in[9],
                                      d_in[10], as1v, ad1v, b1f, as2v, ad2v, b2f,
                                      flag);
  k_valpha<<<1, 256, 0, stream>>>(W1t, as1v, ad1v, va_s, va_d);
  k_va2<<<2, 256, 0, stream>>>(W2t, as2v, ad2v, va2_s, va2_d);

  // CSR by dst (incl. self-loops)
  k_degree <<<(ET + 255) / 256, 256, 0, stream>>>(edge_index, deg);
  k_partial<<<49, 1024, 0, stream>>>(deg, row_off, btot);
  k_bases  <<<1, 64, 0, stream>>>(btot, bbase, row_off, 49);
  k_add    <<<49, 1024, 0, stream>>>(row_off, cursor, bbase);
  k_scatter<<<(ET + 255) / 256, 256, 0, stream>>>(edge_index, cursor, srcs);

  // layer 1: alphas from ne, fused agg over ne, then GEMM (+bias+ELU) -> x2
  k_alpha1_ne<<<(N_NODES + 3) / 4, 256, 0, stream>>>(ne_b, va_s, va_d, as1, ad1);
  k_fagg1<<<(N_NODES + 3) / 4, 256, 0, stream>>>(row_off, srcs, ne_b, as1, ad1, aggne);
  dim3 gl1((N_NODES + 127) / 128, 4);
  k_gemm_l1<<<gl1, 256, 0, stream>>>(aggne, W1t, b1f, x2, N_NODES);

  // layer 2 (mean-reassociated): alphas from x2, per-src weights, weighted sum
  k_alpha2_x2<<<(N_NODES + 3) / 4, 256, 0, stream>>>(x2, va2_s, va2_d, as2, ad2);
  k_nodew<<<(N_NODES + 3) / 4, 256, 0, stream>>>(row_off, srcs, as2, ad2, cwt);
  k_wsum<<<(N_NODES + 63) / 64, 256, 0, stream>>>(x2, cwt, s_vec);
  k_gemm_tiny<<<1, 256, 0, stream>>>(s_vec, W2t, out_g);

  k_final<<<(out_size + 255) / 256, 256, 0, stream>>>(out_g, b2f, out, out_size);
}

// Round 10
// 347.741 us; speedup vs baseline: 2.3663x; 1.1349x over previous
//
#include <hip/hip_runtime.h>
#include <cstdint>

#define N_NODES 50000
#define N_EDGES 500000
#define ET (N_NODES + N_EDGES)   /* 550000 edges incl. self-loops */

typedef unsigned short u16;
typedef unsigned int   u32;
typedef __attribute__((ext_vector_type(8))) short short8;   // 8 bf16 (4 VGPRs)
typedef __attribute__((ext_vector_type(4))) float f32x4;

__device__ __forceinline__ float bf2f(u16 s) { return __uint_as_float((u32)s << 16); }
__device__ __forceinline__ u16 f2bf(float f) {          // round-to-nearest-even
  u32 u = __float_as_uint(f);
  u32 r = (u + 0x7FFFu + ((u >> 16) & 1u)) >> 16;
  return (u16)r;
}
__device__ __forceinline__ void unpack8(uint4 u, float* f) {  // 8 bf16 -> fp32
  f[0] = __uint_as_float(u.x << 16); f[1] = __uint_as_float(u.x & 0xffff0000u);
  f[2] = __uint_as_float(u.y << 16); f[3] = __uint_as_float(u.y & 0xffff0000u);
  f[4] = __uint_as_float(u.z << 16); f[5] = __uint_as_float(u.z & 0xffff0000u);
  f[6] = __uint_as_float(u.w << 16); f[7] = __uint_as_float(u.w & 0xffff0000u);
}
__device__ __forceinline__ float lrelu(float v) { return v >= 0.f ? v : 0.2f * v; }

// ---------------- dtype detect + canonicalize ----------------
__global__ void k_detect(const u16* __restrict__ ne, int* __restrict__ flag) {
  int lane = threadIdx.x;  // 64 threads, one wave
  int bad = 0;
  #pragma unroll
  for (int j = 0; j < 2; ++j) {
    float v = fabsf(bf2f(ne[lane * 2 + j * 128]));  // even positions only
    bad += (!(v < 16.0f)) ? 1 : 0;                  // catches NaN too
  }
  #pragma unroll
  for (int off = 32; off >= 1; off >>= 1) bad += __shfl_xor(bad, off, 64);
  if (lane == 0) flag[0] = (bad > 16) ? 1 : 0;      // 1 => inputs are fp32
}

__global__ void k_cvt_bf16(const void* __restrict__ src, u16* __restrict__ dst,
                           int n, const int* __restrict__ flag) {
  int i = blockIdx.x * 256 + threadIdx.x;
  if (i >= n) return;
  if (flag[0]) dst[i] = f2bf(((const float*)src)[i]);
  else         dst[i] = ((const u16*)src)[i];
}

// W [K][N] -> Wt [N][K] bf16
__global__ void k_cvt_w_t(const void* __restrict__ src, u16* __restrict__ dst,
                          int K, int N, const int* __restrict__ flag) {
  int i = blockIdx.x * 256 + threadIdx.x;
  if (i >= K * N) return;
  int n = i / K, k = i - n * K;
  u16 v;
  if (flag[0]) v = f2bf(((const float*)src)[k * N + n]);
  else         v = ((const u16*)src)[k * N + n];
  dst[i] = v;
}

// all 6 small fp32 param vectors in one launch (2304 elements total)
__global__ void k_cvt_params(const void* s0, const void* s1, const void* s2,
                             const void* s3, const void* s4, const void* s5,
                             float* d0, float* d1, float* d2,
                             float* d3, float* d4, float* d5,
                             const int* __restrict__ flag) {
  int i = blockIdx.x * 256 + threadIdx.x;
  const void* s; float* d; int j;
  if      (i < 512)  { s = s0; d = d0; j = i; }
  else if (i < 1024) { s = s1; d = d1; j = i - 512; }
  else if (i < 1536) { s = s2; d = d2; j = i - 1024; }
  else if (i < 1792) { s = s3; d = d3; j = i - 1536; }
  else if (i < 2048) { s = s4; d = d4; j = i - 1792; }
  else if (i < 2304) { s = s5; d = d5; j = i - 2048; }
  else return;
  if (flag[0]) d[j] = ((const float*)s)[j];
  else         d[j] = bf2f(((const u16*)s)[j]);
}

// ---------------- CSR build (dst-sorted) ----------------
__global__ void k_degree(const int* __restrict__ ei, int* __restrict__ deg) {
  int e = blockIdx.x * 256 + threadIdx.x;
  if (e >= ET) return;
  int d = (e < N_EDGES) ? ei[N_EDGES + e] : (e - N_EDGES);
  atomicAdd(&deg[d], 1);
}

__global__ __launch_bounds__(1024) void k_partial(const int* __restrict__ deg,
                                                  int* __restrict__ excl,
                                                  int* __restrict__ btot) {
  __shared__ int wsum[16];
  int tid = threadIdx.x;
  int i = blockIdx.x * 1024 + tid;
  int v = (i < N_NODES) ? deg[i] : 0;
  int lane = tid & 63, wid = tid >> 6;
  int incl = v;
  #pragma unroll
  for (int off = 1; off < 64; off <<= 1) {
    int t = __shfl_up(incl, off, 64);
    if (lane >= off) incl += t;
  }
  if (lane == 63) wsum[wid] = incl;
  __syncthreads();
  int prefix = 0;
  for (int w = 0; w < wid; ++w) prefix += wsum[w];
  if (i < N_NODES) excl[i] = prefix + incl - v;
  if (tid == 1023) btot[blockIdx.x] = prefix + incl;
}

__global__ void k_bases(const int* __restrict__ btot, int* __restrict__ bbase,
                        int* __restrict__ row_off, int nb) {
  int lane = threadIdx.x;  // 64 threads, single wave
  int v = (lane < nb) ? btot[lane] : 0;
  int incl = v;
  #pragma unroll
  for (int off = 1; off < 64; off <<= 1) {
    int t = __shfl_up(incl, off, 64);
    if (lane >= off) incl += t;
  }
  if (lane < nb) bbase[lane] = incl - v;
  if (lane == 0) row_off[N_NODES] = ET;
}

__global__ __launch_bounds__(1024) void k_add(int* __restrict__ row_off,
                                              int* __restrict__ cursor,
                                              const int* __restrict__ bbase) {
  int i = blockIdx.x * 1024 + threadIdx.x;
  if (i < N_NODES) {
    int r = row_off[i] + bbase[blockIdx.x];
    row_off[i] = r;
    cursor[i] = r;
  }
}

__global__ void k_scatter(const int* __restrict__ ei, int* __restrict__ cursor,
                          int* __restrict__ srcs) {
  int e = blockIdx.x * 256 + threadIdx.x;
  if (e >= ET) return;
  int s, d;
  if (e < N_EDGES) { s = ei[e]; d = ei[N_EDGES + e]; }
  else { s = d = e - N_EDGES; }
  int pos = atomicAdd(&cursor[d], 1);
  srcs[pos] = s;
}

// ---------------- layer-1 GEMM on aggregated ne, fused bias+ELU ----
#define LSTR 40
__global__ __launch_bounds__(256) void k_gemm_l1(const u16* __restrict__ aggne,
                                                 const u16* __restrict__ W1t,
                                                 const float* __restrict__ b1f,
                                                 u16* __restrict__ x2, int M) {
  __shared__ __align__(16) u16 As[128 * LSTR];
  __shared__ __align__(16) u16 Bs[128 * LSTR];
  const int tid = threadIdx.x;
  const int lane = tid & 63, wid = tid >> 6;
  const int wr = (wid >> 1) * 64, wc = (wid & 1) * 64;
  const int m = lane & 15, q = lane >> 4;
  const int row0 = blockIdx.x * 128, head = blockIdx.y;
  const u16* Bt = W1t + (size_t)head * 128 * 64;   // [128 rows][64]
  f32x4 acc[4][4] = {};
  #pragma unroll
  for (int kk = 0; kk < 64; kk += 32) {
    #pragma unroll
    for (int i = 0; i < 2; ++i) {             // stage A 128x32 (lda=256)
      int v = tid + i * 256;
      int row = v >> 2, ch = (v & 3) * 8;
      uint4 u = make_uint4(0, 0, 0, 0);
      int gr = row0 + row;
      if (gr < M) u = *(const uint4*)(aggne + (size_t)gr * 256 + head * 64 + kk + ch);
      *(uint4*)(As + row * LSTR + ch) = u;
    }
    #pragma unroll
    for (int i = 0; i < 2; ++i) {             // stage Bt 128x32 (stride 64)
      int v = tid + i * 256;
      int row = v >> 2, ch = (v & 3) * 8;
      uint4 u = *(const uint4*)(Bt + (size_t)row * 64 + kk + ch);
      *(uint4*)(Bs + row * LSTR + ch) = u;
    }
    __syncthreads();
    short8 af[4], bfr[4];
    #pragma unroll
    for (int t = 0; t < 4; ++t) {
      af[t]  = *(const short8*)(As + (wr + t * 16 + m) * LSTR + q * 8);
      bfr[t] = *(const short8*)(Bs + (wc + t * 16 + m) * LSTR + q * 8);
    }
    #pragma unroll
    for (int mt = 0; mt < 4; ++mt)
      #pragma unroll
      for (int nt = 0; nt < 4; ++nt)
        acc[mt][nt] = __builtin_amdgcn_mfma_f32_16x16x32_bf16(
            af[mt], bfr[nt], acc[mt][nt], 0, 0, 0);
    __syncthreads();
  }
  #pragma unroll
  for (int mt = 0; mt < 4; ++mt) {
    int grb = row0 + wr + mt * 16 + q * 4;
    #pragma unroll
    for (int nt = 0; nt < 4; ++nt) {
      int lc = wc + nt * 16 + m;              // local col in [0,128)
      float bias = b1f[head * 128 + lc];
      #pragma unroll
      for (int r = 0; r < 4; ++r) {
        int gr = grb + r;
        if (gr < M) {
          float v = acc[mt][nt][r] + bias;
          v = v > 0.f ? v : (__expf(v) - 1.0f);   // ELU
          x2[(size_t)gr * 512 + head * 128 + lc] = f2bf(v);
        }
      }
    }
  }
}

// ---------------- va vectors (layer1): va[h][k] = sum_c a1[h*128+c]*W1t[h*128+c][k]
__global__ void k_valpha(const u16* __restrict__ W1t,
                         const float* __restrict__ as1v, const float* __restrict__ ad1v,
                         float* __restrict__ va_s, float* __restrict__ va_d) {
  int t = threadIdx.x;           // 256 threads: h = t>>6, k = t&63
  int h = t >> 6, k = t & 63;
  float s = 0.f, d = 0.f;
  for (int c = 0; c < 128; ++c) {
    float w = bf2f(W1t[(size_t)(h * 128 + c) * 64 + k]);
    s = fmaf(as1v[h * 128 + c], w, s);
    d = fmaf(ad1v[h * 128 + c], w, d);
  }
  va_s[t] = s;
  va_d[t] = d;
}

// ---------------- va2 vectors (layer2): va2[k] = sum_c a2[c]*W2t[c][k], k<512
__global__ void k_va2(const u16* __restrict__ W2t,
                      const float* __restrict__ as2v, const float* __restrict__ ad2v,
                      float* __restrict__ va2_s, float* __restrict__ va2_d) {
  int k = blockIdx.x * 256 + threadIdx.x;
  if (k >= 512) return;
  float s = 0.f, d = 0.f;
  for (int c = 0; c < 256; ++c) {
    float w = bf2f(W2t[(size_t)c * 512 + k]);
    s = fmaf(as2v[c], w, s);
    d = fmaf(ad2v[c], w, d);
  }
  va2_s[k] = s;
  va2_d[k] = d;
}

// ---------------- layer-1 attention logits straight from ne ----------------
__global__ __launch_bounds__(256) void k_alpha1_ne(const u16* __restrict__ ne_b,
                                                   const float* __restrict__ va_s,
                                                   const float* __restrict__ va_d,
                                                   float* __restrict__ as_o,
                                                   float* __restrict__ ad_o) {
  int wid = threadIdx.x >> 6, lane = threadIdx.x & 63;
  int n = blockIdx.x * 4 + wid;
  if (n >= N_NODES) return;
  float v = bf2f(ne_b[(size_t)n * 64 + lane]);
  #pragma unroll
  for (int h = 0; h < 4; ++h) {
    float s = v * va_s[h * 64 + lane];
    float d = v * va_d[h * 64 + lane];
    #pragma unroll
    for (int off = 32; off >= 1; off >>= 1) {
      s += __shfl_xor(s, off, 64);
      d += __shfl_xor(d, off, 64);
    }
    if (lane == 0) { as_o[n * 4 + h] = s; ad_o[n * 4 + h] = d; }
  }
}

// ---------------- layer-2 attention logits straight from x2 ----------------
__global__ __launch_bounds__(256) void k_alpha2_x2(const u16* __restrict__ x2,
                                                   const float* __restrict__ va2_s,
                                                   const float* __restrict__ va2_d,
                                                   float* __restrict__ as_o,
                                                   float* __restrict__ ad_o) {
  int wid = threadIdx.x >> 6, lane = threadIdx.x & 63;
  int n = blockIdx.x * 4 + wid;
  if (n >= N_NODES) return;
  float f[8];
  unpack8(*(const uint4*)(x2 + (size_t)n * 512 + lane * 8), f);
  float4 s0 = *(const float4*)(va2_s + lane * 8);
  float4 s1 = *(const float4*)(va2_s + lane * 8 + 4);
  float4 d0 = *(const float4*)(va2_d + lane * 8);
  float4 d1 = *(const float4*)(va2_d + lane * 8 + 4);
  float fs[8] = {s0.x, s0.y, s0.z, s0.w, s1.x, s1.y, s1.z, s1.w};
  float fd[8] = {d0.x, d0.y, d0.z, d0.w, d1.x, d1.y, d1.z, d1.w};
  float s = 0.f, d = 0.f;
  #pragma unroll
  for (int j = 0; j < 8; ++j) { s = fmaf(f[j], fs[j], s); d = fmaf(f[j], fd[j], d); }
  #pragma unroll
  for (int off = 32; off >= 1; off >>= 1) {
    s += __shfl_xor(s, off, 64);
    d += __shfl_xor(d, off, 64);
  }
  if (lane == 0) { as_o[n] = s; ad_o[n] = d; }
}

// ---------------- fused layer-1 aggregation: one wave per node ----------
__global__ __launch_bounds__(256) void k_fagg1(const int* __restrict__ row_off,
                                               const int* __restrict__ srcs,
                                               const u16* __restrict__ ne_b,
                                               const float* __restrict__ as1,
                                               const float* __restrict__ ad1,
                                               u16* __restrict__ aggne) {
  int wid = threadIdx.x >> 6, lane = threadIdx.x & 63;
  int n = blockIdx.x * 4 + wid;
  if (n >= N_NODES) return;
  int start = row_off[n], end = row_off[n + 1];
  int g = lane >> 4, il = lane & 15;     // head group g, lane-in-group
  float adn_g = ad1[n * 4 + g];
  float mx = -1e30f;
  for (int e0 = start; e0 < end; e0 += 16) {
    int e = e0 + il;
    if (e < end) mx = fmaxf(mx, lrelu(as1[srcs[e] * 4 + g] + adn_g));
  }
  #pragma unroll
  for (int off = 8; off >= 1; off >>= 1) mx = fmaxf(mx, __shfl_xor(mx, off, 64));
  float sum = 0.f;
  for (int e0 = start; e0 < end; e0 += 16) {
    int e = e0 + il;
    if (e < end) sum += __expf(lrelu(as1[srcs[e] * 4 + g] + adn_g) - mx);
  }
  #pragma unroll
  for (int off = 8; off >= 1; off >>= 1) sum += __shfl_xor(sum, off, 64);
  float inv = 1.0f / (sum + 1e-16f);
  float m_[4], i_[4], d_[4];
  #pragma unroll
  for (int h = 0; h < 4; ++h) {
    m_[h] = __shfl(mx, h * 16, 64);
    i_[h] = __shfl(inv, h * 16, 64);
    d_[h] = __shfl(adn_g, h * 16, 64);
  }
  float acc[4] = {};
  for (int e0 = start; e0 < end; e0 += 64) {
    int lim = end - e0; if (lim > 64) lim = 64;
    int es = e0 + lane;
    int sreg = srcs[es < end ? es : end - 1];
    float4 a = *(const float4*)(as1 + sreg * 4);
    float wreg[4];
    wreg[0] = __expf(lrelu(a.x + d_[0]) - m_[0]) * i_[0];
    wreg[1] = __expf(lrelu(a.y + d_[1]) - m_[1]) * i_[1];
    wreg[2] = __expf(lrelu(a.z + d_[2]) - m_[2]) * i_[2];
    wreg[3] = __expf(lrelu(a.w + d_[3]) - m_[3]) * i_[3];
    int j = 0;
    for (; j + 1 < lim; j += 2) {
      int s0 = __shfl(sreg, j, 64), s1 = __shfl(sreg, j + 1, 64);
      float f0 = bf2f(ne_b[(size_t)s0 * 64 + lane]);
      float f1 = bf2f(ne_b[(size_t)s1 * 64 + lane]);
      #pragma unroll
      for (int h = 0; h < 4; ++h) {
        float w0 = __shfl(wreg[h], j, 64);
        float w1 = __shfl(wreg[h], j + 1, 64);
        acc[h] = fmaf(w0, f0, acc[h]);
        acc[h] = fmaf(w1, f1, acc[h]);
      }
    }
    if (j < lim) {
      int s0 = __shfl(sreg, j, 64);
      float f0 = bf2f(ne_b[(size_t)s0 * 64 + lane]);
      #pragma unroll
      for (int h = 0; h < 4; ++h)
        acc[h] = fmaf(__shfl(wreg[h], j, 64), f0, acc[h]);
    }
  }
  #pragma unroll
  for (int h = 0; h < 4; ++h)
    aggne[(size_t)n * 256 + h * 64 + lane] = f2bf(acc[h]);
}

// ---------------- layer-2: per-src total softmax weight c[s] ----------
__global__ __launch_bounds__(256) void k_nodew(const int* __restrict__ row_off,
                                               const int* __restrict__ srcs,
                                               const float* __restrict__ as2,
                                               const float* __restrict__ ad2,
                                               float* __restrict__ c) {
  int wid = threadIdx.x >> 6, lane = threadIdx.x & 63;
  int n = blockIdx.x * 4 + wid;
  if (n >= N_NODES) return;
  int start = row_off[n], end = row_off[n + 1];
  float adn = ad2[n];
  float mx = -1e30f;
  for (int e = start + lane; e < end; e += 64)
    mx = fmaxf(mx, lrelu(as2[srcs[e]] + adn));
  #pragma unroll
  for (int off = 32; off >= 1; off >>= 1) mx = fmaxf(mx, __shfl_xor(mx, off, 64));
  float sum = 0.f;
  for (int e = start + lane; e < end; e += 64)
    sum += __expf(lrelu(as2[srcs[e]] + adn) - mx);
  #pragma unroll
  for (int off = 32; off >= 1; off >>= 1) sum += __shfl_xor(sum, off, 64);
  float inv = 1.0f / (sum + 1e-16f);
  for (int e = start + lane; e < end; e += 64) {
    int s = srcs[e];
    float w = __expf(lrelu(as2[s] + adn) - mx) * inv;
    atomicAdd(&c[s], w);
  }
}

// ---------------- weighted column sum: s_vec[ch] = sum_n c[n]*x2[n][ch] ----
// 256 blocks x 4 waves; each wave reads full 1KB rows (uint4/lane),
// grid-stride over nodes; LDS reduce; 512 atomics per BLOCK.
#define WSB 256
__global__ __launch_bounds__(256) void k_wsum(const u16* __restrict__ x2,
                                              const float* __restrict__ c,
                                              float* __restrict__ s_vec) {
  __shared__ float part[4][512];
  int wid = threadIdx.x >> 6, lane = threadIdx.x & 63;
  int wglob = blockIdx.x * 4 + wid;          // 0..WSB*4-1
  float acc[8] = {};
  int n = wglob;
  for (; n + WSB * 4 < N_NODES; n += WSB * 8) {   // unroll x2: two rows in flight
    int n2 = n + WSB * 4;
    float c0 = c[n], c1 = c[n2];
    uint4 u0 = *(const uint4*)(x2 + (size_t)n * 512 + lane * 8);
    uint4 u1 = *(const uint4*)(x2 + (size_t)n2 * 512 + lane * 8);
    float f0[8], f1[8];
    unpack8(u0, f0); unpack8(u1, f1);
    #pragma unroll
    for (int j = 0; j < 8; ++j) {
      acc[j] = fmaf(c0, f0[j], acc[j]);
      acc[j] = fmaf(c1, f1[j], acc[j]);
    }
  }
  if (n < N_NODES) {
    float c0 = c[n];
    uint4 u0 = *(const uint4*)(x2 + (size_t)n * 512 + lane * 8);
    float f0[8];
    unpack8(u0, f0);
    #pragma unroll
    for (int j = 0; j < 8; ++j) acc[j] = fmaf(c0, f0[j], acc[j]);
  }
  #pragma unroll
  for (int j = 0; j < 8; ++j) part[wid][lane * 8 + j] = acc[j];
  __syncthreads();
  int t = threadIdx.x;
  float v0 = part[0][t] + part[1][t] + part[2][t] + part[3][t];
  float v1 = part[0][t + 256] + part[1][t + 256] + part[2][t + 256] + part[3][t + 256];
  atomicAdd(&s_vec[t], v0);
  atomicAdd(&s_vec[t + 256], v1);
}

// ---------------- tiny GEMM: out_g[cc] = sum_k s_vec[k] * W2t[cc][k] ----
// 4 blocks x 4 waves; wave produces 16 channels via coalesced row reads.
__global__ __launch_bounds__(256) void k_gemm_tiny(const float* __restrict__ s_vec,
                                                   const u16* __restrict__ W2t,
                                                   float* __restrict__ out_g) {
  int wid = threadIdx.x >> 6, lane = threadIdx.x & 63;
  int cbase = blockIdx.x * 64 + wid * 16;
  float sv[8];
  #pragma unroll
  for (int j = 0; j < 8; ++j) sv[j] = s_vec[lane * 8 + j];
  for (int i = 0; i < 16; ++i) {
    int cc = cbase + i;
    uint4 u = *(const uint4*)(W2t + (size_t)cc * 512 + lane * 8);
    float f[8];
    unpack8(u, f);
    float p = 0.f;
    #pragma unroll
    for (int j = 0; j < 8; ++j) p = fmaf(sv[j], f[j], p);
    #pragma unroll
    for (int off = 32; off >= 1; off >>= 1) p += __shfl_xor(p, off, 64);
    if (lane == 0) out_g[cc] = p;
  }
}

__global__ void k_final(const float* __restrict__ out_g, const float* __restrict__ b2f,
                        float* __restrict__ out, int out_size) {
  int i = blockIdx.x * 256 + threadIdx.x;
  if (i < out_size)
    out[i] = out_g[i & 255] * (1.0f / (float)N_NODES) + b2f[i & 255];
}

// ---------------- launch ----------------
extern "C" void kernel_launch(void* const* d_in, const int* in_sizes, int n_in,
                              void* d_out, int out_size, void* d_ws, size_t ws_size,
                              hipStream_t stream) {
  (void)in_sizes; (void)n_in; (void)ws_size;
  const int* edge_index = (const int*)d_in[0];
  float* out = (float*)d_out;   // reference output dtype is float32

  char* w = (char*)d_ws;
  size_t off = 0;
  auto alloc = [&](size_t bytes) -> void* {
    void* p = w + off;
    off += (bytes + 255) & ~(size_t)255;
    return p;
  };
  u16*   ne_b    = (u16*)  alloc((size_t)N_NODES * 64 * 2);   // 6.4 MB bf16
  u16*   W1t     = (u16*)  alloc(32768 * 2);                  // [512][64]
  u16*   W2t     = (u16*)  alloc(131072 * 2);                 // [256][512]
  float* as1v    = (float*)alloc(512 * 4);
  float* ad1v    = (float*)alloc(512 * 4);
  float* b1f     = (float*)alloc(512 * 4);
  float* as2v    = (float*)alloc(256 * 4);
  float* ad2v    = (float*)alloc(256 * 4);
  float* b2f     = (float*)alloc(256 * 4);
  float* va_s    = (float*)alloc(256 * 4);
  float* va_d    = (float*)alloc(256 * 4);
  float* va2_s   = (float*)alloc(512 * 4);
  float* va2_d   = (float*)alloc(512 * 4);
  u16*   aggne   = (u16*)  alloc((size_t)N_NODES * 256 * 2);  // 25.6 MB
  u16*   x2      = (u16*)  alloc((size_t)N_NODES * 512 * 2);  // 51.2 MB
  float* as1     = (float*)alloc((size_t)N_NODES * 4 * 4);
  float* ad1     = (float*)alloc((size_t)N_NODES * 4 * 4);
  float* as2     = (float*)alloc((size_t)N_NODES * 4);
  float* ad2     = (float*)alloc((size_t)N_NODES * 4);
  float* cwt     = (float*)alloc((size_t)N_NODES * 4);
  float* s_vec   = (float*)alloc(512 * 4);
  float* out_g   = (float*)alloc(256 * 4);
  int*   row_off = (int*)  alloc((size_t)(N_NODES + 1) * 4);
  int*   cursor  = (int*)  alloc((size_t)N_NODES * 4);
  int*   deg     = (int*)  alloc((size_t)N_NODES * 4);
  int*   srcs    = (int*)  alloc((size_t)ET * 4);
  int*   btot    = (int*)  alloc(64 * 4);
  int*   bbase   = (int*)  alloc(64 * 4);
  int*   flag    = (int*)  alloc(64 * 4);

  hipMemsetAsync(deg, 0, (size_t)N_NODES * 4, stream);
  hipMemsetAsync(cwt, 0, (size_t)N_NODES * 4, stream);
  hipMemsetAsync(s_vec, 0, 512 * 4, stream);

  // dtype detect + canonicalize
  k_detect<<<1, 64, 0, stream>>>((const u16*)d_in[2], flag);
  k_cvt_bf16<<<(N_NODES * 64 + 255) / 256, 256, 0, stream>>>(d_in[2], ne_b,
                                                             N_NODES * 64, flag);
  k_cvt_w_t<<<(32768 + 255) / 256, 256, 0, stream>>>(d_in[3], W1t, 64, 512, flag);
  k_cvt_w_t<<<(131072 + 255) / 256, 256, 0, stream>>>(d_in[7], W2t, 512, 256, flag);
  k_cvt_params<<<9, 256, 0, stream>>>(d_in[4], d_in[5], d_in[6], d_in[8], d_in[9],
                                      d_in[10], as1v, ad1v, b1f, as2v, ad2v, b2f,
                                      flag);
  k_valpha<<<1, 256, 0, stream>>>(W1t, as1v, ad1v, va_s, va_d);
  k_va2<<<2, 256, 0, stream>>>(W2t, as2v, ad2v, va2_s, va2_d);

  // CSR by dst (incl. self-loops)
  k_degree <<<(ET + 255) / 256, 256, 0, stream>>>(edge_index, deg);
  k_partial<<<49, 1024, 0, stream>>>(deg, row_off, btot);
  k_bases  <<<1, 64, 0, stream>>>(btot, bbase, row_off, 49);
  k_add    <<<49, 1024, 0, stream>>>(row_off, cursor, bbase);
  k_scatter<<<(ET + 255) / 256, 256, 0, stream>>>(edge_index, cursor, srcs);

  // layer 1: alphas from ne, fused agg over ne, then GEMM (+bias+ELU) -> x2
  k_alpha1_ne<<<(N_NODES + 3) / 4, 256, 0, stream>>>(ne_b, va_s, va_d, as1, ad1);
  k_fagg1<<<(N_NODES + 3) / 4, 256, 0, stream>>>(row_off, srcs, ne_b, as1, ad1, aggne);
  dim3 gl1((N_NODES + 127) / 128, 4);
  k_gemm_l1<<<gl1, 256, 0, stream>>>(aggne, W1t, b1f, x2, N_NODES);

  // layer 2 (mean-reassociated): alphas from x2, per-src weights, weighted sum
  k_alpha2_x2<<<(N_NODES + 3) / 4, 256, 0, stream>>>(x2, va2_s, va2_d, as2, ad2);
  k_nodew<<<(N_NODES + 3) / 4, 256, 0, stream>>>(row_off, srcs, as2, ad2, cwt);
  k_wsum<<<WSB, 256, 0, stream>>>(x2, cwt, s_vec);
  k_gemm_tiny<<<4, 256, 0, stream>>>(s_vec, W2t, out_g);

  k_final<<<(out_size + 255) / 256, 256, 0, stream>>>(out_g, b2f, out, out_size);
}